// Round 1
// baseline (11790.372 us; speedup 1.0000x reference)
//
#include <hip/hip_runtime.h>
#include <math.h>

namespace {
constexpr int B_ = 64, T_ = 12, N_ = 1024, H_ = 64, E_ = 16, K_ = 3;
constexpr int C_  = 65;          // DIN + H
constexpr int BC_ = B_ * C_;     // 4160
constexpr int OG_ = 128;         // gate output = 2H
constexpr int OU_ = 64;          // update output = H
constexpr float EPS_ = 1e-12f;
}

// ---------------------------------------------------------------------------
// e = LN(node_emb + time_emb[t]) * lng + lnb, for gate and upd params.
// Writes row-major (for contraction) and transposed (for sup kernel coalescing).
__global__ void k_compute_e(const float* __restrict__ node_emb,
                            const float* __restrict__ time_emb,
                            const float* __restrict__ g_lng, const float* __restrict__ g_lnb,
                            const float* __restrict__ u_lng, const float* __restrict__ u_lnb,
                            int t,
                            float* __restrict__ eg, float* __restrict__ egT,
                            float* __restrict__ eu, float* __restrict__ euT) {
  int n = blockIdx.x * blockDim.x + threadIdx.x;
  if (n >= N_) return;
  float v[E_];
  float m = 0.f;
#pragma unroll
  for (int d = 0; d < E_; d++) { v[d] = node_emb[n * E_ + d] + time_emb[t * E_ + d]; m += v[d]; }
  m *= (1.0f / E_);
  float var = 0.f;
#pragma unroll
  for (int d = 0; d < E_; d++) { float x = v[d] - m; var += x * x; }
  var *= (1.0f / E_);
  float rs = rsqrtf(var + EPS_);
#pragma unroll
  for (int d = 0; d < E_; d++) {
    float nv = (v[d] - m) * rs;
    float g = nv * g_lng[d] + g_lnb[d];
    float u = nv * u_lng[d] + u_lnb[d];
    eg[n * E_ + d] = g; egT[d * N_ + n] = g;
    eu[n * E_ + d] = u; euT[d * N_ + n] = u;
  }
}

// ---------------------------------------------------------------------------
// sup[n,:] = softmax over m of e[n]·e[m].  One block per row n. eT is [E][N].
__global__ __launch_bounds__(256) void k_sup(const float* __restrict__ eT,
                                             float* __restrict__ sup) {
  const int n = blockIdx.x;
  const int tid = threadIdx.x;
  __shared__ float red[256];
  float en[E_];
#pragma unroll
  for (int d = 0; d < E_; d++) en[d] = eT[d * N_ + n];
  float lg[4];
  float mx = -3.4e38f;
#pragma unroll
  for (int j = 0; j < 4; j++) {
    int m = tid + 256 * j;
    float s = 0.f;
#pragma unroll
    for (int d = 0; d < E_; d++) s = fmaf(en[d], eT[d * N_ + m], s);
    lg[j] = s;
    mx = fmaxf(mx, s);
  }
  red[tid] = mx; __syncthreads();
  for (int off = 128; off > 0; off >>= 1) {
    if (tid < off) red[tid] = fmaxf(red[tid], red[tid + off]);
    __syncthreads();
  }
  mx = red[0]; __syncthreads();
  float sum = 0.f;
#pragma unroll
  for (int j = 0; j < 4; j++) { lg[j] = __expf(lg[j] - mx); sum += lg[j]; }
  red[tid] = sum; __syncthreads();
  for (int off = 128; off > 0; off >>= 1) {
    if (tid < off) red[tid] += red[tid + off];
    __syncthreads();
  }
  float inv = 1.0f / red[0];
#pragma unroll
  for (int j = 0; j < 4; j++) sup[(size_t)n * N_ + tid + 256 * j] = lg[j] * inv;
}

// ---------------------------------------------------------------------------
// X[m, b*65+c] = c==0 ? x_t[b,m] : h[b,m,c-1]    (gate input)
__global__ void k_build_x_gate(const float* __restrict__ src, const float* __restrict__ h,
                               int t, float* __restrict__ X) {
  int idx = blockIdx.x * 256 + threadIdx.x;
  if (idx >= N_ * BC_) return;
  int m = idx / BC_;
  int j = idx - m * BC_;
  int b = j / C_;
  int c = j - b * C_;
  X[idx] = (c == 0) ? src[((size_t)b * T_ + t) * N_ + m]
                    : h[((size_t)b * N_ + m) * H_ + (c - 1)];
}

// X[m, b*65+c] = c==0 ? x_t[b,m] : z[b,m,c-1]*h[b,m,c-1]    (update input)
__global__ void k_build_x_upd(const float* __restrict__ src, const float* __restrict__ h,
                              const float* __restrict__ z, int t, float* __restrict__ X) {
  int idx = blockIdx.x * 256 + threadIdx.x;
  if (idx >= N_ * BC_) return;
  int m = idx / BC_;
  int j = idx - m * BC_;
  int b = j / C_;
  int c = j - b * C_;
  if (c == 0) X[idx] = src[((size_t)b * T_ + t) * N_ + m];
  else {
    size_t hi = ((size_t)b * N_ + m) * H_ + (c - 1);
    X[idx] = z[hi] * h[hi];
  }
}

// ---------------------------------------------------------------------------
// C[1024 x 4160] = A[1024 x 1024] * B[1024 x 4160], fp32, 128x64 tile, BK=16.
#define GBM 128
#define GBN 64
#define GBK 16
__global__ __launch_bounds__(256) void k_gemm(const float* __restrict__ A,
                                              const float* __restrict__ Bm,
                                              float* __restrict__ Cm) {
  __shared__ float As[GBK][132];   // pad to 132: conflict-free + 16B-aligned rows
  __shared__ float Bs[GBK][GBN];
  const int tid = threadIdx.x;
  const int tx = tid & 15;         // 16 col-groups of 4
  const int ty = tid >> 4;         // 16 row-groups of 8
  const int row0 = blockIdx.y * GBM;
  const int col0 = blockIdx.x * GBN;
  float acc[8][4] = {};
  for (int k0 = 0; k0 < N_; k0 += GBK) {
#pragma unroll
    for (int q = 0; q < 8; q++) {          // A tile 128x16
      int i = tid + q * 256;
      int m = i >> 4, kk = i & 15;
      As[kk][m] = A[(size_t)(row0 + m) * N_ + k0 + kk];
    }
#pragma unroll
    for (int q = 0; q < 4; q++) {          // B tile 16x64
      int i = tid + q * 256;
      int kk = i >> 6, j = i & 63;
      Bs[kk][j] = Bm[(size_t)(k0 + kk) * BC_ + col0 + j];
    }
    __syncthreads();
#pragma unroll
    for (int kk = 0; kk < GBK; kk++) {
      float av[8], bv[4];
#pragma unroll
      for (int rr = 0; rr < 8; rr++) av[rr] = As[kk][ty * 8 + rr];
#pragma unroll
      for (int cc = 0; cc < 4; cc++) bv[cc] = Bs[kk][tx * 4 + cc];
#pragma unroll
      for (int rr = 0; rr < 8; rr++)
#pragma unroll
        for (int cc = 0; cc < 4; cc++)
          acc[rr][cc] = fmaf(av[rr], bv[cc], acc[rr][cc]);
    }
    __syncthreads();
  }
#pragma unroll
  for (int rr = 0; rr < 8; rr++) {
    float4 v = make_float4(acc[rr][0], acc[rr][1], acc[rr][2], acc[rr][3]);
    *(float4*)&Cm[(size_t)(row0 + ty * 8 + rr) * BC_ + col0 + tx * 4] = v;
  }
}

// ---------------------------------------------------------------------------
// Gate contraction: per node n, out[b,o] = sum_{k,i} xg_k[b,i] * W[k,i,o] + bias[o];
// W[k,i,o] = sum_d e[n,d] wp[d,k,i,o] computed on the fly. zr=sigmoid -> z,r.
__global__ __launch_bounds__(256) void k_gate_contract(
    const float* __restrict__ eg,
    const float* __restrict__ X, const float* __restrict__ y1, const float* __restrict__ y2,
    const float* __restrict__ wp, const float* __restrict__ bp,
    float* __restrict__ z, float* __restrict__ r) {
  const int n = blockIdx.x;
  const int tid = threadIdx.x;
  __shared__ float es[E_];
  __shared__ float Ws[16][OG_];   // 8 KB
  __shared__ float xs[64][16];    // 4 KB
  if (tid < E_) es[tid] = eg[n * E_ + tid];
  const int og = tid & 31;        // o = og*4+oo
  const int bg = tid >> 5;        // b = bg*8+bb
  float acc[8][4] = {};
  for (int k = 0; k < K_; k++) {
    for (int i0 = 0; i0 < C_; i0 += 16) {
      const int iv = (C_ - i0 < 16) ? (C_ - i0) : 16;
      __syncthreads();
#pragma unroll
      for (int q = 0; q < 8; q++) {            // W tile: 16x128
        int idx = tid + q * 256;
        int ii = idx >> 7, o = idx & 127;
        float w = 0.f;
        if (ii < iv) {
#pragma unroll
          for (int d = 0; d < E_; d++)
            w = fmaf(es[d], wp[(((size_t)d * K_ + k) * C_ + i0 + ii) * OG_ + o], w);
        }
        Ws[ii][o] = w;
      }
#pragma unroll
      for (int q = 0; q < 4; q++) {            // xg tile: 64x16
        int idx = tid + q * 256;
        int b = idx >> 4, ii = idx & 15;
        float v = 0.f;
        if (ii < iv) {
          size_t a = (size_t)n * BC_ + (size_t)b * C_ + i0 + ii;
          if (k == 0)      v = X[a];
          else if (k == 1) v = y1[a];
          else             v = 2.0f * y2[a] - X[a];
        }
        xs[b][ii] = v;
      }
      __syncthreads();
#pragma unroll
      for (int ii = 0; ii < 16; ii++) {
        float4 wv = *(const float4*)&Ws[ii][og * 4];
#pragma unroll
        for (int bb = 0; bb < 8; bb++) {
          float xv = xs[bg * 8 + bb][ii];
          acc[bb][0] = fmaf(xv, wv.x, acc[bb][0]);
          acc[bb][1] = fmaf(xv, wv.y, acc[bb][1]);
          acc[bb][2] = fmaf(xv, wv.z, acc[bb][2]);
          acc[bb][3] = fmaf(xv, wv.w, acc[bb][3]);
        }
      }
    }
  }
#pragma unroll
  for (int oo = 0; oo < 4; oo++) {
    int o = og * 4 + oo;
    float bias = 0.f;
#pragma unroll
    for (int d = 0; d < E_; d++) bias = fmaf(es[d], bp[d * OG_ + o], bias);
#pragma unroll
    for (int bb = 0; bb < 8; bb++) {
      int b = bg * 8 + bb;
      float v = acc[bb][oo] + bias;
      float s = 1.0f / (1.0f + __expf(-v));
      size_t oidx = ((size_t)b * N_ + n) * H_;
      if (o < H_) z[oidx + o] = s;
      else        r[oidx + (o - H_)] = s;
    }
  }
}

// ---------------------------------------------------------------------------
// Update contraction + GRU state update: hc = tanh(...); h = r*h + (1-r)*hc.
__global__ __launch_bounds__(256) void k_upd_contract(
    const float* __restrict__ eu,
    const float* __restrict__ X, const float* __restrict__ y1, const float* __restrict__ y2,
    const float* __restrict__ wp, const float* __restrict__ bp,
    const float* __restrict__ r,
    float* __restrict__ h) {
  const int n = blockIdx.x;
  const int tid = threadIdx.x;
  __shared__ float es[E_];
  __shared__ float Ws[16][OU_];   // 4 KB
  __shared__ float xs[64][16];    // 4 KB
  if (tid < E_) es[tid] = eu[n * E_ + tid];
  const int og = tid & 15;        // o = og*4+oo  (64 outputs)
  const int bg = tid >> 4;        // b = bg*4+bb  (16 groups of 4)
  float acc[4][4] = {};
  for (int k = 0; k < K_; k++) {
    for (int i0 = 0; i0 < C_; i0 += 16) {
      const int iv = (C_ - i0 < 16) ? (C_ - i0) : 16;
      __syncthreads();
#pragma unroll
      for (int q = 0; q < 4; q++) {            // W tile: 16x64
        int idx = tid + q * 256;
        int ii = idx >> 6, o = idx & 63;
        float w = 0.f;
        if (ii < iv) {
#pragma unroll
          for (int d = 0; d < E_; d++)
            w = fmaf(es[d], wp[(((size_t)d * K_ + k) * C_ + i0 + ii) * OU_ + o], w);
        }
        Ws[ii][o] = w;
      }
#pragma unroll
      for (int q = 0; q < 4; q++) {            // xg tile: 64x16
        int idx = tid + q * 256;
        int b = idx >> 4, ii = idx & 15;
        float v = 0.f;
        if (ii < iv) {
          size_t a = (size_t)n * BC_ + (size_t)b * C_ + i0 + ii;
          if (k == 0)      v = X[a];
          else if (k == 1) v = y1[a];
          else             v = 2.0f * y2[a] - X[a];
        }
        xs[b][ii] = v;
      }
      __syncthreads();
#pragma unroll
      for (int ii = 0; ii < 16; ii++) {
        float4 wv = *(const float4*)&Ws[ii][og * 4];
#pragma unroll
        for (int bb = 0; bb < 4; bb++) {
          float xv = xs[bg * 4 + bb][ii];
          acc[bb][0] = fmaf(xv, wv.x, acc[bb][0]);
          acc[bb][1] = fmaf(xv, wv.y, acc[bb][1]);
          acc[bb][2] = fmaf(xv, wv.z, acc[bb][2]);
          acc[bb][3] = fmaf(xv, wv.w, acc[bb][3]);
        }
      }
    }
  }
#pragma unroll
  for (int oo = 0; oo < 4; oo++) {
    int o = og * 4 + oo;
    float bias = 0.f;
#pragma unroll
    for (int d = 0; d < E_; d++) bias = fmaf(es[d], bp[d * OU_ + o], bias);
#pragma unroll
    for (int bb = 0; bb < 4; bb++) {
      int b = bg * 4 + bb;
      size_t hi = ((size_t)b * N_ + n) * H_ + o;
      float hc = tanhf(acc[bb][oo] + bias);
      float rv = r[hi];
      h[hi] = rv * h[hi] + (1.0f - rv) * hc;
    }
  }
}

// ---------------------------------------------------------------------------
// y = LN(h) over H; out[b,o,n] = y[b,n,:]·conv_w[o,:] + conv_b[o]
__global__ __launch_bounds__(64) void k_final(const float* __restrict__ h,
                                              const float* __restrict__ out_lng,
                                              const float* __restrict__ out_lnb,
                                              const float* __restrict__ conv_w,
                                              const float* __restrict__ conv_b,
                                              float* __restrict__ out) {
  const int bn = blockIdx.x;          // b*N + n
  const int b = bn >> 10;
  const int n = bn & 1023;
  const int tid = threadIdx.x;        // 64 = one wave
  float v = h[(size_t)bn * H_ + tid];
  float s = v;
  for (int off = 32; off > 0; off >>= 1) s += __shfl_down(s, off);
  s = __shfl(s, 0);
  float mean = s * (1.0f / H_);
  float d = v - mean;
  float vs = d * d;
  for (int off = 32; off > 0; off >>= 1) vs += __shfl_down(vs, off);
  vs = __shfl(vs, 0);
  float var = vs * (1.0f / H_);
  float y = d * rsqrtf(var + EPS_) * out_lng[tid] + out_lnb[tid];
  __shared__ float ys[64];
  ys[tid] = y;
  __syncthreads();
  if (tid < 12) {
    float accv = conv_b[tid];
#pragma unroll
    for (int hh = 0; hh < H_; hh++) accv = fmaf(ys[hh], conv_w[tid * H_ + hh], accv);
    out[((size_t)b * 12 + tid) * N_ + n] = accv;
  }
}

// ---------------------------------------------------------------------------
extern "C" void kernel_launch(void* const* d_in, const int* in_sizes, int n_in,
                              void* d_out, int out_size, void* d_ws, size_t ws_size,
                              hipStream_t stream) {
  const float* src      = (const float*)d_in[0];
  const float* node_emb = (const float*)d_in[1];
  const float* time_emb = (const float*)d_in[2];
  const float* gate_wp  = (const float*)d_in[3];
  const float* gate_bp  = (const float*)d_in[4];
  const float* gate_lng = (const float*)d_in[5];
  const float* gate_lnb = (const float*)d_in[6];
  const float* upd_wp   = (const float*)d_in[7];
  const float* upd_bp   = (const float*)d_in[8];
  const float* upd_lng  = (const float*)d_in[9];
  const float* upd_lnb  = (const float*)d_in[10];
  const float* out_lng  = (const float*)d_in[11];
  const float* out_lnb  = (const float*)d_in[12];
  const float* conv_w   = (const float*)d_in[13];
  const float* conv_b   = (const float*)d_in[14];
  float* out = (float*)d_out;

  float* ws = (float*)d_ws;
  size_t off = 0;
  float* h   = ws + off; off += (size_t)B_ * N_ * H_;   // 4.19M
  float* z   = ws + off; off += (size_t)B_ * N_ * H_;
  float* r   = ws + off; off += (size_t)B_ * N_ * H_;
  float* X   = ws + off; off += (size_t)N_ * BC_;       // 4.26M
  float* y1  = ws + off; off += (size_t)N_ * BC_;
  float* y2  = ws + off; off += (size_t)N_ * BC_;
  float* sup = ws + off; off += (size_t)N_ * N_;        // 1.05M
  float* eg  = ws + off; off += N_ * E_;
  float* egT = ws + off; off += N_ * E_;
  float* eu  = ws + off; off += N_ * E_;
  float* euT = ws + off; off += N_ * E_;
  if (ws_size < off * sizeof(float)) return;  // workspace too small: bail

  hipMemsetAsync(h, 0, (size_t)B_ * N_ * H_ * sizeof(float), stream);

  const int xblocks = (N_ * BC_ + 255) / 256;   // 16640
  dim3 gemm_grid(BC_ / GBN, N_ / GBM);          // (65, 8)

  for (int t = 0; t < T_; t++) {
    k_compute_e<<<4, 256, 0, stream>>>(node_emb, time_emb, gate_lng, gate_lnb,
                                       upd_lng, upd_lnb, t, eg, egT, eu, euT);
    // ---- gate dagcn ----
    k_sup<<<N_, 256, 0, stream>>>(egT, sup);
    k_build_x_gate<<<xblocks, 256, 0, stream>>>(src, h, t, X);
    k_gemm<<<gemm_grid, 256, 0, stream>>>(sup, X, y1);
    k_gemm<<<gemm_grid, 256, 0, stream>>>(sup, y1, y2);
    k_gate_contract<<<N_, 256, 0, stream>>>(eg, X, y1, y2, gate_wp, gate_bp, z, r);
    // ---- update dagcn ----
    k_sup<<<N_, 256, 0, stream>>>(euT, sup);
    k_build_x_upd<<<xblocks, 256, 0, stream>>>(src, h, z, t, X);
    k_gemm<<<gemm_grid, 256, 0, stream>>>(sup, X, y1);
    k_gemm<<<gemm_grid, 256, 0, stream>>>(sup, y1, y2);
    k_upd_contract<<<N_, 256, 0, stream>>>(eu, X, y1, y2, upd_wp, upd_bp, r, h);
  }
  k_final<<<B_ * N_, 64, 0, stream>>>(h, out_lng, out_lnb, conv_w, conv_b, out);
}

// Round 2
// 7943.125 us; speedup vs baseline: 1.4843x; 1.4843x over previous
//
#include <hip/hip_runtime.h>
#include <math.h>

namespace {
constexpr int B_ = 64, T_ = 12, N_ = 1024, H_ = 64, E_ = 16, K_ = 3;
constexpr int C_  = 65;          // DIN + H
constexpr int BC_ = B_ * C_;     // 4160
constexpr int OG_ = 128;         // gate output = 2H
constexpr int OU_ = 64;          // update output = H
constexpr float EPS_ = 1e-12f;
constexpr int NP_ = 4224;        // BC_ padded to 128 for GEMM N-tiling
}

typedef unsigned short u16;
typedef unsigned int u32;
using bf16x8 = __attribute__((ext_vector_type(8))) short;
using f32x4  = __attribute__((ext_vector_type(4))) float;

// float -> bf16 (RNE) and back, for hi/lo split: v ~= hi + lo with ~2^-17 rel err.
__device__ __forceinline__ u16 f2bf(float f) {
  union { float f; u32 u; } x; x.f = f;
  u32 r = x.u + 0x7FFFu + ((x.u >> 16) & 1u);
  return (u16)(r >> 16);
}
__device__ __forceinline__ float bf2f(u16 h) {
  union { u32 u; float f; } x; x.u = ((u32)h) << 16;
  return x.f;
}

// async global->LDS 16B/lane; LDS dest is wave-uniform base + lane*16.
__device__ __forceinline__ void gl_lds16(const void* g, void* l, int lane) {
#if __has_builtin(__builtin_amdgcn_global_load_lds)
  __builtin_amdgcn_global_load_lds((const __attribute__((address_space(1))) u32*)g,
                                   (__attribute__((address_space(3))) u32*)l, 16, 0, 0);
#else
  *(uint4*)((char*)l + lane * 16) = *(const uint4*)g;
#endif
}

// ---------------------------------------------------------------------------
__global__ void k_compute_e(const float* __restrict__ node_emb,
                            const float* __restrict__ time_emb,
                            const float* __restrict__ g_lng, const float* __restrict__ g_lnb,
                            const float* __restrict__ u_lng, const float* __restrict__ u_lnb,
                            int t,
                            float* __restrict__ eg, float* __restrict__ egT,
                            float* __restrict__ eu, float* __restrict__ euT) {
  int n = blockIdx.x * blockDim.x + threadIdx.x;
  if (n >= N_) return;
  float v[E_];
  float m = 0.f;
#pragma unroll
  for (int d = 0; d < E_; d++) { v[d] = node_emb[n * E_ + d] + time_emb[t * E_ + d]; m += v[d]; }
  m *= (1.0f / E_);
  float var = 0.f;
#pragma unroll
  for (int d = 0; d < E_; d++) { float x = v[d] - m; var += x * x; }
  var *= (1.0f / E_);
  float rs = rsqrtf(var + EPS_);
#pragma unroll
  for (int d = 0; d < E_; d++) {
    float nv = (v[d] - m) * rs;
    float g = nv * g_lng[d] + g_lnb[d];
    float u = nv * u_lng[d] + u_lnb[d];
    eg[n * E_ + d] = g; egT[d * N_ + n] = g;
    eu[n * E_ + d] = u; euT[d * N_ + n] = u;
  }
}

// ---------------------------------------------------------------------------
// sup row softmax; emits bf16 hi/lo split directly (only the GEMM consumes sup).
__global__ __launch_bounds__(256) void k_sup(const float* __restrict__ eT,
                                             u16* __restrict__ s_hi,
                                             u16* __restrict__ s_lo) {
  const int n = blockIdx.x;
  const int tid = threadIdx.x;
  __shared__ float red[256];
  float en[E_];
#pragma unroll
  for (int d = 0; d < E_; d++) en[d] = eT[d * N_ + n];
  float lg[4];
  float mx = -3.4e38f;
#pragma unroll
  for (int j = 0; j < 4; j++) {
    int m = tid + 256 * j;
    float s = 0.f;
#pragma unroll
    for (int d = 0; d < E_; d++) s = fmaf(en[d], eT[d * N_ + m], s);
    lg[j] = s;
    mx = fmaxf(mx, s);
  }
  red[tid] = mx; __syncthreads();
  for (int off = 128; off > 0; off >>= 1) {
    if (tid < off) red[tid] = fmaxf(red[tid], red[tid + off]);
    __syncthreads();
  }
  mx = red[0]; __syncthreads();
  float sum = 0.f;
#pragma unroll
  for (int j = 0; j < 4; j++) { lg[j] = __expf(lg[j] - mx); sum += lg[j]; }
  red[tid] = sum; __syncthreads();
  for (int off = 128; off > 0; off >>= 1) {
    if (tid < off) red[tid] += red[tid + off];
    __syncthreads();
  }
  float inv = 1.0f / red[0];
#pragma unroll
  for (int j = 0; j < 4; j++) {
    float v = lg[j] * inv;
    u16 hb = f2bf(v);
    u16 lb = f2bf(v - bf2f(hb));
    size_t o = (size_t)n * N_ + tid + 256 * j;
    s_hi[o] = hb;
    s_lo[o] = lb;
  }
}

// ---------------------------------------------------------------------------
__global__ void k_build_x_gate(const float* __restrict__ src, const float* __restrict__ h,
                               int t, float* __restrict__ X) {
  int idx = blockIdx.x * 256 + threadIdx.x;
  if (idx >= N_ * BC_) return;
  int m = idx / BC_;
  int j = idx - m * BC_;
  int b = j / C_;
  int c = j - b * C_;
  X[idx] = (c == 0) ? src[((size_t)b * T_ + t) * N_ + m]
                    : h[((size_t)b * N_ + m) * H_ + (c - 1)];
}

__global__ void k_build_x_upd(const float* __restrict__ src, const float* __restrict__ h,
                              const float* __restrict__ z, int t, float* __restrict__ X) {
  int idx = blockIdx.x * 256 + threadIdx.x;
  if (idx >= N_ * BC_) return;
  int m = idx / BC_;
  int j = idx - m * BC_;
  int b = j / C_;
  int c = j - b * C_;
  if (c == 0) X[idx] = src[((size_t)b * T_ + t) * N_ + m];
  else {
    size_t hi = ((size_t)b * N_ + m) * H_ + (c - 1);
    X[idx] = z[hi] * h[hi];
  }
}

// ---------------------------------------------------------------------------
// X fp32 [1024 m][4160 col] -> transposed bf16 hi/lo [col][m] (K-contiguous B operand).
__global__ __launch_bounds__(256) void k_xpose(const float* __restrict__ Xf,
                                               u16* __restrict__ t_hi,
                                               u16* __restrict__ t_lo) {
  __shared__ float tile[64][65];
  const int c0 = blockIdx.x * 64;   // 65 blocks -> cols 0..4159
  const int m0 = blockIdx.y * 64;   // 16 blocks
  const int tid = threadIdx.x;
  {
    const int ci = tid & 63, mi = tid >> 6;
#pragma unroll
    for (int p = 0; p < 16; p++) {
      int m = p * 4 + mi;
      tile[m][ci] = Xf[(size_t)(m0 + m) * BC_ + c0 + ci];
    }
  }
  __syncthreads();
  {
    const int mj = tid & 63, cj = tid >> 6;
#pragma unroll
    for (int p = 0; p < 16; p++) {
      int c = p * 4 + cj;
      float v = tile[mj][c];
      u16 hb = f2bf(v);
      u16 lb = f2bf(v - bf2f(hb));
      size_t o = (size_t)(c0 + c) * 1024 + m0 + mj;
      t_hi[o] = hb;
      t_lo[o] = lb;
    }
  }
}

// ---------------------------------------------------------------------------
// Split-precision MFMA GEMM: C[1024 x 4160(4224)] = A[1024x1024] * B[1024 x cols].
// A = sup (hi/lo bf16, [n][k] row-major). B given transposed: [col][k] bf16 hi/lo.
// Stacked K = 3*1024: hi*hi + hi*lo + lo*hi (fp32-equivalent accuracy).
// Epilogue: y fp32 [row][4160]; optional transposed bf16 hi/lo [col][row] for chaining.
__global__ __launch_bounds__(256) void k_gemm_mfma(
    const u16* __restrict__ a_hi, const u16* __restrict__ a_lo,
    const u16* __restrict__ b_hi, const u16* __restrict__ b_lo,
    float* __restrict__ y, u16* __restrict__ yt_hi, u16* __restrict__ yt_lo) {
  __shared__ u16 As[128 * 32];
  __shared__ u16 Bs[128 * 32];
  const int tid  = threadIdx.x;
  const int wave = tid >> 6, lane = tid & 63;
  const int wm = wave >> 1, wn = wave & 1;
  const int m0 = blockIdx.y * 128, c0 = blockIdx.x * 128;
  const int srow = tid >> 2;            // 0..63: tile row staged by this thread
  const int soff = (tid & 3) * 8;       // u16 offset within 32-elem tile row
  u16* AsW0 = &As[(wave * 16) * 32];
  u16* AsW1 = &As[(64 + wave * 16) * 32];
  u16* BsW0 = &Bs[(wave * 16) * 32];
  u16* BsW1 = &Bs[(64 + wave * 16) * 32];
  const int fm = lane & 15, fq = lane >> 4;
  f32x4 acc[4][4] = {};
  for (int ks = 0; ks < 96; ks++) {
    const int phase = ks >> 5;          // 0: hi*hi, 1: hi*lo, 2: lo*hi
    const int kp = (ks & 31) * 32;      // physical k offset
    const u16* Ag = (phase < 2) ? a_hi : a_lo;
    const u16* Bg = (phase == 1) ? b_lo : b_hi;
    gl_lds16(Ag + (size_t)(m0 + srow) * 1024 + kp + soff,      AsW0, lane);
    gl_lds16(Ag + (size_t)(m0 + 64 + srow) * 1024 + kp + soff, AsW1, lane);
    gl_lds16(Bg + (size_t)(c0 + srow) * 1024 + kp + soff,      BsW0, lane);
    gl_lds16(Bg + (size_t)(c0 + 64 + srow) * 1024 + kp + soff, BsW1, lane);
    __syncthreads();
    bf16x8 af[4], bfr[4];
#pragma unroll
    for (int tm = 0; tm < 4; tm++)
      af[tm] = *(const bf16x8*)&As[(wm * 64 + tm * 16 + fm) * 32 + fq * 8];
#pragma unroll
    for (int tn = 0; tn < 4; tn++)
      bfr[tn] = *(const bf16x8*)&Bs[(wn * 64 + tn * 16 + fm) * 32 + fq * 8];
#pragma unroll
    for (int tm = 0; tm < 4; tm++)
#pragma unroll
      for (int tn = 0; tn < 4; tn++)
        acc[tm][tn] = __builtin_amdgcn_mfma_f32_16x16x32_bf16(af[tm], bfr[tn], acc[tm][tn], 0, 0, 0);
    __syncthreads();
  }
  const int q4 = fq * 4;
#pragma unroll
  for (int tn = 0; tn < 4; tn++) {
    const int col = c0 + wn * 64 + tn * 16 + fm;
    if (col >= BC_) continue;           // uniform per 16-col tile
#pragma unroll
    for (int tm = 0; tm < 4; tm++) {
      const int row = m0 + wm * 64 + tm * 16 + q4;
      const f32x4 v = acc[tm][tn];
      y[(size_t)(row + 0) * BC_ + col] = v[0];
      y[(size_t)(row + 1) * BC_ + col] = v[1];
      y[(size_t)(row + 2) * BC_ + col] = v[2];
      y[(size_t)(row + 3) * BC_ + col] = v[3];
      if (yt_hi) {
        unsigned long long ph = 0, pl = 0;
#pragma unroll
        for (int j = 0; j < 4; j++) {
          float vv = v[j];
          u16 hb = f2bf(vv);
          u16 lb = f2bf(vv - bf2f(hb));
          ph |= ((unsigned long long)hb) << (16 * j);
          pl |= ((unsigned long long)lb) << (16 * j);
        }
        *(unsigned long long*)&yt_hi[(size_t)col * 1024 + row] = ph;
        *(unsigned long long*)&yt_lo[(size_t)col * 1024 + row] = pl;
      }
    }
  }
}

// ---------------------------------------------------------------------------
__global__ __launch_bounds__(256) void k_gate_contract(
    const float* __restrict__ eg,
    const float* __restrict__ X, const float* __restrict__ y1, const float* __restrict__ y2,
    const float* __restrict__ wp, const float* __restrict__ bp,
    float* __restrict__ z, float* __restrict__ r) {
  const int n = blockIdx.x;
  const int tid = threadIdx.x;
  __shared__ float es[E_];
  __shared__ float Ws[16][OG_];
  __shared__ float xs[64][16];
  if (tid < E_) es[tid] = eg[n * E_ + tid];
  const int og = tid & 31;
  const int bg = tid >> 5;
  float acc[8][4] = {};
  for (int k = 0; k < K_; k++) {
    for (int i0 = 0; i0 < C_; i0 += 16) {
      const int iv = (C_ - i0 < 16) ? (C_ - i0) : 16;
      __syncthreads();
#pragma unroll
      for (int q = 0; q < 8; q++) {
        int idx = tid + q * 256;
        int ii = idx >> 7, o = idx & 127;
        float w = 0.f;
        if (ii < iv) {
#pragma unroll
          for (int d = 0; d < E_; d++)
            w = fmaf(es[d], wp[(((size_t)d * K_ + k) * C_ + i0 + ii) * OG_ + o], w);
        }
        Ws[ii][o] = w;
      }
#pragma unroll
      for (int q = 0; q < 4; q++) {
        int idx = tid + q * 256;
        int b = idx >> 4, ii = idx & 15;
        float v = 0.f;
        if (ii < iv) {
          size_t a = (size_t)n * BC_ + (size_t)b * C_ + i0 + ii;
          if (k == 0)      v = X[a];
          else if (k == 1) v = y1[a];
          else             v = 2.0f * y2[a] - X[a];
        }
        xs[b][ii] = v;
      }
      __syncthreads();
#pragma unroll
      for (int ii = 0; ii < 16; ii++) {
        float4 wv = *(const float4*)&Ws[ii][og * 4];
#pragma unroll
        for (int bb = 0; bb < 8; bb++) {
          float xv = xs[bg * 8 + bb][ii];
          acc[bb][0] = fmaf(xv, wv.x, acc[bb][0]);
          acc[bb][1] = fmaf(xv, wv.y, acc[bb][1]);
          acc[bb][2] = fmaf(xv, wv.z, acc[bb][2]);
          acc[bb][3] = fmaf(xv, wv.w, acc[bb][3]);
        }
      }
    }
  }
#pragma unroll
  for (int oo = 0; oo < 4; oo++) {
    int o = og * 4 + oo;
    float bias = 0.f;
#pragma unroll
    for (int d = 0; d < E_; d++) bias = fmaf(es[d], bp[d * OG_ + o], bias);
#pragma unroll
    for (int bb = 0; bb < 8; bb++) {
      int b = bg * 8 + bb;
      float v = acc[bb][oo] + bias;
      float s = 1.0f / (1.0f + __expf(-v));
      size_t oidx = ((size_t)b * N_ + n) * H_;
      if (o < H_) z[oidx + o] = s;
      else        r[oidx + (o - H_)] = s;
    }
  }
}

// ---------------------------------------------------------------------------
__global__ __launch_bounds__(256) void k_upd_contract(
    const float* __restrict__ eu,
    const float* __restrict__ X, const float* __restrict__ y1, const float* __restrict__ y2,
    const float* __restrict__ wp, const float* __restrict__ bp,
    const float* __restrict__ r,
    float* __restrict__ h) {
  const int n = blockIdx.x;
  const int tid = threadIdx.x;
  __shared__ float es[E_];
  __shared__ float Ws[16][OU_];
  __shared__ float xs[64][16];
  if (tid < E_) es[tid] = eu[n * E_ + tid];
  const int og = tid & 15;
  const int bg = tid >> 4;
  float acc[4][4] = {};
  for (int k = 0; k < K_; k++) {
    for (int i0 = 0; i0 < C_; i0 += 16) {
      const int iv = (C_ - i0 < 16) ? (C_ - i0) : 16;
      __syncthreads();
#pragma unroll
      for (int q = 0; q < 4; q++) {
        int idx = tid + q * 256;
        int ii = idx >> 6, o = idx & 63;
        float w = 0.f;
        if (ii < iv) {
#pragma unroll
          for (int d = 0; d < E_; d++)
            w = fmaf(es[d], wp[(((size_t)d * K_ + k) * C_ + i0 + ii) * OU_ + o], w);
        }
        Ws[ii][o] = w;
      }
#pragma unroll
      for (int q = 0; q < 4; q++) {
        int idx = tid + q * 256;
        int b = idx >> 4, ii = idx & 15;
        float v = 0.f;
        if (ii < iv) {
          size_t a = (size_t)n * BC_ + (size_t)b * C_ + i0 + ii;
          if (k == 0)      v = X[a];
          else if (k == 1) v = y1[a];
          else             v = 2.0f * y2[a] - X[a];
        }
        xs[b][ii] = v;
      }
      __syncthreads();
#pragma unroll
      for (int ii = 0; ii < 16; ii++) {
        float4 wv = *(const float4*)&Ws[ii][og * 4];
#pragma unroll
        for (int bb = 0; bb < 4; bb++) {
          float xv = xs[bg * 4 + bb][ii];
          acc[bb][0] = fmaf(xv, wv.x, acc[bb][0]);
          acc[bb][1] = fmaf(xv, wv.y, acc[bb][1]);
          acc[bb][2] = fmaf(xv, wv.z, acc[bb][2]);
          acc[bb][3] = fmaf(xv, wv.w, acc[bb][3]);
        }
      }
    }
  }
#pragma unroll
  for (int oo = 0; oo < 4; oo++) {
    int o = og * 4 + oo;
    float bias = 0.f;
#pragma unroll
    for (int d = 0; d < E_; d++) bias = fmaf(es[d], bp[d * OU_ + o], bias);
#pragma unroll
    for (int bb = 0; bb < 4; bb++) {
      int b = bg * 4 + bb;
      size_t hi = ((size_t)b * N_ + n) * H_ + o;
      float hc = tanhf(acc[bb][oo] + bias);
      float rv = r[hi];
      h[hi] = rv * h[hi] + (1.0f - rv) * hc;
    }
  }
}

// ---------------------------------------------------------------------------
__global__ __launch_bounds__(64) void k_final(const float* __restrict__ h,
                                              const float* __restrict__ out_lng,
                                              const float* __restrict__ out_lnb,
                                              const float* __restrict__ conv_w,
                                              const float* __restrict__ conv_b,
                                              float* __restrict__ out) {
  const int bn = blockIdx.x;
  const int b = bn >> 10;
  const int n = bn & 1023;
  const int tid = threadIdx.x;
  float v = h[(size_t)bn * H_ + tid];
  float s = v;
  for (int off = 32; off > 0; off >>= 1) s += __shfl_down(s, off);
  s = __shfl(s, 0);
  float mean = s * (1.0f / H_);
  float d = v - mean;
  float vs = d * d;
  for (int off = 32; off > 0; off >>= 1) vs += __shfl_down(vs, off);
  vs = __shfl(vs, 0);
  float var = vs * (1.0f / H_);
  float y = d * rsqrtf(var + EPS_) * out_lng[tid] + out_lnb[tid];
  __shared__ float ys[64];
  ys[tid] = y;
  __syncthreads();
  if (tid < 12) {
    float accv = conv_b[tid];
#pragma unroll
    for (int hh = 0; hh < H_; hh++) accv = fmaf(ys[hh], conv_w[tid * H_ + hh], accv);
    out[((size_t)b * 12 + tid) * N_ + n] = accv;
  }
}

// ---------------------------------------------------------------------------
extern "C" void kernel_launch(void* const* d_in, const int* in_sizes, int n_in,
                              void* d_out, int out_size, void* d_ws, size_t ws_size,
                              hipStream_t stream) {
  const float* src      = (const float*)d_in[0];
  const float* node_emb = (const float*)d_in[1];
  const float* time_emb = (const float*)d_in[2];
  const float* gate_wp  = (const float*)d_in[3];
  const float* gate_bp  = (const float*)d_in[4];
  const float* gate_lng = (const float*)d_in[5];
  const float* gate_lnb = (const float*)d_in[6];
  const float* upd_wp   = (const float*)d_in[7];
  const float* upd_bp   = (const float*)d_in[8];
  const float* upd_lng  = (const float*)d_in[9];
  const float* upd_lnb  = (const float*)d_in[10];
  const float* out_lng  = (const float*)d_in[11];
  const float* out_lnb  = (const float*)d_in[12];
  const float* conv_w   = (const float*)d_in[13];
  const float* conv_b   = (const float*)d_in[14];
  float* out = (float*)d_out;

  constexpr size_t SZ_H = (size_t)B_ * N_ * H_;      // 4,194,304 floats
  constexpr size_t SZ_X = (size_t)N_ * BC_;          // 4,259,840 floats
  constexpr size_t TC   = (size_t)NP_ * 1024 / 2;    // 2,162,688 float-slots per bf16 mat

  float* ws = (float*)d_ws;
  size_t off = 0;
  float* h    = ws + off; off += SZ_H;
  float* zbuf = ws + off; off += 2 * TC;   // z fp32 (<= 2*TC) OR y1t hi/lo — disjoint lifetimes
  float* r    = ws + off; off += SZ_H;
  float* X    = ws + off; off += SZ_X;
  float* y1   = ws + off; off += SZ_X;
  float* y2b  = ws + off; off += 2 * TC;   // y2 fp32 (<= 2*TC) OR Xt hi/lo — disjoint lifetimes
  float* sup_hi_f = ws + off; off += (size_t)N_ * N_ / 2;
  float* sup_lo_f = ws + off; off += (size_t)N_ * N_ / 2;
  float* eg  = ws + off; off += N_ * E_;
  float* egT = ws + off; off += N_ * E_;
  float* eu  = ws + off; off += N_ * E_;
  float* euT = ws + off; off += N_ * E_;
  if (ws_size < off * sizeof(float)) return;

  float* z  = zbuf;
  float* y2 = y2b;
  u16* y1t_hi = (u16*)zbuf;
  u16* y1t_lo = (u16*)(zbuf + TC);
  u16* Xt_hi  = (u16*)y2b;
  u16* Xt_lo  = (u16*)(y2b + TC);
  u16* sup_hi = (u16*)sup_hi_f;
  u16* sup_lo = (u16*)sup_lo_f;

  hipMemsetAsync(h, 0, SZ_H * sizeof(float), stream);

  const int xblocks = (N_ * BC_ + 255) / 256;
  dim3 ggrid(NP_ / 128, N_ / 128);     // (33, 8)
  dim3 xgrid(BC_ / 64, N_ / 64);       // (65, 16)

  for (int t = 0; t < T_; t++) {
    k_compute_e<<<4, 256, 0, stream>>>(node_emb, time_emb, gate_lng, gate_lnb,
                                       upd_lng, upd_lnb, t, eg, egT, eu, euT);
    // ---- gate dagcn ----
    k_sup<<<N_, 256, 0, stream>>>(egT, sup_hi, sup_lo);
    k_build_x_gate<<<xblocks, 256, 0, stream>>>(src, h, t, X);
    k_xpose<<<xgrid, 256, 0, stream>>>(X, Xt_hi, Xt_lo);
    k_gemm_mfma<<<ggrid, 256, 0, stream>>>(sup_hi, sup_lo, Xt_hi, Xt_lo, y1, y1t_hi, y1t_lo);
    k_gemm_mfma<<<ggrid, 256, 0, stream>>>(sup_hi, sup_lo, y1t_hi, y1t_lo, y2, nullptr, nullptr);
    k_gate_contract<<<N_, 256, 0, stream>>>(eg, X, y1, y2, gate_wp, gate_bp, z, r);
    // ---- update dagcn ----
    k_sup<<<N_, 256, 0, stream>>>(euT, sup_hi, sup_lo);
    k_build_x_upd<<<xblocks, 256, 0, stream>>>(src, h, z, t, X);
    k_xpose<<<xgrid, 256, 0, stream>>>(X, Xt_hi, Xt_lo);
    k_gemm_mfma<<<ggrid, 256, 0, stream>>>(sup_hi, sup_lo, Xt_hi, Xt_lo, y1, y1t_hi, y1t_lo);
    k_gemm_mfma<<<ggrid, 256, 0, stream>>>(sup_hi, sup_lo, y1t_hi, y1t_lo, y2, nullptr, nullptr);
    k_upd_contract<<<N_, 256, 0, stream>>>(eu, X, y1, y2, upd_wp, upd_bp, r, h);
  }
  k_final<<<B_ * N_, 64, 0, stream>>>(h, out_lng, out_lnb, conv_w, conv_b, out);
}

// Round 3
// 6281.267 us; speedup vs baseline: 1.8771x; 1.2646x over previous
//
#include <hip/hip_runtime.h>
#include <math.h>

namespace {
constexpr int B_ = 64, T_ = 12, N_ = 1024, H_ = 64, E_ = 16;
constexpr int C_  = 65;          // DIN + H
constexpr int BC_ = B_ * C_;     // 4160
constexpr int OG_ = 128;         // gate output = 2H
constexpr int OU_ = 64;          // update output = H
constexpr float EPS_ = 1e-12f;
constexpr int NP_ = 4224;        // BC_ padded to 128 for GEMM N-tiling
}

typedef unsigned short u16;
typedef unsigned int u32;
using f16x8 = __attribute__((ext_vector_type(8))) _Float16;
using f16x4 = __attribute__((ext_vector_type(4))) _Float16;
using f32x4 = __attribute__((ext_vector_type(4))) float;

// async global->LDS 16B/lane; LDS dest is wave-uniform base + lane*16.
__device__ __forceinline__ void gl_lds16(const void* g, void* l, int lane) {
#if __has_builtin(__builtin_amdgcn_global_load_lds)
  __builtin_amdgcn_global_load_lds((const __attribute__((address_space(1))) u32*)g,
                                   (__attribute__((address_space(3))) u32*)l, 16, 0, 0);
#else
  *(uint4*)((char*)l + lane * 16) = *(const uint4*)g;
#endif
}

// ---------------------------------------------------------------------------
__global__ void k_compute_e(const float* __restrict__ node_emb,
                            const float* __restrict__ time_emb,
                            const float* __restrict__ g_lng, const float* __restrict__ g_lnb,
                            const float* __restrict__ u_lng, const float* __restrict__ u_lnb,
                            int t,
                            float* __restrict__ eg, float* __restrict__ egT,
                            float* __restrict__ eu, float* __restrict__ euT) {
  int n = blockIdx.x * blockDim.x + threadIdx.x;
  if (n >= N_) return;
  float v[E_];
  float m = 0.f;
#pragma unroll
  for (int d = 0; d < E_; d++) { v[d] = node_emb[n * E_ + d] + time_emb[t * E_ + d]; m += v[d]; }
  m *= (1.0f / E_);
  float var = 0.f;
#pragma unroll
  for (int d = 0; d < E_; d++) { float x = v[d] - m; var += x * x; }
  var *= (1.0f / E_);
  float rs = rsqrtf(var + EPS_);
#pragma unroll
  for (int d = 0; d < E_; d++) {
    float nv = (v[d] - m) * rs;
    float g = nv * g_lng[d] + g_lnb[d];
    float u = nv * u_lng[d] + u_lnb[d];
    eg[n * E_ + d] = g; egT[d * N_ + n] = g;
    eu[n * E_ + d] = u; euT[d * N_ + n] = u;
  }
}

// ---------------------------------------------------------------------------
// sup[n,:] = softmax over m of e[n]·e[m]; emits fp16 (A-operand, row-major).
__global__ __launch_bounds__(256) void k_sup(const float* __restrict__ eT,
                                             _Float16* __restrict__ s16) {
  const int n = blockIdx.x;
  const int tid = threadIdx.x;
  __shared__ float red[256];
  float en[E_];
#pragma unroll
  for (int d = 0; d < E_; d++) en[d] = eT[d * N_ + n];
  float lg[4];
  float mx = -3.4e38f;
#pragma unroll
  for (int j = 0; j < 4; j++) {
    int m = tid + 256 * j;
    float s = 0.f;
#pragma unroll
    for (int d = 0; d < E_; d++) s = fmaf(en[d], eT[d * N_ + m], s);
    lg[j] = s;
    mx = fmaxf(mx, s);
  }
  red[tid] = mx; __syncthreads();
  for (int off = 128; off > 0; off >>= 1) {
    if (tid < off) red[tid] = fmaxf(red[tid], red[tid + off]);
    __syncthreads();
  }
  mx = red[0]; __syncthreads();
  float sum = 0.f;
#pragma unroll
  for (int j = 0; j < 4; j++) { lg[j] = __expf(lg[j] - mx); sum += lg[j]; }
  red[tid] = sum; __syncthreads();
  for (int off = 128; off > 0; off >>= 1) {
    if (tid < off) red[tid] += red[tid + off];
    __syncthreads();
  }
  float inv = 1.0f / red[0];
#pragma unroll
  for (int j = 0; j < 4; j++)
    s16[(size_t)n * N_ + tid + 256 * j] = (_Float16)(lg[j] * inv);
}

// ---------------------------------------------------------------------------
// Fused build + transpose: emits Xt fp16 [bc][m] (GEMM B-operand) and
// Xrow fp16 [m][bc] (contract A source). One block per (b, m-tile of 64).
__global__ __launch_bounds__(256) void k_build_gate(const float* __restrict__ src,
                                                    const float* __restrict__ h, int t,
                                                    _Float16* __restrict__ Xt,
                                                    _Float16* __restrict__ Xrow) {
  __shared__ float tile[64][65];
  const int b = blockIdx.x;
  const int m0 = blockIdx.y * 64;
  const int tid = threadIdx.x;
  {
    const int c = tid & 63, mi = tid >> 6;
#pragma unroll
    for (int p = 0; p < 16; p++) {
      int m = p * 4 + mi;
      tile[m][c + 1] = h[((size_t)b * N_ + m0 + m) * H_ + c];
    }
    if (tid < 64) tile[tid][0] = src[((size_t)b * T_ + t) * N_ + m0 + tid];
  }
  __syncthreads();
  for (int q = 0; q < 17; q++) {
    int idx = tid + q * 256;
    if (idx < 64 * 65) {
      int c = idx >> 6, m = idx & 63;
      Xt[((size_t)(b * C_ + c)) * 1024 + m0 + m] = (_Float16)tile[m][c];
      int mm = idx / 65, cc = idx - mm * 65;
      Xrow[((size_t)(m0 + mm)) * BC_ + b * C_ + cc] = (_Float16)tile[mm][cc];
    }
  }
}

__global__ __launch_bounds__(256) void k_build_upd(const float* __restrict__ src,
                                                   const float* __restrict__ h,
                                                   const float* __restrict__ z, int t,
                                                   _Float16* __restrict__ Xt,
                                                   _Float16* __restrict__ Xrow) {
  __shared__ float tile[64][65];
  const int b = blockIdx.x;
  const int m0 = blockIdx.y * 64;
  const int tid = threadIdx.x;
  {
    const int c = tid & 63, mi = tid >> 6;
#pragma unroll
    for (int p = 0; p < 16; p++) {
      int m = p * 4 + mi;
      size_t a = ((size_t)b * N_ + m0 + m) * H_ + c;
      tile[m][c + 1] = z[a] * h[a];
    }
    if (tid < 64) tile[tid][0] = src[((size_t)b * T_ + t) * N_ + m0 + tid];
  }
  __syncthreads();
  for (int q = 0; q < 17; q++) {
    int idx = tid + q * 256;
    if (idx < 64 * 65) {
      int c = idx >> 6, m = idx & 63;
      Xt[((size_t)(b * C_ + c)) * 1024 + m0 + m] = (_Float16)tile[m][c];
      int mm = idx / 65, cc = idx - mm * 65;
      Xrow[((size_t)(m0 + mm)) * BC_ + b * C_ + cc] = (_Float16)tile[mm][cc];
    }
  }
}

// ---------------------------------------------------------------------------
// fp16 single-pass MFMA GEMM: C[1024 x 4160(4224)] = A[1024x1024] @ B.
// A = sup fp16 [n][m] row-major; B = Xt fp16 [col][m] (K-contiguous).
// Epilogue: yt fp16 [col][row] (next GEMM's B), yrow fp16 [row][col] (contract).
__global__ __launch_bounds__(256) void k_gemm_f16(
    const _Float16* __restrict__ A, const _Float16* __restrict__ Bt,
    _Float16* __restrict__ yt, _Float16* __restrict__ yrow) {
  __shared__ _Float16 As[128 * 32];
  __shared__ _Float16 Bs[128 * 32];
  const int tid  = threadIdx.x;
  const int wave = tid >> 6, lane = tid & 63;
  const int wm = wave >> 1, wn = wave & 1;
  const int m0 = blockIdx.y * 128, c0 = blockIdx.x * 128;
  const int srow = tid >> 2;
  const int soff = (tid & 3) * 8;
  _Float16* AsW0 = &As[(wave * 16) * 32];
  _Float16* AsW1 = &As[(64 + wave * 16) * 32];
  _Float16* BsW0 = &Bs[(wave * 16) * 32];
  _Float16* BsW1 = &Bs[(64 + wave * 16) * 32];
  const int fm = lane & 15, fq = lane >> 4;
  f32x4 acc[4][4] = {};
  for (int ks = 0; ks < 32; ks++) {
    const int kp = ks * 32;
    gl_lds16(A  + (size_t)(m0 + srow) * 1024 + kp + soff,      AsW0, lane);
    gl_lds16(A  + (size_t)(m0 + 64 + srow) * 1024 + kp + soff, AsW1, lane);
    gl_lds16(Bt + (size_t)(c0 + srow) * 1024 + kp + soff,      BsW0, lane);
    gl_lds16(Bt + (size_t)(c0 + 64 + srow) * 1024 + kp + soff, BsW1, lane);
    __syncthreads();
    f16x8 af[4], bfr[4];
#pragma unroll
    for (int tm = 0; tm < 4; tm++)
      af[tm] = *(const f16x8*)&As[(wm * 64 + tm * 16 + fm) * 32 + fq * 8];
#pragma unroll
    for (int tn = 0; tn < 4; tn++)
      bfr[tn] = *(const f16x8*)&Bs[(wn * 64 + tn * 16 + fm) * 32 + fq * 8];
#pragma unroll
    for (int tm = 0; tm < 4; tm++)
#pragma unroll
      for (int tn = 0; tn < 4; tn++)
        acc[tm][tn] = __builtin_amdgcn_mfma_f32_16x16x32_f16(af[tm], bfr[tn], acc[tm][tn], 0, 0, 0);
    __syncthreads();
  }
  const int q4 = fq * 4;
#pragma unroll
  for (int tn = 0; tn < 4; tn++) {
    const int col = c0 + wn * 64 + tn * 16 + fm;
    if (col >= BC_) continue;
#pragma unroll
    for (int tm = 0; tm < 4; tm++) {
      const int row = m0 + wm * 64 + tm * 16 + q4;
      const f32x4 v = acc[tm][tn];
#pragma unroll
      for (int j = 0; j < 4; j++)
        yrow[(size_t)(row + j) * BC_ + col] = (_Float16)v[j];
      if (yt) {
        f16x4 pv;
#pragma unroll
        for (int j = 0; j < 4; j++) pv[j] = (_Float16)v[j];
        *(f16x4*)&yt[(size_t)col * 1024 + row] = pv;
      }
    }
  }
}

// ---------------------------------------------------------------------------
// Gate contraction via MFMA. Per node n: out[b,o] = sum_seg sum_k XG[b,k]·W[k,o].
// W[seg][k][o] = sum_d e[n,d]·wp[d,seg,k,o] computed on VALU into LDS (transposed
// to [o][k] for the B-operand). K per segment = 65, padded to 96 (3 MFMA k-steps).
__global__ __launch_bounds__(256) void k_gate_contract(
    const float* __restrict__ eg,
    const _Float16* __restrict__ X16, const _Float16* __restrict__ y116,
    const _Float16* __restrict__ y216,
    const float* __restrict__ wp, const float* __restrict__ bp,
    float* __restrict__ z, float* __restrict__ r) {
  const int n = blockIdx.x;
  const int tid = threadIdx.x;
  const int wave = tid >> 6, lane = tid & 63;
  const int fm = lane & 15, fq = lane >> 4;
  __shared__ float es[E_];
  __shared__ _Float16 Wls[OG_][104];   // [o][k], stride 104 f16 = 208B (16B-aligned rows)
  __shared__ _Float16 XGls[64][104];   // [b][k]
  if (tid < E_) es[tid] = eg[n * E_ + tid];
  const int ow = tid & 127, pw = tid >> 7;
  f32x4 acc[4][2] = {};
  for (int seg = 0; seg < 3; seg++) {
    __syncthreads();
    // ---- W tile (VALU): rows ii = pw + 2q ----
    for (int q = 0; q < 48; q++) {
      int ii = pw + 2 * q;
      float w = 0.f;
      if (ii < C_) {
        const float* wpp = wp + ((size_t)seg * C_ + ii) * OG_ + ow;
#pragma unroll
        for (int d = 0; d < E_; d++) w = fmaf(es[d], wpp[(size_t)d * (3 * C_ * OG_)], w);
      }
      Wls[ow][ii] = (_Float16)w;
    }
    // ---- XG tile ----
    for (int q = 0; q < 24; q++) {
      int idx = tid + q * 256;
      int b = idx / 96, k = idx - b * 96;
      _Float16 v = (_Float16)0.f;
      if (k < C_) {
        size_t a = (size_t)n * BC_ + b * C_ + k;
        if (seg == 0)      v = X16[a];
        else if (seg == 1) v = y116[a];
        else               v = (_Float16)(2.f * (float)y216[a] - (float)X16[a]);
      }
      XGls[b][k] = v;
    }
    __syncthreads();
#pragma unroll
    for (int kk = 0; kk < 3; kk++) {
      f16x8 af[4], bfr[2];
#pragma unroll
      for (int mt = 0; mt < 4; mt++)
        af[mt] = *(const f16x8*)&XGls[mt * 16 + fm][kk * 32 + fq * 8];
#pragma unroll
      for (int nt = 0; nt < 2; nt++)
        bfr[nt] = *(const f16x8*)&Wls[wave * 32 + nt * 16 + fm][kk * 32 + fq * 8];
#pragma unroll
      for (int mt = 0; mt < 4; mt++)
#pragma unroll
        for (int nt = 0; nt < 2; nt++)
          acc[mt][nt] = __builtin_amdgcn_mfma_f32_16x16x32_f16(af[mt], bfr[nt], acc[mt][nt], 0, 0, 0);
    }
  }
#pragma unroll
  for (int nt = 0; nt < 2; nt++) {
    const int o = wave * 32 + nt * 16 + fm;
    float bias = 0.f;
#pragma unroll
    for (int d = 0; d < E_; d++) bias = fmaf(es[d], bp[d * OG_ + o], bias);
#pragma unroll
    for (int mt = 0; mt < 4; mt++) {
      const f32x4 v = acc[mt][nt];
#pragma unroll
      for (int j = 0; j < 4; j++) {
        int b = mt * 16 + fq * 4 + j;
        float s = 1.0f / (1.0f + __expf(-(v[j] + bias)));
        size_t oidx = ((size_t)b * N_ + n) * H_;
        if (o < H_) z[oidx + o] = s;
        else        r[oidx + (o - H_)] = s;
      }
    }
  }
}

// ---------------------------------------------------------------------------
// Update contraction via MFMA + GRU state update.
__global__ __launch_bounds__(256) void k_upd_contract(
    const float* __restrict__ eu,
    const _Float16* __restrict__ X16, const _Float16* __restrict__ y116,
    const _Float16* __restrict__ y216,
    const float* __restrict__ wp, const float* __restrict__ bp,
    const float* __restrict__ r,
    float* __restrict__ h) {
  const int n = blockIdx.x;
  const int tid = threadIdx.x;
  const int wave = tid >> 6, lane = tid & 63;
  const int fm = lane & 15, fq = lane >> 4;
  __shared__ float es[E_];
  __shared__ _Float16 Wls[OU_][104];
  __shared__ _Float16 XGls[64][104];
  if (tid < E_) es[tid] = eu[n * E_ + tid];
  const int ow = tid & 63, pw = tid >> 6;
  f32x4 acc[4] = {};
  for (int seg = 0; seg < 3; seg++) {
    __syncthreads();
    for (int q = 0; q < 24; q++) {
      int ii = pw + 4 * q;
      float w = 0.f;
      if (ii < C_) {
        const float* wpp = wp + ((size_t)seg * C_ + ii) * OU_ + ow;
#pragma unroll
        for (int d = 0; d < E_; d++) w = fmaf(es[d], wpp[(size_t)d * (3 * C_ * OU_)], w);
      }
      Wls[ow][ii] = (_Float16)w;
    }
    for (int q = 0; q < 24; q++) {
      int idx = tid + q * 256;
      int b = idx / 96, k = idx - b * 96;
      _Float16 v = (_Float16)0.f;
      if (k < C_) {
        size_t a = (size_t)n * BC_ + b * C_ + k;
        if (seg == 0)      v = X16[a];
        else if (seg == 1) v = y116[a];
        else               v = (_Float16)(2.f * (float)y216[a] - (float)X16[a]);
      }
      XGls[b][k] = v;
    }
    __syncthreads();
#pragma unroll
    for (int kk = 0; kk < 3; kk++) {
      f16x8 af[4], bfr;
#pragma unroll
      for (int mt = 0; mt < 4; mt++)
        af[mt] = *(const f16x8*)&XGls[mt * 16 + fm][kk * 32 + fq * 8];
      bfr = *(const f16x8*)&Wls[wave * 16 + fm][kk * 32 + fq * 8];
#pragma unroll
      for (int mt = 0; mt < 4; mt++)
        acc[mt] = __builtin_amdgcn_mfma_f32_16x16x32_f16(af[mt], bfr, acc[mt], 0, 0, 0);
    }
  }
  {
    const int o = wave * 16 + fm;
    float bias = 0.f;
#pragma unroll
    for (int d = 0; d < E_; d++) bias = fmaf(es[d], bp[d * OU_ + o], bias);
#pragma unroll
    for (int mt = 0; mt < 4; mt++) {
      const f32x4 v = acc[mt];
#pragma unroll
      for (int j = 0; j < 4; j++) {
        int b = mt * 16 + fq * 4 + j;
        size_t hi = ((size_t)b * N_ + n) * H_ + o;
        float hc = tanhf(v[j] + bias);
        float rv = r[hi];
        h[hi] = rv * h[hi] + (1.0f - rv) * hc;
      }
    }
  }
}

// ---------------------------------------------------------------------------
__global__ __launch_bounds__(64) void k_final(const float* __restrict__ h,
                                              const float* __restrict__ out_lng,
                                              const float* __restrict__ out_lnb,
                                              const float* __restrict__ conv_w,
                                              const float* __restrict__ conv_b,
                                              float* __restrict__ out) {
  const int bn = blockIdx.x;
  const int b = bn >> 10;
  const int n = bn & 1023;
  const int tid = threadIdx.x;
  float v = h[(size_t)bn * H_ + tid];
  float s = v;
  for (int off = 32; off > 0; off >>= 1) s += __shfl_down(s, off);
  s = __shfl(s, 0);
  float mean = s * (1.0f / H_);
  float d = v - mean;
  float vs = d * d;
  for (int off = 32; off > 0; off >>= 1) vs += __shfl_down(vs, off);
  vs = __shfl(vs, 0);
  float var = vs * (1.0f / H_);
  float y = d * rsqrtf(var + EPS_) * out_lng[tid] + out_lnb[tid];
  __shared__ float ys[64];
  ys[tid] = y;
  __syncthreads();
  if (tid < 12) {
    float accv = conv_b[tid];
#pragma unroll
    for (int hh = 0; hh < H_; hh++) accv = fmaf(ys[hh], conv_w[tid * H_ + hh], accv);
    out[((size_t)b * 12 + tid) * N_ + n] = accv;
  }
}

// ---------------------------------------------------------------------------
extern "C" void kernel_launch(void* const* d_in, const int* in_sizes, int n_in,
                              void* d_out, int out_size, void* d_ws, size_t ws_size,
                              hipStream_t stream) {
  const float* src      = (const float*)d_in[0];
  const float* node_emb = (const float*)d_in[1];
  const float* time_emb = (const float*)d_in[2];
  const float* gate_wp  = (const float*)d_in[3];
  const float* gate_bp  = (const float*)d_in[4];
  const float* gate_lng = (const float*)d_in[5];
  const float* gate_lnb = (const float*)d_in[6];
  const float* upd_wp   = (const float*)d_in[7];
  const float* upd_bp   = (const float*)d_in[8];
  const float* upd_lng  = (const float*)d_in[9];
  const float* upd_lnb  = (const float*)d_in[10];
  const float* out_lng  = (const float*)d_in[11];
  const float* out_lnb  = (const float*)d_in[12];
  const float* conv_w   = (const float*)d_in[13];
  const float* conv_b   = (const float*)d_in[14];
  float* out = (float*)d_out;

  constexpr size_t SZ_H  = (size_t)B_ * N_ * H_;        // 4,194,304 floats
  constexpr size_t SZ_T  = (size_t)NP_ * 1024 / 2;      // fp16 [4224][1024] in float slots
  constexpr size_t SZ_R  = (size_t)N_ * BC_ / 2;        // fp16 [1024][4160] in float slots
  constexpr size_t SZ_S  = (size_t)N_ * N_ / 2;         // fp16 sup in float slots

  float* ws = (float*)d_ws;
  size_t off = 0;
  float* h     = ws + off; off += SZ_H;
  float* z     = ws + off; off += SZ_H;
  float* r     = ws + off; off += SZ_H;
  float* XtF   = ws + off; off += SZ_T;
  float* y1tF  = ws + off; off += SZ_T;
  float* XrF   = ws + off; off += SZ_R;
  float* y1rF  = ws + off; off += SZ_R;
  float* y2rF  = ws + off; off += SZ_R;
  float* supF  = ws + off; off += SZ_S;
  float* eg  = ws + off; off += N_ * E_;
  float* egT = ws + off; off += N_ * E_;
  float* eu  = ws + off; off += N_ * E_;
  float* euT = ws + off; off += N_ * E_;
  if (ws_size < off * sizeof(float)) return;

  _Float16* Xt    = (_Float16*)XtF;
  _Float16* y1t   = (_Float16*)y1tF;
  _Float16* Xrow  = (_Float16*)XrF;
  _Float16* y1row = (_Float16*)y1rF;
  _Float16* y2row = (_Float16*)y2rF;
  _Float16* sup16 = (_Float16*)supF;

  hipMemsetAsync(h, 0, SZ_H * sizeof(float), stream);

  dim3 ggrid(NP_ / 128, N_ / 128);   // (33, 8)
  dim3 bgrid(B_, N_ / 64);           // (64, 16)

  for (int t = 0; t < T_; t++) {
    k_compute_e<<<4, 256, 0, stream>>>(node_emb, time_emb, gate_lng, gate_lnb,
                                       upd_lng, upd_lnb, t, eg, egT, eu, euT);
    // ---- gate dagcn ----
    k_sup<<<N_, 256, 0, stream>>>(egT, sup16);
    k_build_gate<<<bgrid, 256, 0, stream>>>(src, h, t, Xt, Xrow);
    k_gemm_f16<<<ggrid, 256, 0, stream>>>(sup16, Xt, y1t, y1row);
    k_gemm_f16<<<ggrid, 256, 0, stream>>>(sup16, y1t, nullptr, y2row);
    k_gate_contract<<<N_, 256, 0, stream>>>(eg, Xrow, y1row, y2row, gate_wp, gate_bp, z, r);
    // ---- update dagcn ----
    k_sup<<<N_, 256, 0, stream>>>(euT, sup16);
    k_build_upd<<<bgrid, 256, 0, stream>>>(src, h, z, t, Xt, Xrow);
    k_gemm_f16<<<ggrid, 256, 0, stream>>>(sup16, Xt, y1t, y1row);
    k_gemm_f16<<<ggrid, 256, 0, stream>>>(sup16, y1t, nullptr, y2row);
    k_upd_contract<<<N_, 256, 0, stream>>>(eu, Xrow, y1row, y2row, upd_wp, upd_bp, r, h);
  }
  k_final<<<B_ * N_, 64, 0, stream>>>(h, out_lng, out_lnb, conv_w, conv_b, out);
}

// Round 4
// 3352.047 us; speedup vs baseline: 3.5174x; 1.8739x over previous
//
#include <hip/hip_runtime.h>
#include <math.h>

namespace {
constexpr int B_ = 64, T_ = 12, N_ = 1024, H_ = 64, E_ = 16;
constexpr int C_  = 65;          // DIN + H
constexpr int BC_ = B_ * C_;     // 4160
constexpr int OG_ = 128;         // gate output = 2H
constexpr int OU_ = 64;          // update output = H
constexpr float EPS_ = 1e-12f;
constexpr int NP_ = 4224;        // BC_ padded to 128 for GEMM N-tiling
constexpr int KP_ = 224;         // packed contract K: 3*65=195 data + pad to 7*32
constexpr int COLG_ = OG_ * KP_; // 28672
constexpr int COLU_ = OU_ * KP_; // 14336
}

typedef unsigned short u16;
typedef unsigned int u32;
using f16x8 = __attribute__((ext_vector_type(8))) _Float16;
using f16x4 = __attribute__((ext_vector_type(4))) _Float16;
using f32x4 = __attribute__((ext_vector_type(4))) float;

__device__ __forceinline__ u32 div65(u32 x) { return (x * 16135u) >> 20; }  // exact for x<5196

// async global->LDS 16B/lane; LDS dest is wave-uniform base + lane*16.
__device__ __forceinline__ void gl_lds16(const void* g, void* l, int lane) {
#if __has_builtin(__builtin_amdgcn_global_load_lds)
  __builtin_amdgcn_global_load_lds((const __attribute__((address_space(1))) u32*)g,
                                   (__attribute__((address_space(3))) u32*)l, 16, 0, 0);
#else
  *(uint4*)((char*)l + lane * 16) = *(const uint4*)g;
#endif
}

// ---------------------------------------------------------------------------
__global__ void k_compute_e(const float* __restrict__ node_emb,
                            const float* __restrict__ time_emb,
                            const float* __restrict__ g_lng, const float* __restrict__ g_lnb,
                            const float* __restrict__ u_lng, const float* __restrict__ u_lnb,
                            int t,
                            float* __restrict__ eg, float* __restrict__ egT,
                            float* __restrict__ eu, float* __restrict__ euT) {
  int n = blockIdx.x * blockDim.x + threadIdx.x;
  if (n >= N_) return;
  float v[E_];
  float m = 0.f;
#pragma unroll
  for (int d = 0; d < E_; d++) { v[d] = node_emb[n * E_ + d] + time_emb[t * E_ + d]; m += v[d]; }
  m *= (1.0f / E_);
  float var = 0.f;
#pragma unroll
  for (int d = 0; d < E_; d++) { float x = v[d] - m; var += x * x; }
  var *= (1.0f / E_);
  float rs = rsqrtf(var + EPS_);
#pragma unroll
  for (int d = 0; d < E_; d++) {
    float nv = (v[d] - m) * rs;
    float g = nv * g_lng[d] + g_lnb[d];
    float u = nv * u_lng[d] + u_lnb[d];
    eg[n * E_ + d] = g; egT[d * N_ + n] = g;
    eu[n * E_ + d] = u; euT[d * N_ + n] = u;
  }
}

// ---------------------------------------------------------------------------
// sup[n,:] = softmax over m of e[n]·e[m]; emits fp16 (A-operand, row-major).
__global__ __launch_bounds__(256) void k_sup(const float* __restrict__ eT,
                                             _Float16* __restrict__ s16) {
  const int n = blockIdx.x;
  const int tid = threadIdx.x;
  __shared__ float red[256];
  float en[E_];
#pragma unroll
  for (int d = 0; d < E_; d++) en[d] = eT[d * N_ + n];
  float lg[4];
  float mx = -3.4e38f;
#pragma unroll
  for (int j = 0; j < 4; j++) {
    int m = tid + 256 * j;
    float s = 0.f;
#pragma unroll
    for (int d = 0; d < E_; d++) s = fmaf(en[d], eT[d * N_ + m], s);
    lg[j] = s;
    mx = fmaxf(mx, s);
  }
  red[tid] = mx; __syncthreads();
  for (int off = 128; off > 0; off >>= 1) {
    if (tid < off) red[tid] = fmaxf(red[tid], red[tid + off]);
    __syncthreads();
  }
  mx = red[0]; __syncthreads();
  float sum = 0.f;
#pragma unroll
  for (int j = 0; j < 4; j++) { lg[j] = __expf(lg[j] - mx); sum += lg[j]; }
  red[tid] = sum; __syncthreads();
  for (int off = 128; off > 0; off >>= 1) {
    if (tid < off) red[tid] += red[tid + off];
    __syncthreads();
  }
  float inv = 1.0f / red[0];
#pragma unroll
  for (int j = 0; j < 4; j++)
    s16[(size_t)n * N_ + tid + 256 * j] = (_Float16)(lg[j] * inv);
}

// ---------------------------------------------------------------------------
// Repack wp[d][seg][ii][o] -> wpC[(o*224 + seg*65+ii)][16 d] fp16, pads zeroed.
__global__ __launch_bounds__(128) void k_wprep(const float* __restrict__ wp, int NO,
                                               _Float16* __restrict__ wpC) {
  const int k = blockIdx.x;          // 0..223
  const int o = threadIdx.x;
  if (o >= NO) return;
  f16x8 lo = {}, hi = {};
  if (k < 195) {
    const u32 seg = div65((u32)k);
    const u32 ii = k - seg * 65;
#pragma unroll
    for (int d = 0; d < 8; d++)
      lo[d] = (_Float16)wp[(((size_t)d * 3 + seg) * 65 + ii) * NO + o];
#pragma unroll
    for (int d = 0; d < 8; d++)
      hi[d] = (_Float16)wp[(((size_t)(d + 8) * 3 + seg) * 65 + ii) * NO + o];
  }
  _Float16* dst = &wpC[((size_t)o * KP_ + k) * 16];
  *(f16x8*)dst = lo;
  *(f16x8*)(dst + 8) = hi;
}

// ---------------------------------------------------------------------------
// Wt[n][o][224] = sum_d e[n,d] * wpC[(o*224+k)][d].  grid (COLS/1024, 16 n-chunks).
__global__ __launch_bounds__(256) void k_wgen(const float* __restrict__ e,
                                              const _Float16* __restrict__ wpC, int COLS,
                                              _Float16* __restrict__ Wt) {
  const int col0 = blockIdx.x * 1024 + threadIdx.x * 4;
  const int n0 = blockIdx.y * 64;
  __shared__ float es[64][16];
#pragma unroll
  for (int q = 0; q < 4; q++) {
    int idx = threadIdx.x + q * 256;
    es[idx >> 4][idx & 15] = e[(size_t)n0 * 16 + idx];
  }
  __syncthreads();
  float wc[4][16];
#pragma unroll
  for (int cc = 0; cc < 4; cc++) {
    f16x8 a = *(const f16x8*)&wpC[(size_t)(col0 + cc) * 16];
    f16x8 b = *(const f16x8*)&wpC[(size_t)(col0 + cc) * 16 + 8];
#pragma unroll
    for (int d = 0; d < 8; d++) { wc[cc][d] = (float)a[d]; wc[cc][8 + d] = (float)b[d]; }
  }
  for (int nn = 0; nn < 64; nn++) {
    float acc[4] = {};
#pragma unroll
    for (int d = 0; d < 16; d++) {
      float ev = es[nn][d];
#pragma unroll
      for (int cc = 0; cc < 4; cc++) acc[cc] = fmaf(ev, wc[cc][d], acc[cc]);
    }
    f16x4 pv;
#pragma unroll
    for (int cc = 0; cc < 4; cc++) pv[cc] = (_Float16)acc[cc];
    *(f16x4*)&Wt[(size_t)(n0 + nn) * COLS + col0] = pv;
  }
}

// ---------------------------------------------------------------------------
// Fused build: XGpad[n][b][0..64] = [x_t | h], zeros k in [192,224); Xt [col][m].
__global__ __launch_bounds__(256) void k_build_gate(const float* __restrict__ src,
                                                    const float* __restrict__ h, int t,
                                                    _Float16* __restrict__ Xt,
                                                    _Float16* __restrict__ xg) {
  __shared__ float tile[64][65];
  const int b = blockIdx.x;
  const int m0 = blockIdx.y * 64;
  const int tid = threadIdx.x;
  {
    const int c = tid & 63, mi = tid >> 6;
#pragma unroll
    for (int p = 0; p < 16; p++) {
      int m = p * 4 + mi;
      tile[m][c + 1] = h[((size_t)b * N_ + m0 + m) * H_ + c];
    }
    if (tid < 64) tile[tid][0] = src[((size_t)b * T_ + t) * N_ + m0 + tid];
  }
  __syncthreads();
  for (int q = 0; q < 17; q++) {
    int idx = tid + q * 256;
    if (idx < 64 * 65) {
      int c = idx >> 6, m = idx & 63;
      Xt[((size_t)(b * C_ + c)) * 1024 + m0 + m] = (_Float16)tile[m][c];
      u32 mm = div65((u32)idx), cc = (u32)idx - mm * 65;
      xg[((size_t)(m0 + mm) * 64 + b) * KP_ + cc] = (_Float16)tile[mm][cc];
    }
  }
#pragma unroll
  for (int q = 0; q < 8; q++) {
    int idx = tid + q * 256;   // < 2048
    int mm = idx >> 5, kk = 192 + (idx & 31);
    xg[((size_t)(m0 + mm) * 64 + b) * KP_ + kk] = (_Float16)0.f;
  }
}

__global__ __launch_bounds__(256) void k_build_upd(const float* __restrict__ src,
                                                   const float* __restrict__ h,
                                                   const float* __restrict__ z, int t,
                                                   _Float16* __restrict__ Xt,
                                                   _Float16* __restrict__ xg) {
  __shared__ float tile[64][65];
  const int b = blockIdx.x;
  const int m0 = blockIdx.y * 64;
  const int tid = threadIdx.x;
  {
    const int c = tid & 63, mi = tid >> 6;
#pragma unroll
    for (int p = 0; p < 16; p++) {
      int m = p * 4 + mi;
      size_t a = ((size_t)b * N_ + m0 + m) * H_ + c;
      tile[m][c + 1] = z[a] * h[a];
    }
    if (tid < 64) tile[tid][0] = src[((size_t)b * T_ + t) * N_ + m0 + tid];
  }
  __syncthreads();
  for (int q = 0; q < 17; q++) {
    int idx = tid + q * 256;
    if (idx < 64 * 65) {
      int c = idx >> 6, m = idx & 63;
      Xt[((size_t)(b * C_ + c)) * 1024 + m0 + m] = (_Float16)tile[m][c];
      u32 mm = div65((u32)idx), cc = (u32)idx - mm * 65;
      xg[((size_t)(m0 + mm) * 64 + b) * KP_ + cc] = (_Float16)tile[mm][cc];
    }
  }
#pragma unroll
  for (int q = 0; q < 8; q++) {
    int idx = tid + q * 256;
    int mm = idx >> 5, kk = 192 + (idx & 31);
    xg[((size_t)(m0 + mm) * 64 + b) * KP_ + kk] = (_Float16)0.f;
  }
}

// ---------------------------------------------------------------------------
// fp16 MFMA GEMM: y = sup[1024x1024] @ X[1024 x 4160].  A row-major, B=Xt [col][m].
// Epilogue: optional yt [col][row] fp16 (next GEMM's B); XGpad seg write at segoff;
// combine: value = 2*v - XGpad_seg0.
__global__ __launch_bounds__(256) void k_gemm_f16(
    const _Float16* __restrict__ A, const _Float16* __restrict__ Bt,
    _Float16* __restrict__ yt, _Float16* __restrict__ xg, int segoff, int combine) {
  __shared__ _Float16 As[128 * 32];
  __shared__ _Float16 Bs[128 * 32];
  const int tid  = threadIdx.x;
  const int wave = tid >> 6, lane = tid & 63;
  const int wm = wave >> 1, wn = wave & 1;
  const int m0 = blockIdx.y * 128, c0 = blockIdx.x * 128;
  const int srow = tid >> 2;
  const int soff = (tid & 3) * 8;
  _Float16* AsW0 = &As[(wave * 16) * 32];
  _Float16* AsW1 = &As[(64 + wave * 16) * 32];
  _Float16* BsW0 = &Bs[(wave * 16) * 32];
  _Float16* BsW1 = &Bs[(64 + wave * 16) * 32];
  const int fm = lane & 15, fq = lane >> 4;
  f32x4 acc[4][4] = {};
  for (int ks = 0; ks < 32; ks++) {
    const int kp = ks * 32;
    gl_lds16(A  + (size_t)(m0 + srow) * 1024 + kp + soff,      AsW0, lane);
    gl_lds16(A  + (size_t)(m0 + 64 + srow) * 1024 + kp + soff, AsW1, lane);
    gl_lds16(Bt + (size_t)(c0 + srow) * 1024 + kp + soff,      BsW0, lane);
    gl_lds16(Bt + (size_t)(c0 + 64 + srow) * 1024 + kp + soff, BsW1, lane);
    __syncthreads();
    f16x8 af[4], bfr[4];
#pragma unroll
    for (int tm = 0; tm < 4; tm++)
      af[tm] = *(const f16x8*)&As[(wm * 64 + tm * 16 + fm) * 32 + fq * 8];
#pragma unroll
    for (int tn = 0; tn < 4; tn++)
      bfr[tn] = *(const f16x8*)&Bs[(wn * 64 + tn * 16 + fm) * 32 + fq * 8];
#pragma unroll
    for (int tm = 0; tm < 4; tm++)
#pragma unroll
      for (int tn = 0; tn < 4; tn++)
        acc[tm][tn] = __builtin_amdgcn_mfma_f32_16x16x32_f16(af[tm], bfr[tn], acc[tm][tn], 0, 0, 0);
    __syncthreads();
  }
  const int q4 = fq * 4;
#pragma unroll
  for (int tn = 0; tn < 4; tn++) {
    const int col = c0 + wn * 64 + tn * 16 + fm;
    if (col >= BC_) continue;
    const u32 bq = div65((u32)col), cq = (u32)col - bq * 65;
#pragma unroll
    for (int tm = 0; tm < 4; tm++) {
      const int row = m0 + wm * 64 + tm * 16 + q4;
      const f32x4 v = acc[tm][tn];
      if (yt) {
        f16x4 pv;
#pragma unroll
        for (int j = 0; j < 4; j++) pv[j] = (_Float16)v[j];
        *(f16x4*)&yt[(size_t)col * 1024 + row] = pv;
      }
#pragma unroll
      for (int j = 0; j < 4; j++) {
        size_t base = ((size_t)(row + j) * 64 + bq) * KP_;
        float vv = v[j];
        if (combine) vv = 2.f * vv - (float)xg[base + cq];
        xg[base + segoff + cq] = (_Float16)vv;
      }
    }
  }
}

// ---------------------------------------------------------------------------
// Gate contraction: per n, out[64 b][128 o] = XG[n] (64x224) @ Wt[n]^T (224x128).
// All MFMA operands loaded straight from global (k-contiguous rows), no LDS.
__global__ __launch_bounds__(256) void k_contract_gate(
    const float* __restrict__ eg,
    const _Float16* __restrict__ XG, const _Float16* __restrict__ Wt,
    const float* __restrict__ bp,
    float* __restrict__ z, float* __restrict__ r) {
  const int n = blockIdx.x;
  const int tid = threadIdx.x;
  const int wave = tid >> 6, lane = tid & 63;
  const int fm = lane & 15, fq = lane >> 4;
  const int wm = wave >> 1, wn = wave & 1;
  __shared__ float es[16];
  __shared__ float bias_s[128];
  if (tid < 16) es[tid] = eg[n * 16 + tid];
  __syncthreads();
  if (tid < 128) {
    float bv = 0.f;
#pragma unroll
    for (int d = 0; d < 16; d++) bv = fmaf(es[d], bp[d * OG_ + tid], bv);
    bias_s[tid] = bv;
  }
  const _Float16* Ab = XG + (size_t)n * 64 * KP_;
  const _Float16* Bb = Wt + (size_t)n * OG_ * KP_;
  f16x8 af[2][2], bf[2][4];
#pragma unroll
  for (int mt = 0; mt < 2; mt++)
    af[0][mt] = *(const f16x8*)&Ab[(wm * 32 + mt * 16 + fm) * KP_ + fq * 8];
#pragma unroll
  for (int nt = 0; nt < 4; nt++)
    bf[0][nt] = *(const f16x8*)&Bb[(wn * 64 + nt * 16 + fm) * KP_ + fq * 8];
  f32x4 acc[2][4] = {};
#pragma unroll
  for (int kk = 0; kk < 7; kk++) {
    const int cur = kk & 1;
    if (kk < 6) {
      const int ko = (kk + 1) * 32 + fq * 8;
#pragma unroll
      for (int mt = 0; mt < 2; mt++)
        af[cur ^ 1][mt] = *(const f16x8*)&Ab[(wm * 32 + mt * 16 + fm) * KP_ + ko];
#pragma unroll
      for (int nt = 0; nt < 4; nt++)
        bf[cur ^ 1][nt] = *(const f16x8*)&Bb[(wn * 64 + nt * 16 + fm) * KP_ + ko];
    }
#pragma unroll
    for (int mt = 0; mt < 2; mt++)
#pragma unroll
      for (int nt = 0; nt < 4; nt++)
        acc[mt][nt] = __builtin_amdgcn_mfma_f32_16x16x32_f16(af[cur][mt], bf[cur][nt], acc[mt][nt], 0, 0, 0);
  }
  __syncthreads();
#pragma unroll
  for (int nt = 0; nt < 4; nt++) {
    const int o = wn * 64 + nt * 16 + fm;
    const float bias = bias_s[o];
#pragma unroll
    for (int mt = 0; mt < 2; mt++) {
      const f32x4 v = acc[mt][nt];
#pragma unroll
      for (int j = 0; j < 4; j++) {
        const int b = wm * 32 + mt * 16 + fq * 4 + j;
        float s = 1.0f / (1.0f + __expf(-(v[j] + bias)));
        size_t oidx = ((size_t)b * N_ + n) * H_;
        if (o < H_) z[oidx + o] = s;
        else        r[oidx + (o - H_)] = s;
      }
    }
  }
}

// ---------------------------------------------------------------------------
// Update contraction + GRU state update. out[64 b][64 o].
__global__ __launch_bounds__(256) void k_contract_upd(
    const float* __restrict__ eu,
    const _Float16* __restrict__ XG, const _Float16* __restrict__ Wt,
    const float* __restrict__ bp,
    const float* __restrict__ r,
    float* __restrict__ h) {
  const int n = blockIdx.x;
  const int tid = threadIdx.x;
  const int wave = tid >> 6, lane = tid & 63;
  const int fm = lane & 15, fq = lane >> 4;
  __shared__ float es[16];
  __shared__ float bias_s[64];
  if (tid < 16) es[tid] = eu[n * 16 + tid];
  __syncthreads();
  if (tid < 64) {
    float bv = 0.f;
#pragma unroll
    for (int d = 0; d < 16; d++) bv = fmaf(es[d], bp[d * OU_ + tid], bv);
    bias_s[tid] = bv;
  }
  const _Float16* Ab = XG + (size_t)n * 64 * KP_;
  const _Float16* Bb = Wt + (size_t)n * OU_ * KP_;
  f16x8 af[2], bf[2][4];
  af[0] = *(const f16x8*)&Ab[(wave * 16 + fm) * KP_ + fq * 8];
#pragma unroll
  for (int nt = 0; nt < 4; nt++)
    bf[0][nt] = *(const f16x8*)&Bb[(nt * 16 + fm) * KP_ + fq * 8];
  f32x4 acc[4] = {};
#pragma unroll
  for (int kk = 0; kk < 7; kk++) {
    const int cur = kk & 1;
    if (kk < 6) {
      const int ko = (kk + 1) * 32 + fq * 8;
      af[cur ^ 1] = *(const f16x8*)&Ab[(wave * 16 + fm) * KP_ + ko];
#pragma unroll
      for (int nt = 0; nt < 4; nt++)
        bf[cur ^ 1][nt] = *(const f16x8*)&Bb[(nt * 16 + fm) * KP_ + ko];
    }
#pragma unroll
    for (int nt = 0; nt < 4; nt++)
      acc[nt] = __builtin_amdgcn_mfma_f32_16x16x32_f16(af[cur], bf[cur][nt], acc[nt], 0, 0, 0);
  }
  __syncthreads();
#pragma unroll
  for (int nt = 0; nt < 4; nt++) {
    const int o = nt * 16 + fm;
    const float bias = bias_s[o];
    const f32x4 v = acc[nt];
#pragma unroll
    for (int j = 0; j < 4; j++) {
      const int b = wave * 16 + fq * 4 + j;
      size_t hi = ((size_t)b * N_ + n) * H_ + o;
      float hc = tanhf(v[j] + bias);
      float rv = r[hi];
      h[hi] = rv * h[hi] + (1.0f - rv) * hc;
    }
  }
}

// ---------------------------------------------------------------------------
__global__ __launch_bounds__(64) void k_final(const float* __restrict__ h,
                                              const float* __restrict__ out_lng,
                                              const float* __restrict__ out_lnb,
                                              const float* __restrict__ conv_w,
                                              const float* __restrict__ conv_b,
                                              float* __restrict__ out) {
  const int bn = blockIdx.x;
  const int b = bn >> 10;
  const int n = bn & 1023;
  const int tid = threadIdx.x;
  float v = h[(size_t)bn * H_ + tid];
  float s = v;
  for (int off = 32; off > 0; off >>= 1) s += __shfl_down(s, off);
  s = __shfl(s, 0);
  float mean = s * (1.0f / H_);
  float d = v - mean;
  float vs = d * d;
  for (int off = 32; off > 0; off >>= 1) vs += __shfl_down(vs, off);
  vs = __shfl(vs, 0);
  float var = vs * (1.0f / H_);
  float y = d * rsqrtf(var + EPS_) * out_lng[tid] + out_lnb[tid];
  __shared__ float ys[64];
  ys[tid] = y;
  __syncthreads();
  if (tid < 12) {
    float accv = conv_b[tid];
#pragma unroll
    for (int hh = 0; hh < H_; hh++) accv = fmaf(ys[hh], conv_w[tid * H_ + hh], accv);
    out[((size_t)b * 12 + tid) * N_ + n] = accv;
  }
}

// ---------------------------------------------------------------------------
extern "C" void kernel_launch(void* const* d_in, const int* in_sizes, int n_in,
                              void* d_out, int out_size, void* d_ws, size_t ws_size,
                              hipStream_t stream) {
  const float* src      = (const float*)d_in[0];
  const float* node_emb = (const float*)d_in[1];
  const float* time_emb = (const float*)d_in[2];
  const float* gate_wp  = (const float*)d_in[3];
  const float* gate_bp  = (const float*)d_in[4];
  const float* gate_lng = (const float*)d_in[5];
  const float* gate_lnb = (const float*)d_in[6];
  const float* upd_wp   = (const float*)d_in[7];
  const float* upd_bp   = (const float*)d_in[8];
  const float* upd_lng  = (const float*)d_in[9];
  const float* upd_lnb  = (const float*)d_in[10];
  const float* out_lng  = (const float*)d_in[11];
  const float* out_lnb  = (const float*)d_in[12];
  const float* conv_w   = (const float*)d_in[13];
  const float* conv_b   = (const float*)d_in[14];
  float* out = (float*)d_out;

  constexpr size_t SZ_H   = (size_t)B_ * N_ * H_;           // 4,194,304
  constexpr size_t SZ_T   = (size_t)NP_ * 1024 / 2;         // 2,162,688
  constexpr size_t SZ_XG  = (size_t)N_ * 64 * KP_ / 2;      // 7,340,032
  constexpr size_t SZ_WT  = (size_t)N_ * OG_ * KP_ / 2;     // 14,680,064
  constexpr size_t SZ_WCG = (size_t)COLG_ * 16 / 2;         // 229,376
  constexpr size_t SZ_WCU = (size_t)COLU_ * 16 / 2;         // 114,688
  constexpr size_t SZ_S   = (size_t)N_ * N_ / 2;            // 524,288

  float* ws = (float*)d_ws;
  size_t off = 0;
  float* h     = ws + off; off += SZ_H;
  float* z     = ws + off; off += SZ_H;
  float* r     = ws + off; off += SZ_H;
  float* XtF   = ws + off; off += SZ_T;
  float* y1tF  = ws + off; off += SZ_T;
  float* XGF   = ws + off; off += SZ_XG;
  float* WtF   = ws + off; off += SZ_WT;
  float* wcgF  = ws + off; off += SZ_WCG;
  float* wcuF  = ws + off; off += SZ_WCU;
  float* supF  = ws + off; off += SZ_S;
  float* eg  = ws + off; off += N_ * E_;
  float* egT = ws + off; off += N_ * E_;
  float* eu  = ws + off; off += N_ * E_;
  float* euT = ws + off; off += N_ * E_;
  if (ws_size < off * sizeof(float)) return;

  _Float16* Xt    = (_Float16*)XtF;
  _Float16* y1t   = (_Float16*)y1tF;
  _Float16* XG    = (_Float16*)XGF;
  _Float16* Wt    = (_Float16*)WtF;
  _Float16* wpCg  = (_Float16*)wcgF;
  _Float16* wpCu  = (_Float16*)wcuF;
  _Float16* sup16 = (_Float16*)supF;

  hipMemsetAsync(h, 0, SZ_H * sizeof(float), stream);
  k_wprep<<<KP_, 128, 0, stream>>>(gate_wp, OG_, wpCg);
  k_wprep<<<KP_, 128, 0, stream>>>(upd_wp, OU_, wpCu);

  dim3 ggrid(NP_ / 128, N_ / 128);    // (33, 8)
  dim3 bgrid(B_, N_ / 64);            // (64, 16)
  dim3 wggrid(COLG_ / 1024, 16);      // (28, 16)
  dim3 wugrid(COLU_ / 1024, 16);      // (14, 16)

  for (int t = 0; t < T_; t++) {
    k_compute_e<<<4, 256, 0, stream>>>(node_emb, time_emb, gate_lng, gate_lnb,
                                       upd_lng, upd_lnb, t, eg, egT, eu, euT);
    // ---- gate dagcn ----
    k_sup<<<N_, 256, 0, stream>>>(egT, sup16);
    k_build_gate<<<bgrid, 256, 0, stream>>>(src, h, t, Xt, XG);
    k_gemm_f16<<<ggrid, 256, 0, stream>>>(sup16, Xt, y1t, XG, 65, 0);
    k_gemm_f16<<<ggrid, 256, 0, stream>>>(sup16, y1t, nullptr, XG, 130, 1);
    k_wgen<<<wggrid, 256, 0, stream>>>(eg, wpCg, COLG_, Wt);
    k_contract_gate<<<N_, 256, 0, stream>>>(eg, XG, Wt, gate_bp, z, r);
    // ---- update dagcn ----
    k_sup<<<N_, 256, 0, stream>>>(euT, sup16);
    k_build_upd<<<bgrid, 256, 0, stream>>>(src, h, z, t, Xt, XG);
    k_gemm_f16<<<ggrid, 256, 0, stream>>>(sup16, Xt, y1t, XG, 65, 0);
    k_gemm_f16<<<ggrid, 256, 0, stream>>>(sup16, y1t, nullptr, XG, 130, 1);
    k_wgen<<<wugrid, 256, 0, stream>>>(eu, wpCu, COLU_, Wt);
    k_contract_upd<<<N_, 256, 0, stream>>>(eu, XG, Wt, upd_bp, r, h);
  }
  k_final<<<B_ * N_, 64, 0, stream>>>(h, out_lng, out_lnb, conv_w, conv_b, out);
}

// Round 5
// 2936.981 us; speedup vs baseline: 4.0145x; 1.1413x over previous
//
#include <hip/hip_runtime.h>
#include <math.h>

namespace {
constexpr int B_ = 64, T_ = 12, N_ = 1024, H_ = 64, E_ = 16;
constexpr int C_  = 65;          // DIN + H
constexpr int BC_ = B_ * C_;     // 4160
constexpr int OG_ = 128;         // gate output = 2H
constexpr int OU_ = 64;          // update output = H
constexpr float EPS_ = 1e-12f;
constexpr int NP_ = 4224;        // BC_ padded for GEMM N-tiling (multiple of 64)
constexpr int KP_ = 224;         // packed contract K: 3*65=195 data + pad to 7*32
constexpr int COLG_ = OG_ * KP_; // 28672
constexpr int COLU_ = OU_ * KP_; // 14336
}

typedef unsigned short u16;
typedef unsigned int u32;
using f16x8 = __attribute__((ext_vector_type(8))) _Float16;
using f16x4 = __attribute__((ext_vector_type(4))) _Float16;
using f32x4 = __attribute__((ext_vector_type(4))) float;

__device__ __forceinline__ u32 div65(u32 x) { return (x * 16135u) >> 20; }  // exact for x<5196

// async global->LDS 16B/lane; LDS dest is wave-uniform base + lane*16.
__device__ __forceinline__ void gl_lds16(const void* g, void* l, int lane) {
#if __has_builtin(__builtin_amdgcn_global_load_lds)
  __builtin_amdgcn_global_load_lds((const __attribute__((address_space(1))) u32*)g,
                                   (__attribute__((address_space(3))) u32*)l, 16, 0, 0);
#else
  *(uint4*)((char*)l + lane * 16) = *(const uint4*)g;
#endif
}

// ---------------------------------------------------------------------------
__global__ void k_compute_e(const float* __restrict__ node_emb,
                            const float* __restrict__ time_emb,
                            const float* __restrict__ g_lng, const float* __restrict__ g_lnb,
                            const float* __restrict__ u_lng, const float* __restrict__ u_lnb,
                            int t,
                            float* __restrict__ eg, float* __restrict__ egT,
                            float* __restrict__ eu, float* __restrict__ euT) {
  int n = blockIdx.x * blockDim.x + threadIdx.x;
  if (n >= N_) return;
  float v[E_];
  float m = 0.f;
#pragma unroll
  for (int d = 0; d < E_; d++) { v[d] = node_emb[n * E_ + d] + time_emb[t * E_ + d]; m += v[d]; }
  m *= (1.0f / E_);
  float var = 0.f;
#pragma unroll
  for (int d = 0; d < E_; d++) { float x = v[d] - m; var += x * x; }
  var *= (1.0f / E_);
  float rs = rsqrtf(var + EPS_);
#pragma unroll
  for (int d = 0; d < E_; d++) {
    float nv = (v[d] - m) * rs;
    float g = nv * g_lng[d] + g_lnb[d];
    float u = nv * u_lng[d] + u_lnb[d];
    eg[n * E_ + d] = g; egT[d * N_ + n] = g;
    eu[n * E_ + d] = u; euT[d * N_ + n] = u;
  }
}

// ---------------------------------------------------------------------------
// sup[n,:] = softmax over m of e[n]·e[m]; emits fp16 (A-operand, row-major).
__global__ __launch_bounds__(256) void k_sup(const float* __restrict__ eT,
                                             _Float16* __restrict__ s16) {
  const int n = blockIdx.x;
  const int tid = threadIdx.x;
  __shared__ float red[256];
  float en[E_];
#pragma unroll
  for (int d = 0; d < E_; d++) en[d] = eT[d * N_ + n];
  float lg[4];
  float mx = -3.4e38f;
#pragma unroll
  for (int j = 0; j < 4; j++) {
    int m = tid + 256 * j;
    float s = 0.f;
#pragma unroll
    for (int d = 0; d < E_; d++) s = fmaf(en[d], eT[d * N_ + m], s);
    lg[j] = s;
    mx = fmaxf(mx, s);
  }
  red[tid] = mx; __syncthreads();
  for (int off = 128; off > 0; off >>= 1) {
    if (tid < off) red[tid] = fmaxf(red[tid], red[tid + off]);
    __syncthreads();
  }
  mx = red[0]; __syncthreads();
  float sum = 0.f;
#pragma unroll
  for (int j = 0; j < 4; j++) { lg[j] = __expf(lg[j] - mx); sum += lg[j]; }
  red[tid] = sum; __syncthreads();
  for (int off = 128; off > 0; off >>= 1) {
    if (tid < off) red[tid] += red[tid + off];
    __syncthreads();
  }
  float inv = 1.0f / red[0];
#pragma unroll
  for (int j = 0; j < 4; j++)
    s16[(size_t)n * N_ + tid + 256 * j] = (_Float16)(lg[j] * inv);
}

// ---------------------------------------------------------------------------
// Repack wp[d][seg][ii][o] -> wpC[(o*224 + seg*65+ii)][16 d] fp16, pads zeroed.
__global__ __launch_bounds__(128) void k_wprep(const float* __restrict__ wp, int NO,
                                               _Float16* __restrict__ wpC) {
  const int k = blockIdx.x;          // 0..223
  const int o = threadIdx.x;
  if (o >= NO) return;
  f16x8 lo = {}, hi = {};
  if (k < 195) {
    const u32 seg = div65((u32)k);
    const u32 ii = k - seg * 65;
#pragma unroll
    for (int d = 0; d < 8; d++)
      lo[d] = (_Float16)wp[(((size_t)d * 3 + seg) * 65 + ii) * NO + o];
#pragma unroll
    for (int d = 0; d < 8; d++)
      hi[d] = (_Float16)wp[(((size_t)(d + 8) * 3 + seg) * 65 + ii) * NO + o];
  }
  _Float16* dst = &wpC[((size_t)o * KP_ + k) * 16];
  *(f16x8*)dst = lo;
  *(f16x8*)(dst + 8) = hi;
}

// ---------------------------------------------------------------------------
// Wt[n][o][224] = sum_d e[n,d] * wpC[(o*224+k)][d].  grid (COLS/1024, 16 n-chunks).
__global__ __launch_bounds__(256) void k_wgen(const float* __restrict__ e,
                                              const _Float16* __restrict__ wpC, int COLS,
                                              _Float16* __restrict__ Wt) {
  const int col0 = blockIdx.x * 1024 + threadIdx.x * 4;
  const int n0 = blockIdx.y * 64;
  __shared__ float es[64][16];
#pragma unroll
  for (int q = 0; q < 4; q++) {
    int idx = threadIdx.x + q * 256;
    es[idx >> 4][idx & 15] = e[(size_t)n0 * 16 + idx];
  }
  __syncthreads();
  float wc[4][16];
#pragma unroll
  for (int cc = 0; cc < 4; cc++) {
    f16x8 a = *(const f16x8*)&wpC[(size_t)(col0 + cc) * 16];
    f16x8 b = *(const f16x8*)&wpC[(size_t)(col0 + cc) * 16 + 8];
#pragma unroll
    for (int d = 0; d < 8; d++) { wc[cc][d] = (float)a[d]; wc[cc][8 + d] = (float)b[d]; }
  }
  for (int nn = 0; nn < 64; nn++) {
    float acc[4] = {};
#pragma unroll
    for (int d = 0; d < 16; d++) {
      float ev = es[nn][d];
#pragma unroll
      for (int cc = 0; cc < 4; cc++) acc[cc] = fmaf(ev, wc[cc][d], acc[cc]);
    }
    f16x4 pv;
#pragma unroll
    for (int cc = 0; cc < 4; cc++) pv[cc] = (_Float16)acc[cc];
    *(f16x4*)&Wt[(size_t)(n0 + nn) * COLS + col0] = pv;
  }
}

// ---------------------------------------------------------------------------
// Fused build: XGpad[n][b][0..64] = [x_t | h], zeros k in [192,224); Xt [col][m].
__global__ __launch_bounds__(256) void k_build_gate(const float* __restrict__ src,
                                                    const float* __restrict__ h, int t,
                                                    _Float16* __restrict__ Xt,
                                                    _Float16* __restrict__ xg) {
  __shared__ float tile[64][65];
  const int b = blockIdx.x;
  const int m0 = blockIdx.y * 64;
  const int tid = threadIdx.x;
  {
    const int c = tid & 63, mi = tid >> 6;
#pragma unroll
    for (int p = 0; p < 16; p++) {
      int m = p * 4 + mi;
      tile[m][c + 1] = h[((size_t)b * N_ + m0 + m) * H_ + c];
    }
    if (tid < 64) tile[tid][0] = src[((size_t)b * T_ + t) * N_ + m0 + tid];
  }
  __syncthreads();
  for (int q = 0; q < 17; q++) {
    int idx = tid + q * 256;
    if (idx < 64 * 65) {
      int c = idx >> 6, m = idx & 63;
      Xt[((size_t)(b * C_ + c)) * 1024 + m0 + m] = (_Float16)tile[m][c];
      u32 mm = div65((u32)idx), cc = (u32)idx - mm * 65;
      xg[((size_t)(m0 + mm) * 64 + b) * KP_ + cc] = (_Float16)tile[mm][cc];
    }
  }
#pragma unroll
  for (int q = 0; q < 8; q++) {
    int idx = tid + q * 256;   // < 2048
    int mm = idx >> 5, kk = 192 + (idx & 31);
    xg[((size_t)(m0 + mm) * 64 + b) * KP_ + kk] = (_Float16)0.f;
  }
}

__global__ __launch_bounds__(256) void k_build_upd(const float* __restrict__ src,
                                                   const float* __restrict__ h,
                                                   const float* __restrict__ z, int t,
                                                   _Float16* __restrict__ Xt,
                                                   _Float16* __restrict__ xg) {
  __shared__ float tile[64][65];
  const int b = blockIdx.x;
  const int m0 = blockIdx.y * 64;
  const int tid = threadIdx.x;
  {
    const int c = tid & 63, mi = tid >> 6;
#pragma unroll
    for (int p = 0; p < 16; p++) {
      int m = p * 4 + mi;
      size_t a = ((size_t)b * N_ + m0 + m) * H_ + c;
      tile[m][c + 1] = z[a] * h[a];
    }
    if (tid < 64) tile[tid][0] = src[((size_t)b * T_ + t) * N_ + m0 + tid];
  }
  __syncthreads();
  for (int q = 0; q < 17; q++) {
    int idx = tid + q * 256;
    if (idx < 64 * 65) {
      int c = idx >> 6, m = idx & 63;
      Xt[((size_t)(b * C_ + c)) * 1024 + m0 + m] = (_Float16)tile[m][c];
      u32 mm = div65((u32)idx), cc = (u32)idx - mm * 65;
      xg[((size_t)(m0 + mm) * 64 + b) * KP_ + cc] = (_Float16)tile[mm][cc];
    }
  }
#pragma unroll
  for (int q = 0; q < 8; q++) {
    int idx = tid + q * 256;
    int mm = idx >> 5, kk = 192 + (idx & 31);
    xg[((size_t)(m0 + mm) * 64 + b) * KP_ + kk] = (_Float16)0.f;
  }
}

// ---------------------------------------------------------------------------
// fp16 MFMA GEMM, 128x64 tile (BM=128, BN=64), grid (66,8)=528 blocks for
// balanced CU residency (2+/CU).  A = sup [m][k]; B = Xt [col][k].
// Epilogue: optional yt [col][row] fp16 (next GEMM's B); XGpad seg write at
// segoff; combine: value = 2*v - XGpad_seg0.
__global__ __launch_bounds__(256) void k_gemm_f16(
    const _Float16* __restrict__ A, const _Float16* __restrict__ Bt,
    _Float16* __restrict__ yt, _Float16* __restrict__ xg, int segoff, int combine) {
  __shared__ _Float16 As[128 * 32];   // 8 KB
  __shared__ _Float16 Bs[64 * 32];    // 4 KB
  const int tid  = threadIdx.x;
  const int wave = tid >> 6, lane = tid & 63;
  const int m0 = blockIdx.y * 128, c0 = blockIdx.x * 64;
  const int srow = tid >> 2;          // 0..63
  const int soff = (tid & 3) * 8;
  _Float16* AsW0 = &As[(wave * 16) * 32];
  _Float16* AsW1 = &As[(64 + wave * 16) * 32];
  _Float16* BsW0 = &Bs[(wave * 16) * 32];
  const int fm = lane & 15, fq = lane >> 4;
  f32x4 acc[2][4] = {};
  for (int ks = 0; ks < 32; ks++) {
    const int kp = ks * 32;
    gl_lds16(A  + (size_t)(m0 + srow) * 1024 + kp + soff,      AsW0, lane);
    gl_lds16(A  + (size_t)(m0 + 64 + srow) * 1024 + kp + soff, AsW1, lane);
    gl_lds16(Bt + (size_t)(c0 + srow) * 1024 + kp + soff,      BsW0, lane);
    __syncthreads();
    f16x8 af[2], bfr[4];
#pragma unroll
    for (int mt = 0; mt < 2; mt++)
      af[mt] = *(const f16x8*)&As[(wave * 32 + mt * 16 + fm) * 32 + fq * 8];
#pragma unroll
    for (int nt = 0; nt < 4; nt++)
      bfr[nt] = *(const f16x8*)&Bs[(nt * 16 + fm) * 32 + fq * 8];
#pragma unroll
    for (int mt = 0; mt < 2; mt++)
#pragma unroll
      for (int nt = 0; nt < 4; nt++)
        acc[mt][nt] = __builtin_amdgcn_mfma_f32_16x16x32_f16(af[mt], bfr[nt], acc[mt][nt], 0, 0, 0);
    __syncthreads();
  }
  const int q4 = fq * 4;
#pragma unroll
  for (int nt = 0; nt < 4; nt++) {
    const int col = c0 + nt * 16 + fm;
    if (col >= BC_) continue;
    const u32 bq = div65((u32)col), cq = (u32)col - bq * 65;
#pragma unroll
    for (int mt = 0; mt < 2; mt++) {
      const int row = m0 + wave * 32 + mt * 16 + q4;
      const f32x4 v = acc[mt][nt];
      if (yt) {
        f16x4 pv;
#pragma unroll
        for (int j = 0; j < 4; j++) pv[j] = (_Float16)v[j];
        *(f16x4*)&yt[(size_t)col * 1024 + row] = pv;
      }
#pragma unroll
      for (int j = 0; j < 4; j++) {
        size_t base = ((size_t)(row + j) * 64 + bq) * KP_;
        float vv = v[j];
        if (combine) vv = 2.f * vv - (float)xg[base + cq];
        xg[base + segoff + cq] = (_Float16)vv;
      }
    }
  }
}

// ---------------------------------------------------------------------------
// Gate contraction: per n, out[64 b][128 o] = XG[n] (64x224) @ Wt[n]^T (224x128).
__global__ __launch_bounds__(256) void k_contract_gate(
    const float* __restrict__ eg,
    const _Float16* __restrict__ XG, const _Float16* __restrict__ Wt,
    const float* __restrict__ bp,
    float* __restrict__ z, float* __restrict__ r) {
  const int n = blockIdx.x;
  const int tid = threadIdx.x;
  const int wave = tid >> 6, lane = tid & 63;
  const int fm = lane & 15, fq = lane >> 4;
  const int wm = wave >> 1, wn = wave & 1;
  __shared__ float es[16];
  __shared__ float bias_s[128];
  if (tid < 16) es[tid] = eg[n * 16 + tid];
  __syncthreads();
  if (tid < 128) {
    float bv = 0.f;
#pragma unroll
    for (int d = 0; d < 16; d++) bv = fmaf(es[d], bp[d * OG_ + tid], bv);
    bias_s[tid] = bv;
  }
  const _Float16* Ab = XG + (size_t)n * 64 * KP_;
  const _Float16* Bb = Wt + (size_t)n * OG_ * KP_;
  f16x8 af[2][2], bf[2][4];
#pragma unroll
  for (int mt = 0; mt < 2; mt++)
    af[0][mt] = *(const f16x8*)&Ab[(wm * 32 + mt * 16 + fm) * KP_ + fq * 8];
#pragma unroll
  for (int nt = 0; nt < 4; nt++)
    bf[0][nt] = *(const f16x8*)&Bb[(wn * 64 + nt * 16 + fm) * KP_ + fq * 8];
  f32x4 acc[2][4] = {};
#pragma unroll
  for (int kk = 0; kk < 7; kk++) {
    const int cur = kk & 1;
    if (kk < 6) {
      const int ko = (kk + 1) * 32 + fq * 8;
#pragma unroll
      for (int mt = 0; mt < 2; mt++)
        af[cur ^ 1][mt] = *(const f16x8*)&Ab[(wm * 32 + mt * 16 + fm) * KP_ + ko];
#pragma unroll
      for (int nt = 0; nt < 4; nt++)
        bf[cur ^ 1][nt] = *(const f16x8*)&Bb[(wn * 64 + nt * 16 + fm) * KP_ + ko];
    }
#pragma unroll
    for (int mt = 0; mt < 2; mt++)
#pragma unroll
      for (int nt = 0; nt < 4; nt++)
        acc[mt][nt] = __builtin_amdgcn_mfma_f32_16x16x32_f16(af[cur][mt], bf[cur][nt], acc[mt][nt], 0, 0, 0);
  }
  __syncthreads();
#pragma unroll
  for (int nt = 0; nt < 4; nt++) {
    const int o = wn * 64 + nt * 16 + fm;
    const float bias = bias_s[o];
#pragma unroll
    for (int mt = 0; mt < 2; mt++) {
      const f32x4 v = acc[mt][nt];
#pragma unroll
      for (int j = 0; j < 4; j++) {
        const int b = wm * 32 + mt * 16 + fq * 4 + j;
        float s = 1.0f / (1.0f + __expf(-(v[j] + bias)));
        size_t oidx = ((size_t)b * N_ + n) * H_;
        if (o < H_) z[oidx + o] = s;
        else        r[oidx + (o - H_)] = s;
      }
    }
  }
}

// ---------------------------------------------------------------------------
// Update contraction + GRU state update. out[64 b][64 o].
__global__ __launch_bounds__(256) void k_contract_upd(
    const float* __restrict__ eu,
    const _Float16* __restrict__ XG, const _Float16* __restrict__ Wt,
    const float* __restrict__ bp,
    const float* __restrict__ r,
    float* __restrict__ h) {
  const int n = blockIdx.x;
  const int tid = threadIdx.x;
  const int wave = tid >> 6, lane = tid & 63;
  const int fm = lane & 15, fq = lane >> 4;
  __shared__ float es[16];
  __shared__ float bias_s[64];
  if (tid < 16) es[tid] = eu[n * 16 + tid];
  __syncthreads();
  if (tid < 64) {
    float bv = 0.f;
#pragma unroll
    for (int d = 0; d < 16; d++) bv = fmaf(es[d], bp[d * OU_ + tid], bv);
    bias_s[tid] = bv;
  }
  const _Float16* Ab = XG + (size_t)n * 64 * KP_;
  const _Float16* Bb = Wt + (size_t)n * OU_ * KP_;
  f16x8 af[2], bf[2][4];
  af[0] = *(const f16x8*)&Ab[(wave * 16 + fm) * KP_ + fq * 8];
#pragma unroll
  for (int nt = 0; nt < 4; nt++)
    bf[0][nt] = *(const f16x8*)&Bb[(nt * 16 + fm) * KP_ + fq * 8];
  f32x4 acc[4] = {};
#pragma unroll
  for (int kk = 0; kk < 7; kk++) {
    const int cur = kk & 1;
    if (kk < 6) {
      const int ko = (kk + 1) * 32 + fq * 8;
      af[cur ^ 1] = *(const f16x8*)&Ab[(wave * 16 + fm) * KP_ + ko];
#pragma unroll
      for (int nt = 0; nt < 4; nt++)
        bf[cur ^ 1][nt] = *(const f16x8*)&Bb[(nt * 16 + fm) * KP_ + ko];
    }
#pragma unroll
    for (int nt = 0; nt < 4; nt++)
      acc[nt] = __builtin_amdgcn_mfma_f32_16x16x32_f16(af[cur], bf[cur][nt], acc[nt], 0, 0, 0);
  }
  __syncthreads();
#pragma unroll
  for (int nt = 0; nt < 4; nt++) {
    const int o = nt * 16 + fm;
    const float bias = bias_s[o];
    const f32x4 v = acc[nt];
#pragma unroll
    for (int j = 0; j < 4; j++) {
      const int b = wave * 16 + fq * 4 + j;
      size_t hi = ((size_t)b * N_ + n) * H_ + o;
      float hc = tanhf(v[j] + bias);
      float rv = r[hi];
      h[hi] = rv * h[hi] + (1.0f - rv) * hc;
    }
  }
}

// ---------------------------------------------------------------------------
// LN(h) + conv, one thread per (b,n): thread owns the whole 64-float h row
// (full-cacheline float4 reads), LN in registers, conv_w broadcast from LDS,
// stores coalesced over n.  grid = B_*N_/256 = 256 blocks.
__global__ __launch_bounds__(256) void k_final(const float* __restrict__ h,
                                               const float* __restrict__ out_lng,
                                               const float* __restrict__ out_lnb,
                                               const float* __restrict__ conv_w,
                                               const float* __restrict__ conv_b,
                                               float* __restrict__ out) {
  const int b = blockIdx.x >> 2;
  const int n = (blockIdx.x & 3) * 256 + threadIdx.x;
  __shared__ float cw[12][64];
  __shared__ float cb[12];
  __shared__ float lgs[64], lbs[64];
  for (int idx = threadIdx.x; idx < 12 * 64; idx += 256) cw[idx >> 6][idx & 63] = conv_w[idx];
  if (threadIdx.x < 12) cb[threadIdx.x] = conv_b[threadIdx.x];
  if (threadIdx.x < 64) { lgs[threadIdx.x] = out_lng[threadIdx.x]; lbs[threadIdx.x] = out_lnb[threadIdx.x]; }
  __syncthreads();
  const float* hp = &h[((size_t)b * N_ + n) * H_];
  float4 hv[16];
  float mean = 0.f;
#pragma unroll
  for (int i = 0; i < 16; i++) {
    hv[i] = *(const float4*)&hp[i * 4];
    mean += hv[i].x + hv[i].y + hv[i].z + hv[i].w;
  }
  mean *= (1.0f / H_);
  float var = 0.f;
#pragma unroll
  for (int i = 0; i < 16; i++) {
    float dx = hv[i].x - mean, dy = hv[i].y - mean, dz = hv[i].z - mean, dw = hv[i].w - mean;
    var += dx * dx + dy * dy + dz * dz + dw * dw;
  }
  var *= (1.0f / H_);
  const float rs = rsqrtf(var + EPS_);
  float y[64];
#pragma unroll
  for (int i = 0; i < 16; i++) {
    y[4 * i + 0] = (hv[i].x - mean) * rs * lgs[4 * i + 0] + lbs[4 * i + 0];
    y[4 * i + 1] = (hv[i].y - mean) * rs * lgs[4 * i + 1] + lbs[4 * i + 1];
    y[4 * i + 2] = (hv[i].z - mean) * rs * lgs[4 * i + 2] + lbs[4 * i + 2];
    y[4 * i + 3] = (hv[i].w - mean) * rs * lgs[4 * i + 3] + lbs[4 * i + 3];
  }
#pragma unroll
  for (int o = 0; o < 12; o++) {
    float acc = cb[o];
#pragma unroll
    for (int i = 0; i < 64; i++) acc = fmaf(y[i], cw[o][i], acc);
    out[((size_t)b * 12 + o) * N_ + n] = acc;
  }
}

// ---------------------------------------------------------------------------
extern "C" void kernel_launch(void* const* d_in, const int* in_sizes, int n_in,
                              void* d_out, int out_size, void* d_ws, size_t ws_size,
                              hipStream_t stream) {
  const float* src      = (const float*)d_in[0];
  const float* node_emb = (const float*)d_in[1];
  const float* time_emb = (const float*)d_in[2];
  const float* gate_wp  = (const float*)d_in[3];
  const float* gate_bp  = (const float*)d_in[4];
  const float* gate_lng = (const float*)d_in[5];
  const float* gate_lnb = (const float*)d_in[6];
  const float* upd_wp   = (const float*)d_in[7];
  const float* upd_bp   = (const float*)d_in[8];
  const float* upd_lng  = (const float*)d_in[9];
  const float* upd_lnb  = (const float*)d_in[10];
  const float* out_lng  = (const float*)d_in[11];
  const float* out_lnb  = (const float*)d_in[12];
  const float* conv_w   = (const float*)d_in[13];
  const float* conv_b   = (const float*)d_in[14];
  float* out = (float*)d_out;

  constexpr size_t SZ_H   = (size_t)B_ * N_ * H_;           // 4,194,304
  constexpr size_t SZ_T   = (size_t)NP_ * 1024 / 2;         // 2,162,688
  constexpr size_t SZ_XG  = (size_t)N_ * 64 * KP_ / 2;      // 7,340,032
  constexpr size_t SZ_WT  = (size_t)N_ * OG_ * KP_ / 2;     // 14,680,064
  constexpr size_t SZ_WCG = (size_t)COLG_ * 16 / 2;         // 229,376
  constexpr size_t SZ_WCU = (size_t)COLU_ * 16 / 2;         // 114,688
  constexpr size_t SZ_S   = (size_t)N_ * N_ / 2;            // 524,288

  float* ws = (float*)d_ws;
  size_t off = 0;
  float* h     = ws + off; off += SZ_H;
  float* z     = ws + off; off += SZ_H;
  float* r     = ws + off; off += SZ_H;
  float* XtF   = ws + off; off += SZ_T;
  float* y1tF  = ws + off; off += SZ_T;
  float* XGF   = ws + off; off += SZ_XG;
  float* WtF   = ws + off; off += SZ_WT;
  float* wcgF  = ws + off; off += SZ_WCG;
  float* wcuF  = ws + off; off += SZ_WCU;
  float* supF  = ws + off; off += SZ_S;
  float* eg  = ws + off; off += N_ * E_;
  float* egT = ws + off; off += N_ * E_;
  float* eu  = ws + off; off += N_ * E_;
  float* euT = ws + off; off += N_ * E_;
  if (ws_size < off * sizeof(float)) return;

  _Float16* Xt    = (_Float16*)XtF;
  _Float16* y1t   = (_Float16*)y1tF;
  _Float16* XG    = (_Float16*)XGF;
  _Float16* Wt    = (_Float16*)WtF;
  _Float16* wpCg  = (_Float16*)wcgF;
  _Float16* wpCu  = (_Float16*)wcuF;
  _Float16* sup16 = (_Float16*)supF;

  hipMemsetAsync(h, 0, SZ_H * sizeof(float), stream);
  k_wprep<<<KP_, 128, 0, stream>>>(gate_wp, OG_, wpCg);
  k_wprep<<<KP_, 128, 0, stream>>>(upd_wp, OU_, wpCu);

  dim3 ggrid(NP_ / 64, N_ / 128);     // (66, 8) = 528 blocks
  dim3 bgrid(B_, N_ / 64);            // (64, 16)
  dim3 wggrid(COLG_ / 1024, 16);      // (28, 16)
  dim3 wugrid(COLU_ / 1024, 16);      // (14, 16)

  for (int t = 0; t < T_; t++) {
    k_compute_e<<<4, 256, 0, stream>>>(node_emb, time_emb, gate_lng, gate_lnb,
                                       upd_lng, upd_lnb, t, eg, egT, eu, euT);
    // ---- gate dagcn ----
    k_sup<<<N_, 256, 0, stream>>>(egT, sup16);
    k_build_gate<<<bgrid, 256, 0, stream>>>(src, h, t, Xt, XG);
    k_gemm_f16<<<ggrid, 256, 0, stream>>>(sup16, Xt, y1t, XG, 65, 0);
    k_gemm_f16<<<ggrid, 256, 0, stream>>>(sup16, y1t, nullptr, XG, 130, 1);
    k_wgen<<<wggrid, 256, 0, stream>>>(eg, wpCg, COLG_, Wt);
    k_contract_gate<<<N_, 256, 0, stream>>>(eg, XG, Wt, gate_bp, z, r);
    // ---- update dagcn ----
    k_sup<<<N_, 256, 0, stream>>>(euT, sup16);
    k_build_upd<<<bgrid, 256, 0, stream>>>(src, h, z, t, Xt, XG);
    k_gemm_f16<<<ggrid, 256, 0, stream>>>(sup16, Xt, y1t, XG, 65, 0);
    k_gemm_f16<<<ggrid, 256, 0, stream>>>(sup16, y1t, nullptr, XG, 130, 1);
    k_wgen<<<wugrid, 256, 0, stream>>>(eu, wpCu, COLU_, Wt);
    k_contract_upd<<<N_, 256, 0, stream>>>(eu, XG, Wt, upd_bp, r, h);
  }
  k_final<<<B_ * N_ / 256, 256, 0, stream>>>(h, out_lng, out_lnb, conv_w, conv_b, out);
}

// Round 6
// 2554.963 us; speedup vs baseline: 4.6147x; 1.1495x over previous
//
#include <hip/hip_runtime.h>
#include <math.h>

namespace {
constexpr int B_ = 64, T_ = 12, N_ = 1024, H_ = 64, E_ = 16;
constexpr int C_  = 65;          // DIN + H
constexpr int BC_ = B_ * C_;     // 4160
constexpr int OG_ = 128;         // gate output = 2H
constexpr int OU_ = 64;          // update output = H
constexpr float EPS_ = 1e-12f;
constexpr int NP_ = 4224;        // BC_ padded for GEMM N-tiling (multiple of 64)
constexpr int KP_ = 224;         // packed contract K: 3*65=195 data + pad to 7*32
constexpr int COLG_ = OG_ * KP_; // 28672
constexpr int COLU_ = OU_ * KP_; // 14336
}

typedef unsigned short u16;
typedef unsigned int u32;
using f16x8 = __attribute__((ext_vector_type(8))) _Float16;
using f16x4 = __attribute__((ext_vector_type(4))) _Float16;
using f32x4 = __attribute__((ext_vector_type(4))) float;

__device__ __forceinline__ u32 div65(u32 x) { return (x * 16135u) >> 20; }  // exact for x<5196

// async global->LDS 16B/lane; LDS dest is wave-uniform base + lane*16.
__device__ __forceinline__ void gl_lds16(const void* g, void* l, int lane) {
#if __has_builtin(__builtin_amdgcn_global_load_lds)
  __builtin_amdgcn_global_load_lds((const __attribute__((address_space(1))) u32*)g,
                                   (__attribute__((address_space(3))) u32*)l, 16, 0, 0);
#else
  *(uint4*)((char*)l + lane * 16) = *(const uint4*)g;
#endif
}

// ---------------------------------------------------------------------------
__global__ void k_compute_e(const float* __restrict__ node_emb,
                            const float* __restrict__ time_emb,
                            const float* __restrict__ g_lng, const float* __restrict__ g_lnb,
                            const float* __restrict__ u_lng, const float* __restrict__ u_lnb,
                            int t,
                            float* __restrict__ eg, float* __restrict__ egT,
                            float* __restrict__ eu, float* __restrict__ euT) {
  int n = blockIdx.x * blockDim.x + threadIdx.x;
  if (n >= N_) return;
  float v[E_];
  float m = 0.f;
#pragma unroll
  for (int d = 0; d < E_; d++) { v[d] = node_emb[n * E_ + d] + time_emb[t * E_ + d]; m += v[d]; }
  m *= (1.0f / E_);
  float var = 0.f;
#pragma unroll
  for (int d = 0; d < E_; d++) { float x = v[d] - m; var += x * x; }
  var *= (1.0f / E_);
  float rs = rsqrtf(var + EPS_);
#pragma unroll
  for (int d = 0; d < E_; d++) {
    float nv = (v[d] - m) * rs;
    float g = nv * g_lng[d] + g_lnb[d];
    float u = nv * u_lng[d] + u_lnb[d];
    eg[n * E_ + d] = g; egT[d * N_ + n] = g;
    eu[n * E_ + d] = u; euT[d * N_ + n] = u;
  }
}

// ---------------------------------------------------------------------------
// Repack wp[d][seg][ii][o] -> wpC[(o*224 + seg*65+ii)][16 d] fp16, pads zeroed.
__global__ __launch_bounds__(128) void k_wprep(const float* __restrict__ wp, int NO,
                                               _Float16* __restrict__ wpC) {
  const int k = blockIdx.x;          // 0..223
  const int o = threadIdx.x;
  if (o >= NO) return;
  f16x8 lo = {}, hi = {};
  if (k < 195) {
    const u32 seg = div65((u32)k);
    const u32 ii = k - seg * 65;
#pragma unroll
    for (int d = 0; d < 8; d++)
      lo[d] = (_Float16)wp[(((size_t)d * 3 + seg) * 65 + ii) * NO + o];
#pragma unroll
    for (int d = 0; d < 8; d++)
      hi[d] = (_Float16)wp[(((size_t)(d + 8) * 3 + seg) * 65 + ii) * NO + o];
  }
  _Float16* dst = &wpC[((size_t)o * KP_ + k) * 16];
  *(f16x8*)dst = lo;
  *(f16x8*)(dst + 8) = hi;
}

// ---------------------------------------------------------------------------
// Shared bodies used by fused prep/post kernels.
__device__ __forceinline__ void sup_body(const float* __restrict__ eT,
                                         _Float16* __restrict__ s16,
                                         int n, int tid, float* red) {
  float en[E_];
#pragma unroll
  for (int d = 0; d < E_; d++) en[d] = eT[d * N_ + n];
  float lg[4];
  float mx = -3.4e38f;
#pragma unroll
  for (int j = 0; j < 4; j++) {
    int m = tid + 256 * j;
    float s = 0.f;
#pragma unroll
    for (int d = 0; d < E_; d++) s = fmaf(en[d], eT[d * N_ + m], s);
    lg[j] = s;
    mx = fmaxf(mx, s);
  }
  red[tid] = mx; __syncthreads();
  for (int off = 128; off > 0; off >>= 1) {
    if (tid < off) red[tid] = fmaxf(red[tid], red[tid + off]);
    __syncthreads();
  }
  mx = red[0]; __syncthreads();
  float sum = 0.f;
#pragma unroll
  for (int j = 0; j < 4; j++) { lg[j] = __expf(lg[j] - mx); sum += lg[j]; }
  red[tid] = sum; __syncthreads();
  for (int off = 128; off > 0; off >>= 1) {
    if (tid < off) red[tid] += red[tid + off];
    __syncthreads();
  }
  float inv = 1.0f / red[0];
#pragma unroll
  for (int j = 0; j < 4; j++)
    s16[(size_t)n * N_ + tid + 256 * j] = (_Float16)(lg[j] * inv);
}

// build: tile[64 m][65 c] already filled -> write Xt [col][m] and xg [n][b][k] + pad.
__device__ __forceinline__ void build_emit(float (*tile)[65], int b, int m0, int tid,
                                           _Float16* __restrict__ Xt,
                                           _Float16* __restrict__ xg) {
  for (int q = 0; q < 17; q++) {
    int idx = tid + q * 256;
    if (idx < 64 * 65) {
      int c = idx >> 6, m = idx & 63;
      Xt[((size_t)(b * C_ + c)) * 1024 + m0 + m] = (_Float16)tile[m][c];
      u32 mm = div65((u32)idx), cc = (u32)idx - mm * 65;
      xg[((size_t)(m0 + mm) * 64 + b) * KP_ + cc] = (_Float16)tile[mm][cc];
    }
  }
#pragma unroll
  for (int q = 0; q < 8; q++) {
    int idx = tid + q * 256;   // < 2048
    int mm = idx >> 5, kk = 192 + (idx & 31);
    xg[((size_t)(m0 + mm) * 64 + b) * KP_ + kk] = (_Float16)0.f;
  }
}

// wgen: Wt[n][col] = sum_d e[n,d]*wpC[col][d] for 64 n, 1024 cols per block.
__device__ __forceinline__ void wgen_body(const float* __restrict__ e,
                                          const _Float16* __restrict__ wpC, int COLS,
                                          _Float16* __restrict__ Wt,
                                          int xb, int yb, int tid, float (*es)[16]) {
  const int col0 = xb * 1024 + tid * 4;
  const int n0 = yb * 64;
#pragma unroll
  for (int q = 0; q < 4; q++) {
    int idx = tid + q * 256;
    es[idx >> 4][idx & 15] = e[(size_t)n0 * 16 + idx];
  }
  __syncthreads();
  float wc[4][16];
#pragma unroll
  for (int cc = 0; cc < 4; cc++) {
    f16x8 a = *(const f16x8*)&wpC[(size_t)(col0 + cc) * 16];
    f16x8 b = *(const f16x8*)&wpC[(size_t)(col0 + cc) * 16 + 8];
#pragma unroll
    for (int d = 0; d < 8; d++) { wc[cc][d] = (float)a[d]; wc[cc][8 + d] = (float)b[d]; }
  }
  for (int nn = 0; nn < 64; nn++) {
    float acc[4] = {};
#pragma unroll
    for (int d = 0; d < 16; d++) {
      float ev = es[nn][d];
#pragma unroll
      for (int cc = 0; cc < 4; cc++) acc[cc] = fmaf(ev, wc[cc][d], acc[cc]);
    }
    f16x4 pv;
#pragma unroll
    for (int cc = 0; cc < 4; cc++) pv[cc] = (_Float16)acc[cc];
    *(f16x4*)&Wt[(size_t)(n0 + nn) * COLS + col0] = pv;
  }
}

// ---------------------------------------------------------------------------
// Fused step-prep: [0,1024) sup_gate, [1024,2048) sup_upd, [2048,3072) build_gate,
// [3072,3520) wgen_gate.  All depend only on compute_e outputs + h(t-1).
__global__ __launch_bounds__(256) void k_prep(
    const float* __restrict__ egT, const float* __restrict__ euT,
    const float* __restrict__ src, const float* __restrict__ h, int t,
    _Float16* __restrict__ supG, _Float16* __restrict__ supU,
    _Float16* __restrict__ Xt, _Float16* __restrict__ xg,
    const float* __restrict__ eg, const _Float16* __restrict__ wpCg,
    _Float16* __restrict__ Wt) {
  __shared__ float smem[64 * 65];
  const int bid = blockIdx.x;
  const int tid = threadIdx.x;
  if (bid < 2048) {
    sup_body(bid < 1024 ? egT : euT, bid < 1024 ? supG : supU, bid & 1023, tid, smem);
  } else if (bid < 3072) {
    const int idx = bid - 2048;
    const int b = idx & 63;
    const int m0 = (idx >> 6) * 64;
    float (*tile)[65] = (float(*)[65])smem;
    {
      const int c = tid & 63, mi = tid >> 6;
#pragma unroll
      for (int p = 0; p < 16; p++) {
        int m = p * 4 + mi;
        tile[m][c + 1] = h[((size_t)b * N_ + m0 + m) * H_ + c];
      }
      if (tid < 64) tile[tid][0] = src[((size_t)b * T_ + t) * N_ + m0 + tid];
    }
    __syncthreads();
    build_emit(tile, b, m0, tid, Xt, xg);
  } else {
    const int widx = bid - 3072;       // 0..447
    wgen_body(eg, wpCg, COLG_, Wt, widx % 28, widx / 28, tid, (float(*)[16])smem);
  }
}

// ---------------------------------------------------------------------------
// Fused post-gate: [0,1024) build_upd (needs z), [1024,1248) wgen_upd.
__global__ __launch_bounds__(256) void k_postg(
    const float* __restrict__ src, const float* __restrict__ h,
    const float* __restrict__ z, int t,
    _Float16* __restrict__ Xt, _Float16* __restrict__ xg,
    const float* __restrict__ eu, const _Float16* __restrict__ wpCu,
    _Float16* __restrict__ Wt) {
  __shared__ float smem[64 * 65];
  const int bid = blockIdx.x;
  const int tid = threadIdx.x;
  if (bid < 1024) {
    const int b = bid & 63;
    const int m0 = (bid >> 6) * 64;
    float (*tile)[65] = (float(*)[65])smem;
    {
      const int c = tid & 63, mi = tid >> 6;
#pragma unroll
      for (int p = 0; p < 16; p++) {
        int m = p * 4 + mi;
        size_t a = ((size_t)b * N_ + m0 + m) * H_ + c;
        tile[m][c + 1] = z[a] * h[a];
      }
      if (tid < 64) tile[tid][0] = src[((size_t)b * T_ + t) * N_ + m0 + tid];
    }
    __syncthreads();
    build_emit(tile, b, m0, tid, Xt, xg);
  } else {
    const int widx = bid - 1024;       // 0..223
    wgen_body(eu, wpCu, COLU_, Wt, widx % 14, widx / 14, tid, (float(*)[16])smem);
  }
}

// ---------------------------------------------------------------------------
// fp16 MFMA GEMM, 128x64 tile, BK=64 (16 iters, 16 MFMA/wave/iter), XOR-swizzled
// LDS (conflict-free b128 reads).  A = sup [m][k]; B = Xt [col][k].
// Epilogue: optional yt [col][row] fp16; XGpad seg write; combine: 2*v - seg0.
__global__ __launch_bounds__(256) void k_gemm_f16(
    const _Float16* __restrict__ A, const _Float16* __restrict__ Bt,
    _Float16* __restrict__ yt, _Float16* __restrict__ xg, int segoff, int combine) {
  __shared__ _Float16 As[128 * 64];   // 16 KB
  __shared__ _Float16 Bs[64 * 64];    // 8 KB
  const int tid  = threadIdx.x;
  const int wave = tid >> 6, lane = tid & 63;
  const int m0 = blockIdx.y * 128, c0 = blockIdx.x * 64;
  const int lrow = lane >> 3;         // row within 8-row staging group
  const int lchunk = lane & 7;        // 16B chunk slot within 128B row
  const int fm = lane & 15, fq = lane >> 4;
  f32x4 acc[2][4] = {};
  for (int ks = 0; ks < 16; ks++) {
    const int kp = ks * 64;
#pragma unroll
    for (int q = 0; q < 4; q++) {          // A: 16 groups of 8 rows
      const int seg = wave * 4 + q;
      const int row = seg * 8 + lrow;
      const int sw = lchunk ^ (row & 7);   // slot s holds global chunk s^(row&7)
      gl_lds16(A + (size_t)(m0 + row) * 1024 + kp + sw * 8, &As[seg * 8 * 64], lane);
    }
#pragma unroll
    for (int q = 0; q < 2; q++) {          // B: 8 groups of 8 rows
      const int seg = wave * 2 + q;
      const int row = seg * 8 + lrow;
      const int sw = lchunk ^ (row & 7);
      gl_lds16(Bt + (size_t)(c0 + row) * 1024 + kp + sw * 8, &Bs[seg * 8 * 64], lane);
    }
    __syncthreads();
#pragma unroll
    for (int kk = 0; kk < 2; kk++) {
      f16x8 af[2], bfr[4];
      const int g = kk * 4 + fq;
#pragma unroll
      for (int mt = 0; mt < 2; mt++) {
        const int row = wave * 32 + mt * 16 + fm;
        af[mt] = *(const f16x8*)&As[row * 64 + (g ^ (row & 7)) * 8];
      }
#pragma unroll
      for (int nt = 0; nt < 4; nt++) {
        const int row = nt * 16 + fm;
        bfr[nt] = *(const f16x8*)&Bs[row * 64 + (g ^ (row & 7)) * 8];
      }
#pragma unroll
      for (int mt = 0; mt < 2; mt++)
#pragma unroll
        for (int nt = 0; nt < 4; nt++)
          acc[mt][nt] = __builtin_amdgcn_mfma_f32_16x16x32_f16(af[mt], bfr[nt], acc[mt][nt], 0, 0, 0);
    }
    __syncthreads();
  }
  const int q4 = fq * 4;
#pragma unroll
  for (int nt = 0; nt < 4; nt++) {
    const int col = c0 + nt * 16 + fm;
    if (col >= BC_) continue;
    const u32 bq = div65((u32)col), cq = (u32)col - bq * 65;
#pragma unroll
    for (int mt = 0; mt < 2; mt++) {
      const int row = m0 + wave * 32 + mt * 16 + q4;
      const f32x4 v = acc[mt][nt];
      if (yt) {
        f16x4 pv;
#pragma unroll
        for (int j = 0; j < 4; j++) pv[j] = (_Float16)v[j];
        *(f16x4*)&yt[(size_t)col * 1024 + row] = pv;
      }
#pragma unroll
      for (int j = 0; j < 4; j++) {
        size_t base = ((size_t)(row + j) * 64 + bq) * KP_;
        float vv = v[j];
        if (combine) vv = 2.f * vv - (float)xg[base + cq];
        xg[base + segoff + cq] = (_Float16)vv;
      }
    }
  }
}

// ---------------------------------------------------------------------------
// Gate contraction: per n, out[64 b][128 o] = XG[n] (64x224) @ Wt[n]^T (224x128).
__global__ __launch_bounds__(256) void k_contract_gate(
    const float* __restrict__ eg,
    const _Float16* __restrict__ XG, const _Float16* __restrict__ Wt,
    const float* __restrict__ bp,
    float* __restrict__ z, float* __restrict__ r) {
  const int n = blockIdx.x;
  const int tid = threadIdx.x;
  const int wave = tid >> 6, lane = tid & 63;
  const int fm = lane & 15, fq = lane >> 4;
  const int wm = wave >> 1, wn = wave & 1;
  __shared__ float es[16];
  __shared__ float bias_s[128];
  if (tid < 16) es[tid] = eg[n * 16 + tid];
  __syncthreads();
  if (tid < 128) {
    float bv = 0.f;
#pragma unroll
    for (int d = 0; d < 16; d++) bv = fmaf(es[d], bp[d * OG_ + tid], bv);
    bias_s[tid] = bv;
  }
  const _Float16* Ab = XG + (size_t)n * 64 * KP_;
  const _Float16* Bb = Wt + (size_t)n * OG_ * KP_;
  f16x8 af[2][2], bf[2][4];
#pragma unroll
  for (int mt = 0; mt < 2; mt++)
    af[0][mt] = *(const f16x8*)&Ab[(wm * 32 + mt * 16 + fm) * KP_ + fq * 8];
#pragma unroll
  for (int nt = 0; nt < 4; nt++)
    bf[0][nt] = *(const f16x8*)&Bb[(wn * 64 + nt * 16 + fm) * KP_ + fq * 8];
  f32x4 acc[2][4] = {};
#pragma unroll
  for (int kk = 0; kk < 7; kk++) {
    const int cur = kk & 1;
    if (kk < 6) {
      const int ko = (kk + 1) * 32 + fq * 8;
#pragma unroll
      for (int mt = 0; mt < 2; mt++)
        af[cur ^ 1][mt] = *(const f16x8*)&Ab[(wm * 32 + mt * 16 + fm) * KP_ + ko];
#pragma unroll
      for (int nt = 0; nt < 4; nt++)
        bf[cur ^ 1][nt] = *(const f16x8*)&Bb[(wn * 64 + nt * 16 + fm) * KP_ + ko];
    }
#pragma unroll
    for (int mt = 0; mt < 2; mt++)
#pragma unroll
      for (int nt = 0; nt < 4; nt++)
        acc[mt][nt] = __builtin_amdgcn_mfma_f32_16x16x32_f16(af[cur][mt], bf[cur][nt], acc[mt][nt], 0, 0, 0);
  }
  __syncthreads();
#pragma unroll
  for (int nt = 0; nt < 4; nt++) {
    const int o = wn * 64 + nt * 16 + fm;
    const float bias = bias_s[o];
#pragma unroll
    for (int mt = 0; mt < 2; mt++) {
      const f32x4 v = acc[mt][nt];
#pragma unroll
      for (int j = 0; j < 4; j++) {
        const int b = wm * 32 + mt * 16 + fq * 4 + j;
        float s = 1.0f / (1.0f + __expf(-(v[j] + bias)));
        size_t oidx = ((size_t)b * N_ + n) * H_;
        if (o < H_) z[oidx + o] = s;
        else        r[oidx + (o - H_)] = s;
      }
    }
  }
}

// ---------------------------------------------------------------------------
// Update contraction + GRU state update. out[64 b][64 o].
__global__ __launch_bounds__(256) void k_contract_upd(
    const float* __restrict__ eu,
    const _Float16* __restrict__ XG, const _Float16* __restrict__ Wt,
    const float* __restrict__ bp,
    const float* __restrict__ r,
    float* __restrict__ h) {
  const int n = blockIdx.x;
  const int tid = threadIdx.x;
  const int wave = tid >> 6, lane = tid & 63;
  const int fm = lane & 15, fq = lane >> 4;
  __shared__ float es[16];
  __shared__ float bias_s[64];
  if (tid < 16) es[tid] = eu[n * 16 + tid];
  __syncthreads();
  if (tid < 64) {
    float bv = 0.f;
#pragma unroll
    for (int d = 0; d < 16; d++) bv = fmaf(es[d], bp[d * OU_ + tid], bv);
    bias_s[tid] = bv;
  }
  const _Float16* Ab = XG + (size_t)n * 64 * KP_;
  const _Float16* Bb = Wt + (size_t)n * OU_ * KP_;
  f16x8 af[2], bf[2][4];
  af[0] = *(const f16x8*)&Ab[(wave * 16 + fm) * KP_ + fq * 8];
#pragma unroll
  for (int nt = 0; nt < 4; nt++)
    bf[0][nt] = *(const f16x8*)&Bb[(nt * 16 + fm) * KP_ + fq * 8];
  f32x4 acc[4] = {};
#pragma unroll
  for (int kk = 0; kk < 7; kk++) {
    const int cur = kk & 1;
    if (kk < 6) {
      const int ko = (kk + 1) * 32 + fq * 8;
      af[cur ^ 1] = *(const f16x8*)&Ab[(wave * 16 + fm) * KP_ + ko];
#pragma unroll
      for (int nt = 0; nt < 4; nt++)
        bf[cur ^ 1][nt] = *(const f16x8*)&Bb[(nt * 16 + fm) * KP_ + ko];
    }
#pragma unroll
    for (int nt = 0; nt < 4; nt++)
      acc[nt] = __builtin_amdgcn_mfma_f32_16x16x32_f16(af[cur], bf[cur][nt], acc[nt], 0, 0, 0);
  }
  __syncthreads();
#pragma unroll
  for (int nt = 0; nt < 4; nt++) {
    const int o = nt * 16 + fm;
    const float bias = bias_s[o];
    const f32x4 v = acc[nt];
#pragma unroll
    for (int j = 0; j < 4; j++) {
      const int b = wave * 16 + fq * 4 + j;
      size_t hi = ((size_t)b * N_ + n) * H_ + o;
      float hc = tanhf(v[j] + bias);
      float rv = r[hi];
      h[hi] = rv * h[hi] + (1.0f - rv) * hc;
    }
  }
}

// ---------------------------------------------------------------------------
// LN(h) + conv, one thread per (b,n).
__global__ __launch_bounds__(256) void k_final(const float* __restrict__ h,
                                               const float* __restrict__ out_lng,
                                               const float* __restrict__ out_lnb,
                                               const float* __restrict__ conv_w,
                                               const float* __restrict__ conv_b,
                                               float* __restrict__ out) {
  const int b = blockIdx.x >> 2;
  const int n = (blockIdx.x & 3) * 256 + threadIdx.x;
  __shared__ float cw[12][64];
  __shared__ float cb[12];
  __shared__ float lgs[64], lbs[64];
  for (int idx = threadIdx.x; idx < 12 * 64; idx += 256) cw[idx >> 6][idx & 63] = conv_w[idx];
  if (threadIdx.x < 12) cb[threadIdx.x] = conv_b[threadIdx.x];
  if (threadIdx.x < 64) { lgs[threadIdx.x] = out_lng[threadIdx.x]; lbs[threadIdx.x] = out_lnb[threadIdx.x]; }
  __syncthreads();
  const float* hp = &h[((size_t)b * N_ + n) * H_];
  float4 hv[16];
  float mean = 0.f;
#pragma unroll
  for (int i = 0; i < 16; i++) {
    hv[i] = *(const float4*)&hp[i * 4];
    mean += hv[i].x + hv[i].y + hv[i].z + hv[i].w;
  }
  mean *= (1.0f / H_);
  float var = 0.f;
#pragma unroll
  for (int i = 0; i < 16; i++) {
    float dx = hv[i].x - mean, dy = hv[i].y - mean, dz = hv[i].z - mean, dw = hv[i].w - mean;
    var += dx * dx + dy * dy + dz * dz + dw * dw;
  }
  var *= (1.0f / H_);
  const float rs = rsqrtf(var + EPS_);
  float y[64];
#pragma unroll
  for (int i = 0; i < 16; i++) {
    y[4 * i + 0] = (hv[i].x - mean) * rs * lgs[4 * i + 0] + lbs[4 * i + 0];
    y[4 * i + 1] = (hv[i].y - mean) * rs * lgs[4 * i + 1] + lbs[4 * i + 1];
    y[4 * i + 2] = (hv[i].z - mean) * rs * lgs[4 * i + 2] + lbs[4 * i + 2];
    y[4 * i + 3] = (hv[i].w - mean) * rs * lgs[4 * i + 3] + lbs[4 * i + 3];
  }
#pragma unroll
  for (int o = 0; o < 12; o++) {
    float acc = cb[o];
#pragma unroll
    for (int i = 0; i < 64; i++) acc = fmaf(y[i], cw[o][i], acc);
    out[((size_t)b * 12 + o) * N_ + n] = acc;
  }
}

// ---------------------------------------------------------------------------
extern "C" void kernel_launch(void* const* d_in, const int* in_sizes, int n_in,
                              void* d_out, int out_size, void* d_ws, size_t ws_size,
                              hipStream_t stream) {
  const float* src      = (const float*)d_in[0];
  const float* node_emb = (const float*)d_in[1];
  const float* time_emb = (const float*)d_in[2];
  const float* gate_wp  = (const float*)d_in[3];
  const float* gate_bp  = (const float*)d_in[4];
  const float* gate_lng = (const float*)d_in[5];
  const float* gate_lnb = (const float*)d_in[6];
  const float* upd_wp   = (const float*)d_in[7];
  const float* upd_bp   = (const float*)d_in[8];
  const float* upd_lng  = (const float*)d_in[9];
  const float* upd_lnb  = (const float*)d_in[10];
  const float* out_lng  = (const float*)d_in[11];
  const float* out_lnb  = (const float*)d_in[12];
  const float* conv_w   = (const float*)d_in[13];
  const float* conv_b   = (const float*)d_in[14];
  float* out = (float*)d_out;

  constexpr size_t SZ_H   = (size_t)B_ * N_ * H_;           // 4,194,304
  constexpr size_t SZ_T   = (size_t)NP_ * 1024 / 2;         // 2,162,688
  constexpr size_t SZ_XG  = (size_t)N_ * 64 * KP_ / 2;      // 7,340,032
  constexpr size_t SZ_WT  = (size_t)N_ * OG_ * KP_ / 2;     // 14,680,064
  constexpr size_t SZ_WCG = (size_t)COLG_ * 16 / 2;         // 229,376
  constexpr size_t SZ_WCU = (size_t)COLU_ * 16 / 2;         // 114,688
  constexpr size_t SZ_S   = (size_t)N_ * N_ / 2;            // 524,288

  float* ws = (float*)d_ws;
  size_t off = 0;
  float* h     = ws + off; off += SZ_H;
  float* z     = ws + off; off += SZ_H;
  float* r     = ws + off; off += SZ_H;
  float* XtF   = ws + off; off += SZ_T;
  float* y1tF  = ws + off; off += SZ_T;
  float* XGF   = ws + off; off += SZ_XG;
  float* WtF   = ws + off; off += SZ_WT;
  float* wcgF  = ws + off; off += SZ_WCG;
  float* wcuF  = ws + off; off += SZ_WCU;
  float* supGF = ws + off; off += SZ_S;
  float* supUF = ws + off; off += SZ_S;
  float* eg  = ws + off; off += N_ * E_;
  float* egT = ws + off; off += N_ * E_;
  float* eu  = ws + off; off += N_ * E_;
  float* euT = ws + off; off += N_ * E_;
  if (ws_size < off * sizeof(float)) return;

  _Float16* Xt    = (_Float16*)XtF;
  _Float16* y1t   = (_Float16*)y1tF;
  _Float16* XG    = (_Float16*)XGF;
  _Float16* Wt    = (_Float16*)WtF;
  _Float16* wpCg  = (_Float16*)wcgF;
  _Float16* wpCu  = (_Float16*)wcuF;
  _Float16* supG  = (_Float16*)supGF;
  _Float16* supU  = (_Float16*)supUF;

  hipMemsetAsync(h, 0, SZ_H * sizeof(float), stream);
  k_wprep<<<KP_, 128, 0, stream>>>(gate_wp, OG_, wpCg);
  k_wprep<<<KP_, 128, 0, stream>>>(upd_wp, OU_, wpCu);

  dim3 ggrid(NP_ / 64, N_ / 128);     // (66, 8) = 528 blocks

  for (int t = 0; t < T_; t++) {
    k_compute_e<<<4, 256, 0, stream>>>(node_emb, time_emb, gate_lng, gate_lnb,
                                       upd_lng, upd_lnb, t, eg, egT, eu, euT);
    k_prep<<<3520, 256, 0, stream>>>(egT, euT, src, h, t, supG, supU, Xt, XG,
                                     eg, wpCg, Wt);
    // ---- gate dagcn ----
    k_gemm_f16<<<ggrid, 256, 0, stream>>>(supG, Xt, y1t, XG, 65, 0);
    k_gemm_f16<<<ggrid, 256, 0, stream>>>(supG, y1t, nullptr, XG, 130, 1);
    k_contract_gate<<<N_, 256, 0, stream>>>(eg, XG, Wt, gate_bp, z, r);
    // ---- update dagcn ----
    k_postg<<<1248, 256, 0, stream>>>(src, h, z, t, Xt, XG, eu, wpCu, Wt);
    k_gemm_f16<<<ggrid, 256, 0, stream>>>(supU, Xt, y1t, XG, 65, 0);
    k_gemm_f16<<<ggrid, 256, 0, stream>>>(supU, y1t, nullptr, XG, 130, 1);
    k_contract_upd<<<N_, 256, 0, stream>>>(eu, XG, Wt, upd_bp, r, h);
  }
  k_final<<<B_ * N_ / 256, 256, 0, stream>>>(h, out_lng, out_lnb, conv_w, conv_b, out);
}

// Round 7
// 2506.947 us; speedup vs baseline: 4.7031x; 1.0192x over previous
//
#include <hip/hip_runtime.h>
#include <math.h>

namespace {
constexpr int B_ = 64, T_ = 12, N_ = 1024, H_ = 64, E_ = 16;
constexpr int C_  = 65;          // DIN + H
constexpr int BC_ = B_ * C_;     // 4160
constexpr int OG_ = 128;         // gate output = 2H
constexpr int OU_ = 64;          // update output = H
constexpr float EPS_ = 1e-12f;
constexpr int NP_ = 4224;        // BC_ padded for GEMM N-tiling
constexpr int KP_ = 224;         // packed contract K: 3*65=195 + pad to 7*32
constexpr int COLG_ = OG_ * KP_; // 28672
constexpr int COLU_ = OU_ * KP_; // 14336
constexpr int NE_ = N_ * E_;     // 16384
}

typedef unsigned short u16;
typedef unsigned int u32;
using f16x8 = __attribute__((ext_vector_type(8))) _Float16;
using f16x4 = __attribute__((ext_vector_type(4))) _Float16;
using f32x4 = __attribute__((ext_vector_type(4))) float;

__device__ __forceinline__ u32 div65(u32 x) { return (x * 16135u) >> 20; }  // exact for x<5196

// async global->LDS 16B/lane; LDS dest is wave-uniform base + lane*16.
__device__ __forceinline__ void gl_lds16(const void* g, void* l, int lane) {
#if __has_builtin(__builtin_amdgcn_global_load_lds)
  __builtin_amdgcn_global_load_lds((const __attribute__((address_space(1))) u32*)g,
                                   (__attribute__((address_space(3))) u32*)l, 16, 0, 0);
#else
  *(uint4*)((char*)l + lane * 16) = *(const uint4*)g;
#endif
}

// ---------------------------------------------------------------------------
// device bodies shared by fused kernels
// ---------------------------------------------------------------------------
__device__ __forceinline__ void wprep_body(const float* __restrict__ wp, int NO,
                                           _Float16* __restrict__ wpC, int k, int tid) {
  if (tid >= NO) return;
  f16x8 lo = {}, hi = {};
  if (k < 195) {
    const u32 seg = div65((u32)k);
    const u32 ii = k - seg * 65;
#pragma unroll
    for (int d = 0; d < 8; d++)
      lo[d] = (_Float16)wp[(((size_t)d * 3 + seg) * 65 + ii) * NO + tid];
#pragma unroll
    for (int d = 0; d < 8; d++)
      hi[d] = (_Float16)wp[(((size_t)(d + 8) * 3 + seg) * 65 + ii) * NO + tid];
  }
  _Float16* dst = &wpC[((size_t)tid * KP_ + k) * 16];
  *(f16x8*)dst = lo;
  *(f16x8*)(dst + 8) = hi;
}

__device__ __forceinline__ void sup_body(const float* __restrict__ eT,
                                         _Float16* __restrict__ s16,
                                         int n, int tid, float* red) {
  float en[E_];
#pragma unroll
  for (int d = 0; d < E_; d++) en[d] = eT[d * N_ + n];
  float lg[4];
  float mx = -3.4e38f;
#pragma unroll
  for (int j = 0; j < 4; j++) {
    int m = tid + 256 * j;
    float s = 0.f;
#pragma unroll
    for (int d = 0; d < E_; d++) s = fmaf(en[d], eT[d * N_ + m], s);
    lg[j] = s;
    mx = fmaxf(mx, s);
  }
  red[tid] = mx; __syncthreads();
  for (int off = 128; off > 0; off >>= 1) {
    if (tid < off) red[tid] = fmaxf(red[tid], red[tid + off]);
    __syncthreads();
  }
  mx = red[0]; __syncthreads();
  float sum = 0.f;
#pragma unroll
  for (int j = 0; j < 4; j++) { lg[j] = __expf(lg[j] - mx); sum += lg[j]; }
  red[tid] = sum; __syncthreads();
  for (int off = 128; off > 0; off >>= 1) {
    if (tid < off) red[tid] += red[tid + off];
    __syncthreads();
  }
  float inv = 1.0f / red[0];
#pragma unroll
  for (int j = 0; j < 4; j++)
    s16[(size_t)n * N_ + tid + 256 * j] = (_Float16)(lg[j] * inv);
}

__device__ __forceinline__ void wgen_body(const float* __restrict__ e,
                                          const _Float16* __restrict__ wpC, int COLS,
                                          _Float16* __restrict__ Wt,
                                          int xb, int yb, int tid, float (*es)[16]) {
  const int col0 = xb * 1024 + tid * 4;
  const int n0 = yb * 64;
#pragma unroll
  for (int q = 0; q < 4; q++) {
    int idx = tid + q * 256;
    es[idx >> 4][idx & 15] = e[(size_t)n0 * 16 + idx];
  }
  __syncthreads();
  float wc[4][16];
#pragma unroll
  for (int cc = 0; cc < 4; cc++) {
    f16x8 a = *(const f16x8*)&wpC[(size_t)(col0 + cc) * 16];
    f16x8 b = *(const f16x8*)&wpC[(size_t)(col0 + cc) * 16 + 8];
#pragma unroll
    for (int d = 0; d < 8; d++) { wc[cc][d] = (float)a[d]; wc[cc][8 + d] = (float)b[d]; }
  }
  for (int nn = 0; nn < 64; nn++) {
    float acc[4] = {};
#pragma unroll
    for (int d = 0; d < 16; d++) {
      float ev = es[nn][d];
#pragma unroll
      for (int cc = 0; cc < 4; cc++) acc[cc] = fmaf(ev, wc[cc][d], acc[cc]);
    }
    f16x4 pv;
#pragma unroll
    for (int cc = 0; cc < 4; cc++) pv[cc] = (_Float16)acc[cc];
    *(f16x4*)&Wt[(size_t)(n0 + nn) * COLS + col0] = pv;
  }
}

// fp16 MFMA GEMM body, 128x64 tile, BK=64, XOR-swizzled LDS.
__device__ __forceinline__ void gemm_body(
    const _Float16* __restrict__ A, const _Float16* __restrict__ Bt,
    _Float16* __restrict__ yt, _Float16* xg, int segoff, int combine,
    int bx, int by, int tid, _Float16* As, _Float16* Bs) {
  const int wave = tid >> 6, lane = tid & 63;
  const int m0 = by * 128, c0 = bx * 64;
  const int lrow = lane >> 3;
  const int lchunk = lane & 7;
  const int fm = lane & 15, fq = lane >> 4;
  f32x4 acc[2][4] = {};
  for (int ks = 0; ks < 16; ks++) {
    const int kp = ks * 64;
#pragma unroll
    for (int q = 0; q < 4; q++) {          // A: 16 groups of 8 rows
      const int seg = wave * 4 + q;
      const int row = seg * 8 + lrow;
      const int sw = lchunk ^ (row & 7);
      gl_lds16(A + (size_t)(m0 + row) * 1024 + kp + sw * 8, &As[seg * 8 * 64], lane);
    }
#pragma unroll
    for (int q = 0; q < 2; q++) {          // B: 8 groups of 8 rows
      const int seg = wave * 2 + q;
      const int row = seg * 8 + lrow;
      const int sw = lchunk ^ (row & 7);
      gl_lds16(Bt + (size_t)(c0 + row) * 1024 + kp + sw * 8, &Bs[seg * 8 * 64], lane);
    }
    __syncthreads();
#pragma unroll
    for (int kk = 0; kk < 2; kk++) {
      f16x8 af[2], bfr[4];
      const int g = kk * 4 + fq;
#pragma unroll
      for (int mt = 0; mt < 2; mt++) {
        const int row = wave * 32 + mt * 16 + fm;
        af[mt] = *(const f16x8*)&As[row * 64 + (g ^ (row & 7)) * 8];
      }
#pragma unroll
      for (int nt = 0; nt < 4; nt++) {
        const int row = nt * 16 + fm;
        bfr[nt] = *(const f16x8*)&Bs[row * 64 + (g ^ (row & 7)) * 8];
      }
#pragma unroll
      for (int mt = 0; mt < 2; mt++)
#pragma unroll
        for (int nt = 0; nt < 4; nt++)
          acc[mt][nt] = __builtin_amdgcn_mfma_f32_16x16x32_f16(af[mt], bfr[nt], acc[mt][nt], 0, 0, 0);
    }
    __syncthreads();
  }
  const int q4 = fq * 4;
#pragma unroll
  for (int nt = 0; nt < 4; nt++) {
    const int col = c0 + nt * 16 + fm;
    if (col >= BC_) continue;
    const u32 bq = div65((u32)col), cq = (u32)col - bq * 65;
#pragma unroll
    for (int mt = 0; mt < 2; mt++) {
      const int row = m0 + wave * 32 + mt * 16 + q4;
      const f32x4 v = acc[mt][nt];
      if (yt) {
        f16x4 pv;
#pragma unroll
        for (int j = 0; j < 4; j++) pv[j] = (_Float16)v[j];
        *(f16x4*)&yt[(size_t)col * 1024 + row] = pv;
      }
#pragma unroll
      for (int j = 0; j < 4; j++) {
        size_t base = ((size_t)(row + j) * 64 + bq) * KP_;
        float vv = v[j];
        if (combine) vv = 2.f * vv - (float)xg[base + cq];
        xg[base + segoff + cq] = (_Float16)vv;
      }
    }
  }
}

// ---------------------------------------------------------------------------
// Prologue 1: wprep gate [0,224), wprep upd [224,448), compute_e all t [448,496).
__global__ __launch_bounds__(256) void k_pre0(
    const float* __restrict__ gate_wp, const float* __restrict__ upd_wp,
    _Float16* __restrict__ wpCg, _Float16* __restrict__ wpCu,
    const float* __restrict__ node_emb, const float* __restrict__ time_emb,
    const float* __restrict__ g_lng, const float* __restrict__ g_lnb,
    const float* __restrict__ u_lng, const float* __restrict__ u_lnb,
    float* __restrict__ eg_all, float* __restrict__ egT_all,
    float* __restrict__ eu_all, float* __restrict__ euT_all) {
  const int bid = blockIdx.x, tid = threadIdx.x;
  if (bid < KP_)     { wprep_body(gate_wp, OG_, wpCg, bid, tid); return; }
  if (bid < 2 * KP_) { wprep_body(upd_wp,  OU_, wpCu, bid - KP_, tid); return; }
  const int idx = bid - 2 * KP_;          // 0..47
  const int t = idx >> 2;
  const int n = (idx & 3) * 256 + tid;
  float v[E_];
  float m = 0.f;
#pragma unroll
  for (int d = 0; d < E_; d++) { v[d] = node_emb[n * E_ + d] + time_emb[t * E_ + d]; m += v[d]; }
  m *= (1.0f / E_);
  float var = 0.f;
#pragma unroll
  for (int d = 0; d < E_; d++) { float x = v[d] - m; var += x * x; }
  var *= (1.0f / E_);
  float rs = rsqrtf(var + EPS_);
#pragma unroll
  for (int d = 0; d < E_; d++) {
    float nv = (v[d] - m) * rs;
    float g = nv * g_lng[d] + g_lnb[d];
    float u = nv * u_lng[d] + u_lnb[d];
    eg_all[(size_t)t * NE_ + n * E_ + d] = g;
    egT_all[(size_t)t * NE_ + d * N_ + n] = g;
    eu_all[(size_t)t * NE_ + n * E_ + d] = u;
    euT_all[(size_t)t * NE_ + d * N_ + n] = u;
  }
}

// ---------------------------------------------------------------------------
// Prologue 2: sup gate t=0 [0,1024), sup upd t=0 [1024,2048),
// build0 (gate X = [x_0 | 0], pads zeroed) [2048,3072).
__global__ __launch_bounds__(256) void k_pro(
    const float* __restrict__ egT0, const float* __restrict__ euT0,
    const float* __restrict__ src,
    _Float16* __restrict__ supG, _Float16* __restrict__ supU0,
    _Float16* __restrict__ Xt, _Float16* __restrict__ xg) {
  __shared__ float red[256];
  const int bid = blockIdx.x, tid = threadIdx.x;
  if (bid < 1024) { sup_body(egT0, supG, bid, tid, red); return; }
  if (bid < 2048) { sup_body(euT0, supU0, bid - 1024, tid, red); return; }
  const int idx = bid - 2048;
  const int b = idx & 63, m0 = (idx >> 6) * 64;
  for (int q = 0; q < 17; q++) {
    int i = tid + q * 256;
    if (i < 64 * 65) {
      int c = i >> 6, m = i & 63;
      float xv = (c == 0) ? src[((size_t)b * T_) * N_ + m0 + m] : 0.f;
      Xt[((size_t)(b * C_ + c)) * 1024 + m0 + m] = (_Float16)xv;
      u32 mm = div65((u32)i), cc = (u32)i - mm * 65;
      float xv2 = (cc == 0) ? src[((size_t)b * T_) * N_ + m0 + mm] : 0.f;
      xg[((size_t)(m0 + mm) * 64 + b) * KP_ + cc] = (_Float16)xv2;
    }
  }
#pragma unroll
  for (int q = 0; q < 8; q++) {
    int i = tid + q * 256;
    int mm = i >> 5, kk = 192 + (i & 31);
    xg[((size_t)(m0 + mm) * 64 + b) * KP_ + kk] = (_Float16)0.f;
  }
}

// ---------------------------------------------------------------------------
// gemm gate1 [0,528) + wgen gate [528,976)
__global__ __launch_bounds__(256) void k_g1(
    const _Float16* __restrict__ supG, const _Float16* __restrict__ Xt,
    _Float16* __restrict__ y1t, _Float16* xg,
    const float* __restrict__ eg_t, const _Float16* __restrict__ wpCg,
    _Float16* __restrict__ WtG) {
  __shared__ __align__(16) _Float16 smem[12288];
  const int bid = blockIdx.x, tid = threadIdx.x;
  if (bid < 528) {
    gemm_body(supG, Xt, y1t, xg, 65, 0, bid % 66, bid / 66, tid, smem, smem + 8192);
  } else {
    const int w = bid - 528;
    wgen_body(eg_t, wpCg, COLG_, WtG, w % 28, w / 28, tid, (float(*)[16])smem);
  }
}

// gemm gate2 (combine)
__global__ __launch_bounds__(256) void k_g2(
    const _Float16* __restrict__ supG, const _Float16* __restrict__ y1t,
    _Float16* xg) {
  __shared__ __align__(16) _Float16 smem[12288];
  gemm_body(supG, y1t, nullptr, xg, 130, 1, blockIdx.x % 66, blockIdx.x / 66,
            threadIdx.x, smem, smem + 8192);
}

// gemm upd1 [0,528) + wgen upd [528,752)
__global__ __launch_bounds__(256) void k_g3(
    const _Float16* __restrict__ supU, const _Float16* __restrict__ Xt,
    _Float16* __restrict__ y1t, _Float16* xg,
    const float* __restrict__ eu_t, const _Float16* __restrict__ wpCu,
    _Float16* __restrict__ WtU) {
  __shared__ __align__(16) _Float16 smem[12288];
  const int bid = blockIdx.x, tid = threadIdx.x;
  if (bid < 528) {
    gemm_body(supU, Xt, y1t, xg, 65, 0, bid % 66, bid / 66, tid, smem, smem + 8192);
  } else {
    const int w = bid - 528;
    wgen_body(eu_t, wpCu, COLU_, WtU, w % 14, w / 14, tid, (float(*)[16])smem);
  }
}

// gemm upd2 [0,528) + sup(t+1) gate [528,1552) + sup(t+1) upd [1552,2576)
__global__ __launch_bounds__(256) void k_g4(
    const _Float16* __restrict__ supU, const _Float16* __restrict__ y1t,
    _Float16* xg,
    const float* __restrict__ egT_nx, const float* __restrict__ euT_nx,
    _Float16* __restrict__ supG, _Float16* __restrict__ supU_nx, int dosup) {
  __shared__ __align__(16) _Float16 smem[12288];
  const int bid = blockIdx.x, tid = threadIdx.x;
  if (bid < 528) {
    gemm_body(supU, y1t, nullptr, xg, 130, 1, bid % 66, bid / 66, tid, smem, smem + 8192);
  } else if (dosup) {
    if (bid < 1552) sup_body(egT_nx, supG, bid - 528, tid, (float*)smem);
    else            sup_body(euT_nx, supU_nx, bid - 1552, tid, (float*)smem);
  }
}

// ---------------------------------------------------------------------------
// Fused gate contract: MFMA zr -> z in LDS, r to global fp16; then u = z*h
// written straight into upd inputs (Xt, xg seg0 + src col).
__global__ __launch_bounds__(256) void k_cg(
    const float* __restrict__ eg, const _Float16* XG,
    const _Float16* __restrict__ Wt, const float* __restrict__ bp,
    const float* __restrict__ h, const float* __restrict__ src, int t,
    _Float16* __restrict__ r16, _Float16* __restrict__ Xt, _Float16* xgo) {
  const int n = blockIdx.x;
  const int tid = threadIdx.x;
  const int wave = tid >> 6, lane = tid & 63;
  const int fm = lane & 15, fq = lane >> 4;
  const int wm = wave >> 1, wn = wave & 1;
  __shared__ float es[16];
  __shared__ float bias_s[128];
  __shared__ float zs[64][68];
  if (tid < 16) es[tid] = eg[n * 16 + tid];
  __syncthreads();
  if (tid < 128) {
    float bv = 0.f;
#pragma unroll
    for (int d = 0; d < 16; d++) bv = fmaf(es[d], bp[d * OG_ + tid], bv);
    bias_s[tid] = bv;
  }
  const _Float16* Ab = XG + (size_t)n * 64 * KP_;
  const _Float16* Bb = Wt + (size_t)n * OG_ * KP_;
  f16x8 af[2][2], bf[2][4];
#pragma unroll
  for (int mt = 0; mt < 2; mt++)
    af[0][mt] = *(const f16x8*)&Ab[(wm * 32 + mt * 16 + fm) * KP_ + fq * 8];
#pragma unroll
  for (int nt = 0; nt < 4; nt++)
    bf[0][nt] = *(const f16x8*)&Bb[(wn * 64 + nt * 16 + fm) * KP_ + fq * 8];
  f32x4 acc[2][4] = {};
#pragma unroll
  for (int kk = 0; kk < 7; kk++) {
    const int cur = kk & 1;
    if (kk < 6) {
      const int ko = (kk + 1) * 32 + fq * 8;
#pragma unroll
      for (int mt = 0; mt < 2; mt++)
        af[cur ^ 1][mt] = *(const f16x8*)&Ab[(wm * 32 + mt * 16 + fm) * KP_ + ko];
#pragma unroll
      for (int nt = 0; nt < 4; nt++)
        bf[cur ^ 1][nt] = *(const f16x8*)&Bb[(wn * 64 + nt * 16 + fm) * KP_ + ko];
    }
#pragma unroll
    for (int mt = 0; mt < 2; mt++)
#pragma unroll
      for (int nt = 0; nt < 4; nt++)
        acc[mt][nt] = __builtin_amdgcn_mfma_f32_16x16x32_f16(af[cur][mt], bf[cur][nt], acc[mt][nt], 0, 0, 0);
  }
  __syncthreads();
#pragma unroll
  for (int nt = 0; nt < 4; nt++) {
    const int o = wn * 64 + nt * 16 + fm;
    const float bias = bias_s[o];
#pragma unroll
    for (int mt = 0; mt < 2; mt++) {
      const f32x4 v = acc[mt][nt];
#pragma unroll
      for (int j = 0; j < 4; j++) {
        const int b = wm * 32 + mt * 16 + fq * 4 + j;
        float s = 1.0f / (1.0f + __expf(-(v[j] + bias)));
        if (wn == 0) zs[b][o] = s;
        else r16[((size_t)b * N_ + n) * H_ + (o - H_)] = (_Float16)s;
      }
    }
  }
  __syncthreads();
  {
    const int b = tid >> 2, q = tid & 3;
    const float* hp = &h[((size_t)b * N_ + n) * H_ + q * 16];
    _Float16* xp = &xgo[((size_t)n * 64 + b) * KP_ + 1 + q * 16];
#pragma unroll
    for (int i4 = 0; i4 < 4; i4++) {
      const float4 hv = *(const float4*)(hp + i4 * 4);
      const int ob = q * 16 + i4 * 4;
      float u0 = zs[b][ob + 0] * hv.x;
      float u1 = zs[b][ob + 1] * hv.y;
      float u2 = zs[b][ob + 2] * hv.z;
      float u3 = zs[b][ob + 3] * hv.w;
      xp[i4 * 4 + 0] = (_Float16)u0;
      xp[i4 * 4 + 1] = (_Float16)u1;
      xp[i4 * 4 + 2] = (_Float16)u2;
      xp[i4 * 4 + 3] = (_Float16)u3;
      Xt[((size_t)(b * C_ + 1 + ob + 0)) * 1024 + n] = (_Float16)u0;
      Xt[((size_t)(b * C_ + 1 + ob + 1)) * 1024 + n] = (_Float16)u1;
      Xt[((size_t)(b * C_ + 1 + ob + 2)) * 1024 + n] = (_Float16)u2;
      Xt[((size_t)(b * C_ + 1 + ob + 3)) * 1024 + n] = (_Float16)u3;
    }
    if (tid < 64) {
      float sv = src[((size_t)tid * T_ + t) * N_ + n];
      xgo[((size_t)n * 64 + tid) * KP_] = (_Float16)sv;
      Xt[((size_t)(tid * C_)) * 1024 + n] = (_Float16)sv;
    }
  }
}

// ---------------------------------------------------------------------------
// Fused upd contract: MFMA hc; h_new = r*h + (1-r)*hc via LDS; writes h
// (coalesced) and (t<11) next gate inputs (Xt, xg seg0 + src col).
__global__ __launch_bounds__(256) void k_cu(
    const float* __restrict__ eu, const _Float16* XG,
    const _Float16* __restrict__ Wt, const float* __restrict__ bp,
    const _Float16* __restrict__ r16, const float* __restrict__ src,
    int t, int donext,
    float* __restrict__ h, _Float16* __restrict__ Xt, _Float16* xgo) {
  const int n = blockIdx.x;
  const int tid = threadIdx.x;
  const int wave = tid >> 6, lane = tid & 63;
  const int fm = lane & 15, fq = lane >> 4;
  __shared__ float es[16];
  __shared__ float bias_s[64];
  __shared__ float hs[64][68];
  __shared__ float rs[64][68];
  if (tid < 16) es[tid] = eu[n * 16 + tid];
  __syncthreads();
  if (tid < 64) {
    float bv = 0.f;
#pragma unroll
    for (int d = 0; d < 16; d++) bv = fmaf(es[d], bp[d * OU_ + tid], bv);
    bias_s[tid] = bv;
  }
  {
    const int b = tid >> 2, q = tid & 3;
    const float* hp = &h[((size_t)b * N_ + n) * H_ + q * 16];
    const _Float16* rp = &r16[((size_t)b * N_ + n) * H_ + q * 16];
#pragma unroll
    for (int i4 = 0; i4 < 4; i4++) {
      const float4 hv = *(const float4*)(hp + i4 * 4);
      const int ob = q * 16 + i4 * 4;
      hs[b][ob + 0] = hv.x; hs[b][ob + 1] = hv.y;
      hs[b][ob + 2] = hv.z; hs[b][ob + 3] = hv.w;
    }
    f16x8 r0 = *(const f16x8*)rp;
    f16x8 r1 = *(const f16x8*)(rp + 8);
#pragma unroll
    for (int i = 0; i < 8; i++) {
      rs[b][q * 16 + i] = (float)r0[i];
      rs[b][q * 16 + 8 + i] = (float)r1[i];
    }
  }
  __syncthreads();
  const _Float16* Ab = XG + (size_t)n * 64 * KP_;
  const _Float16* Bb = Wt + (size_t)n * OU_ * KP_;
  f16x8 af[2], bf[2][4];
  af[0] = *(const f16x8*)&Ab[(wave * 16 + fm) * KP_ + fq * 8];
#pragma unroll
  for (int nt = 0; nt < 4; nt++)
    bf[0][nt] = *(const f16x8*)&Bb[(nt * 16 + fm) * KP_ + fq * 8];
  f32x4 acc[4] = {};
#pragma unroll
  for (int kk = 0; kk < 7; kk++) {
    const int cur = kk & 1;
    if (kk < 6) {
      const int ko = (kk + 1) * 32 + fq * 8;
      af[cur ^ 1] = *(const f16x8*)&Ab[(wave * 16 + fm) * KP_ + ko];
#pragma unroll
      for (int nt = 0; nt < 4; nt++)
        bf[cur ^ 1][nt] = *(const f16x8*)&Bb[(nt * 16 + fm) * KP_ + ko];
    }
#pragma unroll
    for (int nt = 0; nt < 4; nt++)
      acc[nt] = __builtin_amdgcn_mfma_f32_16x16x32_f16(af[cur], bf[cur][nt], acc[nt], 0, 0, 0);
  }
#pragma unroll
  for (int nt = 0; nt < 4; nt++) {
    const int o = nt * 16 + fm;
    const float bias = bias_s[o];
    const f32x4 v = acc[nt];
#pragma unroll
    for (int j = 0; j < 4; j++) {
      const int b = wave * 16 + fq * 4 + j;
      float hc = tanhf(v[j] + bias);
      float rv = rs[b][o];
      hs[b][o] = rv * hs[b][o] + (1.0f - rv) * hc;
    }
  }
  __syncthreads();
  {
    const int b = tid >> 2, q = tid & 3;
    float* hp = &h[((size_t)b * N_ + n) * H_ + q * 16];
#pragma unroll
    for (int i4 = 0; i4 < 4; i4++) {
      const int ob = q * 16 + i4 * 4;
      float4 hv = make_float4(hs[b][ob], hs[b][ob + 1], hs[b][ob + 2], hs[b][ob + 3]);
      *(float4*)(hp + i4 * 4) = hv;
    }
    if (donext) {
      _Float16* xp = &xgo[((size_t)n * 64 + b) * KP_ + 1 + q * 16];
#pragma unroll
      for (int i = 0; i < 16; i++) {
        _Float16 hv16 = (_Float16)hs[b][q * 16 + i];
        xp[i] = hv16;
        Xt[((size_t)(b * C_ + 1 + q * 16 + i)) * 1024 + n] = hv16;
      }
      if (tid < 64) {
        float sv = src[((size_t)tid * T_ + (t + 1)) * N_ + n];
        xgo[((size_t)n * 64 + tid) * KP_] = (_Float16)sv;
        Xt[((size_t)(tid * C_)) * 1024 + n] = (_Float16)sv;
      }
    }
  }
}

// ---------------------------------------------------------------------------
// LN(h) + conv, one thread per (b,n).
__global__ __launch_bounds__(256) void k_final(const float* __restrict__ h,
                                               const float* __restrict__ out_lng,
                                               const float* __restrict__ out_lnb,
                                               const float* __restrict__ conv_w,
                                               const float* __restrict__ conv_b,
                                               float* __restrict__ out) {
  const int b = blockIdx.x >> 2;
  const int n = (blockIdx.x & 3) * 256 + threadIdx.x;
  __shared__ float cw[12][64];
  __shared__ float cb[12];
  __shared__ float lgs[64], lbs[64];
  for (int idx = threadIdx.x; idx < 12 * 64; idx += 256) cw[idx >> 6][idx & 63] = conv_w[idx];
  if (threadIdx.x < 12) cb[threadIdx.x] = conv_b[threadIdx.x];
  if (threadIdx.x < 64) { lgs[threadIdx.x] = out_lng[threadIdx.x]; lbs[threadIdx.x] = out_lnb[threadIdx.x]; }
  __syncthreads();
  const float* hp = &h[((size_t)b * N_ + n) * H_];
  float4 hv[16];
  float mean = 0.f;
#pragma unroll
  for (int i = 0; i < 16; i++) {
    hv[i] = *(const float4*)&hp[i * 4];
    mean += hv[i].x + hv[i].y + hv[i].z + hv[i].w;
  }
  mean *= (1.0f / H_);
  float var = 0.f;
#pragma unroll
  for (int i = 0; i < 16; i++) {
    float dx = hv[i].x - mean, dy = hv[i].y - mean, dz = hv[i].z - mean, dw = hv[i].w - mean;
    var += dx * dx + dy * dy + dz * dz + dw * dw;
  }
  var *= (1.0f / H_);
  const float rs = rsqrtf(var + EPS_);
  float y[64];
#pragma unroll
  for (int i = 0; i < 16; i++) {
    y[4 * i + 0] = (hv[i].x - mean) * rs * lgs[4 * i + 0] + lbs[4 * i + 0];
    y[4 * i + 1] = (hv[i].y - mean) * rs * lgs[4 * i + 1] + lbs[4 * i + 1];
    y[4 * i + 2] = (hv[i].z - mean) * rs * lgs[4 * i + 2] + lbs[4 * i + 2];
    y[4 * i + 3] = (hv[i].w - mean) * rs * lgs[4 * i + 3] + lbs[4 * i + 3];
  }
#pragma unroll
  for (int o = 0; o < 12; o++) {
    float acc = cb[o];
#pragma unroll
    for (int i = 0; i < 64; i++) acc = fmaf(y[i], cw[o][i], acc);
    out[((size_t)b * 12 + o) * N_ + n] = acc;
  }
}

// ---------------------------------------------------------------------------
extern "C" void kernel_launch(void* const* d_in, const int* in_sizes, int n_in,
                              void* d_out, int out_size, void* d_ws, size_t ws_size,
                              hipStream_t stream) {
  const float* src      = (const float*)d_in[0];
  const float* node_emb = (const float*)d_in[1];
  const float* time_emb = (const float*)d_in[2];
  const float* gate_wp  = (const float*)d_in[3];
  const float* gate_bp  = (const float*)d_in[4];
  const float* gate_lng = (const float*)d_in[5];
  const float* gate_lnb = (const float*)d_in[6];
  const float* upd_wp   = (const float*)d_in[7];
  const float* upd_bp   = (const float*)d_in[8];
  const float* upd_lng  = (const float*)d_in[9];
  const float* upd_lnb  = (const float*)d_in[10];
  const float* out_lng  = (const float*)d_in[11];
  const float* out_lnb  = (const float*)d_in[12];
  const float* conv_w   = (const float*)d_in[13];
  const float* conv_b   = (const float*)d_in[14];
  float* out = (float*)d_out;

  constexpr size_t SZ_H   = (size_t)B_ * N_ * H_;        // 4,194,304
  constexpr size_t SZ_R   = SZ_H / 2;                    // r fp16: 2,097,152 slots
  constexpr size_t SZ_T   = (size_t)NP_ * 1024 / 2;      // 2,162,688
  constexpr size_t SZ_XG  = (size_t)N_ * 64 * KP_ / 2;   // 7,340,032
  constexpr size_t SZ_WT  = (size_t)N_ * OG_ * KP_ / 2;  // 14,680,064 (WtU aliases 1st half)
  constexpr size_t SZ_WCG = (size_t)COLG_ * 16 / 2;      // 229,376
  constexpr size_t SZ_WCU = (size_t)COLU_ * 16 / 2;      // 114,688
  constexpr size_t SZ_S   = (size_t)N_ * N_ / 2;         // 524,288 (fp16 sup in float slots)

  float* ws = (float*)d_ws;
  size_t off = 0;
  float* h      = ws + off; off += SZ_H;
  float* r16F   = ws + off; off += SZ_R;
  float* XtF    = ws + off; off += SZ_T;
  float* y1tF   = ws + off; off += SZ_T;
  float* xgF    = ws + off; off += SZ_XG;
  float* WtF    = ws + off; off += SZ_WT;
  float* wcgF   = ws + off; off += SZ_WCG;
  float* wcuF   = ws + off; off += SZ_WCU;
  float* supGF  = ws + off; off += SZ_S;
  float* supUF  = ws + off; off += 2 * SZ_S;     // double-buffered
  float* eg_all  = ws + off; off += (size_t)T_ * NE_;
  float* egT_all = ws + off; off += (size_t)T_ * NE_;
  float* eu_all  = ws + off; off += (size_t)T_ * NE_;
  float* euT_all = ws + off; off += (size_t)T_ * NE_;
  if (ws_size < off * sizeof(float)) return;     // ~141.4 MB

  _Float16* r16  = (_Float16*)r16F;
  _Float16* Xt   = (_Float16*)XtF;
  _Float16* y1t  = (_Float16*)y1tF;
  _Float16* xg   = (_Float16*)xgF;
  _Float16* WtG  = (_Float16*)WtF;
  _Float16* WtU  = (_Float16*)WtF;               // aliases WtG's dead 1st half
  _Float16* wpCg = (_Float16*)wcgF;
  _Float16* wpCu = (_Float16*)wcuF;
  _Float16* supG = (_Float16*)supGF;
  _Float16* supU = (_Float16*)supUF;

  hipMemsetAsync(h, 0, SZ_H * sizeof(float), stream);
  k_pre0<<<2 * KP_ + 48, 256, 0, stream>>>(gate_wp, upd_wp, wpCg, wpCu,
                                           node_emb, time_emb,
                                           gate_lng, gate_lnb, upd_lng, upd_lnb,
                                           eg_all, egT_all, eu_all, euT_all);
  k_pro<<<3072, 256, 0, stream>>>(egT_all, euT_all, src, supG, supU, Xt, xg);

  for (int t = 0; t < T_; t++) {
    _Float16* sU  = supU + (size_t)(t & 1) * N_ * N_;
    _Float16* sUn = supU + (size_t)((t + 1) & 1) * N_ * N_;
    const float* eg_t = eg_all + (size_t)t * NE_;
    const float* eu_t = eu_all + (size_t)t * NE_;
    const int tn = (t < T_ - 1) ? t + 1 : t;
    const int more = (t < T_ - 1) ? 1 : 0;
    k_g1<<<976, 256, 0, stream>>>(supG, Xt, y1t, xg, eg_t, wpCg, WtG);
    k_g2<<<528, 256, 0, stream>>>(supG, y1t, xg);
    k_cg<<<N_, 256, 0, stream>>>(eg_t, xg, WtG, gate_bp, h, src, t, r16, Xt, xg);
    k_g3<<<752, 256, 0, stream>>>(sU, Xt, y1t, xg, eu_t, wpCu, WtU);
    k_g4<<<2576, 256, 0, stream>>>(sU, y1t, xg,
                                   egT_all + (size_t)tn * NE_,
                                   euT_all + (size_t)tn * NE_,
                                   supG, sUn, more);
    k_cu<<<N_, 256, 0, stream>>>(eu_t, xg, WtU, upd_bp, r16, src, t, more,
                                 h, Xt, xg);
  }
  k_final<<<B_ * N_ / 256, 256, 0, stream>>>(h, out_lng, out_lnb, conv_w, conv_b, out);
}

// Round 8
// 2120.742 us; speedup vs baseline: 5.5596x; 1.1821x over previous
//
#include <hip/hip_runtime.h>
#include <math.h>

namespace {
constexpr int B_ = 64, T_ = 12, N_ = 1024, H_ = 64, E_ = 16;
constexpr int C_  = 65;          // DIN + H
constexpr int BC_ = B_ * C_;     // 4160
constexpr int OG_ = 128;         // gate output = 2H
constexpr int OU_ = 64;          // update output = H
constexpr float EPS_ = 1e-12f;
constexpr int NP_ = 4224;        // BC_ padded for GEMM N-tiling
constexpr int KP_ = 224;         // packed contract K: 3*65=195 + pad to 7*32
constexpr int COLG_ = OG_ * KP_; // 28672
constexpr int COLU_ = OU_ * KP_; // 14336
constexpr int NE_ = N_ * E_;     // 16384
}

typedef unsigned short u16;
typedef unsigned int u32;
using f16x8 = __attribute__((ext_vector_type(8))) _Float16;
using f16x4 = __attribute__((ext_vector_type(4))) _Float16;
using f32x4 = __attribute__((ext_vector_type(4))) float;

__device__ __forceinline__ u32 div65(u32 x) { return (x * 16135u) >> 20; }  // exact for x<5196

// async global->LDS 16B/lane; LDS dest is wave-uniform base + lane*16.
__device__ __forceinline__ void gl_lds16(const void* g, void* l, int lane) {
#if __has_builtin(__builtin_amdgcn_global_load_lds)
  __builtin_amdgcn_global_load_lds((const __attribute__((address_space(1))) u32*)g,
                                   (__attribute__((address_space(3))) u32*)l, 16, 0, 0);
#else
  *(uint4*)((char*)l + lane * 16) = *(const uint4*)g;
#endif
}

// ---------------------------------------------------------------------------
// device bodies shared by fused kernels
// ---------------------------------------------------------------------------
__device__ __forceinline__ void wprep_body(const float* __restrict__ wp, int NO,
                                           _Float16* __restrict__ wpC, int k, int tid) {
  if (tid >= NO) return;
  f16x8 lo = {}, hi = {};
  if (k < 195) {
    const u32 seg = div65((u32)k);
    const u32 ii = k - seg * 65;
#pragma unroll
    for (int d = 0; d < 8; d++)
      lo[d] = (_Float16)wp[(((size_t)d * 3 + seg) * 65 + ii) * NO + tid];
#pragma unroll
    for (int d = 0; d < 8; d++)
      hi[d] = (_Float16)wp[(((size_t)(d + 8) * 3 + seg) * 65 + ii) * NO + tid];
  }
  _Float16* dst = &wpC[((size_t)tid * KP_ + k) * 16];
  *(f16x8*)dst = lo;
  *(f16x8*)(dst + 8) = hi;
}

__device__ __forceinline__ void sup_body(const float* __restrict__ eT,
                                         _Float16* __restrict__ s16,
                                         int n, int tid, float* red) {
  float en[E_];
#pragma unroll
  for (int d = 0; d < E_; d++) en[d] = eT[d * N_ + n];
  float lg[4];
  float mx = -3.4e38f;
#pragma unroll
  for (int j = 0; j < 4; j++) {
    int m = tid + 256 * j;
    float s = 0.f;
#pragma unroll
    for (int d = 0; d < E_; d++) s = fmaf(en[d], eT[d * N_ + m], s);
    lg[j] = s;
    mx = fmaxf(mx, s);
  }
  red[tid] = mx; __syncthreads();
  for (int off = 128; off > 0; off >>= 1) {
    if (tid < off) red[tid] = fmaxf(red[tid], red[tid + off]);
    __syncthreads();
  }
  mx = red[0]; __syncthreads();
  float sum = 0.f;
#pragma unroll
  for (int j = 0; j < 4; j++) { lg[j] = __expf(lg[j] - mx); sum += lg[j]; }
  red[tid] = sum; __syncthreads();
  for (int off = 128; off > 0; off >>= 1) {
    if (tid < off) red[tid] += red[tid + off];
    __syncthreads();
  }
  float inv = 1.0f / red[0];
#pragma unroll
  for (int j = 0; j < 4; j++)
    s16[(size_t)n * N_ + tid + 256 * j] = (_Float16)(lg[j] * inv);
}

__device__ __forceinline__ void wgen_body(const float* __restrict__ e,
                                          const _Float16* __restrict__ wpC, int COLS,
                                          _Float16* __restrict__ Wt,
                                          int xb, int yb, int tid, float (*es)[16]) {
  const int col0 = xb * 1024 + tid * 4;
  const int n0 = yb * 64;
#pragma unroll
  for (int q = 0; q < 4; q++) {
    int idx = tid + q * 256;
    es[idx >> 4][idx & 15] = e[(size_t)n0 * 16 + idx];
  }
  __syncthreads();
  float wc[4][16];
#pragma unroll
  for (int cc = 0; cc < 4; cc++) {
    f16x8 a = *(const f16x8*)&wpC[(size_t)(col0 + cc) * 16];
    f16x8 b = *(const f16x8*)&wpC[(size_t)(col0 + cc) * 16 + 8];
#pragma unroll
    for (int d = 0; d < 8; d++) { wc[cc][d] = (float)a[d]; wc[cc][8 + d] = (float)b[d]; }
  }
  for (int nn = 0; nn < 64; nn++) {
    float acc[4] = {};
#pragma unroll
    for (int d = 0; d < 16; d++) {
      float ev = es[nn][d];
#pragma unroll
      for (int cc = 0; cc < 4; cc++) acc[cc] = fmaf(ev, wc[cc][d], acc[cc]);
    }
    f16x4 pv;
#pragma unroll
    for (int cc = 0; cc < 4; cc++) pv[cc] = (_Float16)acc[cc];
    *(f16x4*)&Wt[(size_t)(n0 + nn) * COLS + col0] = pv;
  }
}

// fp16 MFMA GEMM body, 128x64 tile, BK=64, XOR-swizzled LDS.
__device__ __forceinline__ void gemm_body(
    const _Float16* __restrict__ A, const _Float16* __restrict__ Bt,
    _Float16* __restrict__ yt, _Float16* xg, int segoff, int combine,
    int bx, int by, int tid, _Float16* As, _Float16* Bs) {
  const int wave = tid >> 6, lane = tid & 63;
  const int m0 = by * 128, c0 = bx * 64;
  const int lrow = lane >> 3;
  const int lchunk = lane & 7;
  const int fm = lane & 15, fq = lane >> 4;
  f32x4 acc[2][4] = {};
  for (int ks = 0; ks < 16; ks++) {
    const int kp = ks * 64;
#pragma unroll
    for (int q = 0; q < 4; q++) {          // A: 16 groups of 8 rows
      const int seg = wave * 4 + q;
      const int row = seg * 8 + lrow;
      const int sw = lchunk ^ (row & 7);
      gl_lds16(A + (size_t)(m0 + row) * 1024 + kp + sw * 8, &As[seg * 8 * 64], lane);
    }
#pragma unroll
    for (int q = 0; q < 2; q++) {          // B: 8 groups of 8 rows
      const int seg = wave * 2 + q;
      const int row = seg * 8 + lrow;
      const int sw = lchunk ^ (row & 7);
      gl_lds16(Bt + (size_t)(c0 + row) * 1024 + kp + sw * 8, &Bs[seg * 8 * 64], lane);
    }
    __syncthreads();
#pragma unroll
    for (int kk = 0; kk < 2; kk++) {
      f16x8 af[2], bfr[4];
      const int g = kk * 4 + fq;
#pragma unroll
      for (int mt = 0; mt < 2; mt++) {
        const int row = wave * 32 + mt * 16 + fm;
        af[mt] = *(const f16x8*)&As[row * 64 + (g ^ (row & 7)) * 8];
      }
#pragma unroll
      for (int nt = 0; nt < 4; nt++) {
        const int row = nt * 16 + fm;
        bfr[nt] = *(const f16x8*)&Bs[row * 64 + (g ^ (row & 7)) * 8];
      }
#pragma unroll
      for (int mt = 0; mt < 2; mt++)
#pragma unroll
        for (int nt = 0; nt < 4; nt++)
          acc[mt][nt] = __builtin_amdgcn_mfma_f32_16x16x32_f16(af[mt], bfr[nt], acc[mt][nt], 0, 0, 0);
    }
    __syncthreads();
  }
  const int q4 = fq * 4;
#pragma unroll
  for (int nt = 0; nt < 4; nt++) {
    const int col = c0 + nt * 16 + fm;
    if (col >= BC_) continue;
    const u32 bq = div65((u32)col), cq = (u32)col - bq * 65;
#pragma unroll
    for (int mt = 0; mt < 2; mt++) {
      const int row = m0 + wave * 32 + mt * 16 + q4;
      const f32x4 v = acc[mt][nt];
      if (yt) {
        f16x4 pv;
#pragma unroll
        for (int j = 0; j < 4; j++) pv[j] = (_Float16)v[j];
        *(f16x4*)&yt[(size_t)col * 1024 + row] = pv;
      }
#pragma unroll
      for (int j = 0; j < 4; j++) {
        size_t base = ((size_t)(row + j) * 64 + bq) * KP_;
        float vv = v[j];
        if (combine) vv = 2.f * vv - (float)xg[base + cq];
        xg[base + segoff + cq] = (_Float16)vv;
      }
    }
  }
}

// ---------------------------------------------------------------------------
// Prologue 1: wprep gate [0,224), wprep upd [224,448), compute_e all t [448,496).
__global__ __launch_bounds__(256) void k_pre0(
    const float* __restrict__ gate_wp, const float* __restrict__ upd_wp,
    _Float16* __restrict__ wpCg, _Float16* __restrict__ wpCu,
    const float* __restrict__ node_emb, const float* __restrict__ time_emb,
    const float* __restrict__ g_lng, const float* __restrict__ g_lnb,
    const float* __restrict__ u_lng, const float* __restrict__ u_lnb,
    float* __restrict__ eg_all, float* __restrict__ egT_all,
    float* __restrict__ eu_all, float* __restrict__ euT_all) {
  const int bid = blockIdx.x, tid = threadIdx.x;
  if (bid < KP_)     { wprep_body(gate_wp, OG_, wpCg, bid, tid); return; }
  if (bid < 2 * KP_) { wprep_body(upd_wp,  OU_, wpCu, bid - KP_, tid); return; }
  const int idx = bid - 2 * KP_;          // 0..47
  const int t = idx >> 2;
  const int n = (idx & 3) * 256 + tid;
  float v[E_];
  float m = 0.f;
#pragma unroll
  for (int d = 0; d < E_; d++) { v[d] = node_emb[n * E_ + d] + time_emb[t * E_ + d]; m += v[d]; }
  m *= (1.0f / E_);
  float var = 0.f;
#pragma unroll
  for (int d = 0; d < E_; d++) { float x = v[d] - m; var += x * x; }
  var *= (1.0f / E_);
  float rs = rsqrtf(var + EPS_);
#pragma unroll
  for (int d = 0; d < E_; d++) {
    float nv = (v[d] - m) * rs;
    float g = nv * g_lng[d] + g_lnb[d];
    float u = nv * u_lng[d] + u_lnb[d];
    eg_all[(size_t)t * NE_ + n * E_ + d] = g;
    egT_all[(size_t)t * NE_ + d * N_ + n] = g;
    eu_all[(size_t)t * NE_ + n * E_ + d] = u;
    euT_all[(size_t)t * NE_ + d * N_ + n] = u;
  }
}

// ---------------------------------------------------------------------------
// Prologue 2: sup gate t=0 [0,1024), sup upd t=0 [1024,2048),
// build0 (gate X = [x_0 | 0], pads zeroed) [2048,3072).
__global__ __launch_bounds__(256) void k_pro(
    const float* __restrict__ egT0, const float* __restrict__ euT0,
    const float* __restrict__ src,
    _Float16* __restrict__ supG, _Float16* __restrict__ supU0,
    _Float16* __restrict__ Xt, _Float16* __restrict__ xg) {
  __shared__ float red[256];
  const int bid = blockIdx.x, tid = threadIdx.x;
  if (bid < 1024) { sup_body(egT0, supG, bid, tid, red); return; }
  if (bid < 2048) { sup_body(euT0, supU0, bid - 1024, tid, red); return; }
  const int idx = bid - 2048;
  const int b = idx & 63, m0 = (idx >> 6) * 64;
  for (int q = 0; q < 17; q++) {
    int i = tid + q * 256;
    if (i < 64 * 65) {
      int c = i >> 6, m = i & 63;
      float xv = (c == 0) ? src[((size_t)b * T_) * N_ + m0 + m] : 0.f;
      Xt[((size_t)(b * C_ + c)) * 1024 + m0 + m] = (_Float16)xv;
      u32 mm = div65((u32)i), cc = (u32)i - mm * 65;
      float xv2 = (cc == 0) ? src[((size_t)b * T_) * N_ + m0 + mm] : 0.f;
      xg[((size_t)(m0 + mm) * 64 + b) * KP_ + cc] = (_Float16)xv2;
    }
  }
#pragma unroll
  for (int q = 0; q < 8; q++) {
    int i = tid + q * 256;
    int mm = i >> 5, kk = 192 + (i & 31);
    xg[((size_t)(m0 + mm) * 64 + b) * KP_ + kk] = (_Float16)0.f;
  }
}

// ---------------------------------------------------------------------------
// Transpose xg seg0 [m][b][0..65) -> Xt [col=(b,c)][m].  Grid (b, m-tile) = 1024.
// Coalesced global reads (32B/thread) and writes (128B per col over 64 lanes);
// LDS stride 66 f16 = 33 dwords (odd) -> conflict-free column reads.
__global__ __launch_bounds__(256) void k_tr(const _Float16* __restrict__ xg,
                                            _Float16* __restrict__ Xt) {
  __shared__ _Float16 tile[64][66];
  const int b = blockIdx.x & 63, m0 = (blockIdx.x >> 6) * 64;
  const int tid = threadIdx.x;
  {
    const int m = tid >> 2, c4 = tid & 3;
    const _Float16* rp = &xg[((size_t)(m0 + m) * 64 + b) * KP_ + c4 * 16];
    f16x8 v0 = *(const f16x8*)rp;
    f16x8 v1 = *(const f16x8*)(rp + 8);
#pragma unroll
    for (int i = 0; i < 8; i++) {
      tile[m][c4 * 16 + i] = v0[i];
      tile[m][c4 * 16 + 8 + i] = v1[i];
    }
    if (c4 == 0) tile[m][64] = rp[64];
  }
  __syncthreads();
  {
    const int m = tid & 63, cg = tid >> 6;
    for (int cc = cg; cc < 65; cc += 4)
      Xt[((size_t)(b * C_ + cc)) * 1024 + m0 + m] = tile[m][cc];
  }
}

// ---------------------------------------------------------------------------
// gemm gate1 [0,528) + wgen gate [528,976)
__global__ __launch_bounds__(256) void k_g1(
    const _Float16* __restrict__ supG, const _Float16* __restrict__ Xt,
    _Float16* __restrict__ y1t, _Float16* xg,
    const float* __restrict__ eg_t, const _Float16* __restrict__ wpCg,
    _Float16* __restrict__ WtG) {
  __shared__ __align__(16) _Float16 smem[12288];
  const int bid = blockIdx.x, tid = threadIdx.x;
  if (bid < 528) {
    gemm_body(supG, Xt, y1t, xg, 65, 0, bid % 66, bid / 66, tid, smem, smem + 8192);
  } else {
    const int w = bid - 528;
    wgen_body(eg_t, wpCg, COLG_, WtG, w % 28, w / 28, tid, (float(*)[16])smem);
  }
}

// gemm gate2 (combine)
__global__ __launch_bounds__(256) void k_g2(
    const _Float16* __restrict__ supG, const _Float16* __restrict__ y1t,
    _Float16* xg) {
  __shared__ __align__(16) _Float16 smem[12288];
  gemm_body(supG, y1t, nullptr, xg, 130, 1, blockIdx.x % 66, blockIdx.x / 66,
            threadIdx.x, smem, smem + 8192);
}

// gemm upd1 [0,528) + wgen upd [528,752)
__global__ __launch_bounds__(256) void k_g3(
    const _Float16* __restrict__ supU, const _Float16* __restrict__ Xt,
    _Float16* __restrict__ y1t, _Float16* xg,
    const float* __restrict__ eu_t, const _Float16* __restrict__ wpCu,
    _Float16* __restrict__ WtU) {
  __shared__ __align__(16) _Float16 smem[12288];
  const int bid = blockIdx.x, tid = threadIdx.x;
  if (bid < 528) {
    gemm_body(supU, Xt, y1t, xg, 65, 0, bid % 66, bid / 66, tid, smem, smem + 8192);
  } else {
    const int w = bid - 528;
    wgen_body(eu_t, wpCu, COLU_, WtU, w % 14, w / 14, tid, (float(*)[16])smem);
  }
}

// gemm upd2 [0,528) + sup(t+1) gate [528,1552) + sup(t+1) upd [1552,2576)
__global__ __launch_bounds__(256) void k_g4(
    const _Float16* __restrict__ supU, const _Float16* __restrict__ y1t,
    _Float16* xg,
    const float* __restrict__ egT_nx, const float* __restrict__ euT_nx,
    _Float16* __restrict__ supG, _Float16* __restrict__ supU_nx, int dosup) {
  __shared__ __align__(16) _Float16 smem[12288];
  const int bid = blockIdx.x, tid = threadIdx.x;
  if (bid < 528) {
    gemm_body(supU, y1t, nullptr, xg, 130, 1, bid % 66, bid / 66, tid, smem, smem + 8192);
  } else if (dosup) {
    if (bid < 1552) sup_body(egT_nx, supG, bid - 528, tid, (float*)smem);
    else            sup_body(euT_nx, supU_nx, bid - 1552, tid, (float*)smem);
  }
}

// ---------------------------------------------------------------------------
// Fused gate contract: MFMA zr -> z,r in LDS; coalesced epilogue writes
// r16 (16B vectors) and u = z*h into xg seg0 (row-major).  No Xt scatter.
__global__ __launch_bounds__(256) void k_cg(
    const float* __restrict__ eg, const _Float16* XG,
    const _Float16* __restrict__ Wt, const float* __restrict__ bp,
    const float* __restrict__ h, const float* __restrict__ src, int t,
    _Float16* __restrict__ r16, _Float16* xgo) {
  const int n = blockIdx.x;
  const int tid = threadIdx.x;
  const int wave = tid >> 6, lane = tid & 63;
  const int fm = lane & 15, fq = lane >> 4;
  const int wm = wave >> 1, wn = wave & 1;
  __shared__ float es[16];
  __shared__ float bias_s[128];
  __shared__ float zs[64][68];
  __shared__ float rs[64][68];
  if (tid < 16) es[tid] = eg[n * 16 + tid];
  __syncthreads();
  if (tid < 128) {
    float bv = 0.f;
#pragma unroll
    for (int d = 0; d < 16; d++) bv = fmaf(es[d], bp[d * OG_ + tid], bv);
    bias_s[tid] = bv;
  }
  const _Float16* Ab = XG + (size_t)n * 64 * KP_;
  const _Float16* Bb = Wt + (size_t)n * OG_ * KP_;
  f16x8 af[2][2], bf[2][4];
#pragma unroll
  for (int mt = 0; mt < 2; mt++)
    af[0][mt] = *(const f16x8*)&Ab[(wm * 32 + mt * 16 + fm) * KP_ + fq * 8];
#pragma unroll
  for (int nt = 0; nt < 4; nt++)
    bf[0][nt] = *(const f16x8*)&Bb[(wn * 64 + nt * 16 + fm) * KP_ + fq * 8];
  f32x4 acc[2][4] = {};
#pragma unroll
  for (int kk = 0; kk < 7; kk++) {
    const int cur = kk & 1;
    if (kk < 6) {
      const int ko = (kk + 1) * 32 + fq * 8;
#pragma unroll
      for (int mt = 0; mt < 2; mt++)
        af[cur ^ 1][mt] = *(const f16x8*)&Ab[(wm * 32 + mt * 16 + fm) * KP_ + ko];
#pragma unroll
      for (int nt = 0; nt < 4; nt++)
        bf[cur ^ 1][nt] = *(const f16x8*)&Bb[(wn * 64 + nt * 16 + fm) * KP_ + ko];
    }
#pragma unroll
    for (int mt = 0; mt < 2; mt++)
#pragma unroll
      for (int nt = 0; nt < 4; nt++)
        acc[mt][nt] = __builtin_amdgcn_mfma_f32_16x16x32_f16(af[cur][mt], bf[cur][nt], acc[mt][nt], 0, 0, 0);
  }
  __syncthreads();
#pragma unroll
  for (int nt = 0; nt < 4; nt++) {
    const int o = wn * 64 + nt * 16 + fm;
    const float bias = bias_s[o];
#pragma unroll
    for (int mt = 0; mt < 2; mt++) {
      const f32x4 v = acc[mt][nt];
#pragma unroll
      for (int j = 0; j < 4; j++) {
        const int b = wm * 32 + mt * 16 + fq * 4 + j;
        float s = 1.0f / (1.0f + __expf(-(v[j] + bias)));
        if (wn == 0) zs[b][o] = s;
        else         rs[b][o - H_] = s;
      }
    }
  }
  __syncthreads();
  {
    const int b = tid >> 2, q = tid & 3;
    const float* hp = &h[((size_t)b * N_ + n) * H_ + q * 16];
    _Float16* xp = &xgo[((size_t)n * 64 + b) * KP_ + 1 + q * 16];
    _Float16* rp = &r16[((size_t)b * N_ + n) * H_ + q * 16];
    f16x8 r0, r1;
#pragma unroll
    for (int i = 0; i < 8; i++) {
      r0[i] = (_Float16)rs[b][q * 16 + i];
      r1[i] = (_Float16)rs[b][q * 16 + 8 + i];
    }
    *(f16x8*)rp = r0;
    *(f16x8*)(rp + 8) = r1;
#pragma unroll
    for (int i4 = 0; i4 < 4; i4++) {
      const float4 hv = *(const float4*)(hp + i4 * 4);
      const int ob = q * 16 + i4 * 4;
      xp[i4 * 4 + 0] = (_Float16)(zs[b][ob + 0] * hv.x);
      xp[i4 * 4 + 1] = (_Float16)(zs[b][ob + 1] * hv.y);
      xp[i4 * 4 + 2] = (_Float16)(zs[b][ob + 2] * hv.z);
      xp[i4 * 4 + 3] = (_Float16)(zs[b][ob + 3] * hv.w);
    }
    if (tid < 64) {
      float sv = src[((size_t)tid * T_ + t) * N_ + n];
      xgo[((size_t)n * 64 + tid) * KP_] = (_Float16)sv;
    }
  }
}

// ---------------------------------------------------------------------------
// Fused upd contract: MFMA hc; h_new = r*h + (1-r)*hc via LDS; writes h
// (coalesced) and (t<11) next gate inputs into xg seg0 (row-major, no scatter).
__global__ __launch_bounds__(256) void k_cu(
    const float* __restrict__ eu, const _Float16* XG,
    const _Float16* __restrict__ Wt, const float* __restrict__ bp,
    const _Float16* __restrict__ r16, const float* __restrict__ src,
    int t, int donext,
    float* __restrict__ h, _Float16* xgo) {
  const int n = blockIdx.x;
  const int tid = threadIdx.x;
  const int wave = tid >> 6, lane = tid & 63;
  const int fm = lane & 15, fq = lane >> 4;
  __shared__ float es[16];
  __shared__ float bias_s[64];
  __shared__ float hs[64][68];
  __shared__ float rs[64][68];
  if (tid < 16) es[tid] = eu[n * 16 + tid];
  __syncthreads();
  if (tid < 64) {
    float bv = 0.f;
#pragma unroll
    for (int d = 0; d < 16; d++) bv = fmaf(es[d], bp[d * OU_ + tid], bv);
    bias_s[tid] = bv;
  }
  {
    const int b = tid >> 2, q = tid & 3;
    const float* hp = &h[((size_t)b * N_ + n) * H_ + q * 16];
    const _Float16* rp = &r16[((size_t)b * N_ + n) * H_ + q * 16];
#pragma unroll
    for (int i4 = 0; i4 < 4; i4++) {
      const float4 hv = *(const float4*)(hp + i4 * 4);
      const int ob = q * 16 + i4 * 4;
      hs[b][ob + 0] = hv.x; hs[b][ob + 1] = hv.y;
      hs[b][ob + 2] = hv.z; hs[b][ob + 3] = hv.w;
    }
    f16x8 r0 = *(const f16x8*)rp;
    f16x8 r1 = *(const f16x8*)(rp + 8);
#pragma unroll
    for (int i = 0; i < 8; i++) {
      rs[b][q * 16 + i] = (float)r0[i];
      rs[b][q * 16 + 8 + i] = (float)r1[i];
    }
  }
  __syncthreads();
  const _Float16* Ab = XG + (size_t)n * 64 * KP_;
  const _Float16* Bb = Wt + (size_t)n * OU_ * KP_;
  f16x8 af[2], bf[2][4];
  af[0] = *(const f16x8*)&Ab[(wave * 16 + fm) * KP_ + fq * 8];
#pragma unroll
  for (int nt = 0; nt < 4; nt++)
    bf[0][nt] = *(const f16x8*)&Bb[(nt * 16 + fm) * KP_ + fq * 8];
  f32x4 acc[4] = {};
#pragma unroll
  for (int kk = 0; kk < 7; kk++) {
    const int cur = kk & 1;
    if (kk < 6) {
      const int ko = (kk + 1) * 32 + fq * 8;
      af[cur ^ 1] = *(const f16x8*)&Ab[(wave * 16 + fm) * KP_ + ko];
#pragma unroll
      for (int nt = 0; nt < 4; nt++)
        bf[cur ^ 1][nt] = *(const f16x8*)&Bb[(nt * 16 + fm) * KP_ + ko];
    }
#pragma unroll
    for (int nt = 0; nt < 4; nt++)
      acc[nt] = __builtin_amdgcn_mfma_f32_16x16x32_f16(af[cur], bf[cur][nt], acc[nt], 0, 0, 0);
  }
#pragma unroll
  for (int nt = 0; nt < 4; nt++) {
    const int o = nt * 16 + fm;
    const float bias = bias_s[o];
    const f32x4 v = acc[nt];
#pragma unroll
    for (int j = 0; j < 4; j++) {
      const int b = wave * 16 + fq * 4 + j;
      float hc = tanhf(v[j] + bias);
      float rv = rs[b][o];
      hs[b][o] = rv * hs[b][o] + (1.0f - rv) * hc;
    }
  }
  __syncthreads();
  {
    const int b = tid >> 2, q = tid & 3;
    float* hp = &h[((size_t)b * N_ + n) * H_ + q * 16];
#pragma unroll
    for (int i4 = 0; i4 < 4; i4++) {
      const int ob = q * 16 + i4 * 4;
      float4 hv = make_float4(hs[b][ob], hs[b][ob + 1], hs[b][ob + 2], hs[b][ob + 3]);
      *(float4*)(hp + i4 * 4) = hv;
    }
    if (donext) {
      _Float16* xp = &xgo[((size_t)n * 64 + b) * KP_ + 1 + q * 16];
#pragma unroll
      for (int i = 0; i < 16; i++)
        xp[i] = (_Float16)hs[b][q * 16 + i];
      if (tid < 64) {
        float sv = src[((size_t)tid * T_ + (t + 1)) * N_ + n];
        xgo[((size_t)n * 64 + tid) * KP_] = (_Float16)sv;
      }
    }
  }
}

// ---------------------------------------------------------------------------
// LN(h) + conv, one thread per (b,n).
__global__ __launch_bounds__(256) void k_final(const float* __restrict__ h,
                                               const float* __restrict__ out_lng,
                                               const float* __restrict__ out_lnb,
                                               const float* __restrict__ conv_w,
                                               const float* __restrict__ conv_b,
                                               float* __restrict__ out) {
  const int b = blockIdx.x >> 2;
  const int n = (blockIdx.x & 3) * 256 + threadIdx.x;
  __shared__ float cw[12][64];
  __shared__ float cb[12];
  __shared__ float lgs[64], lbs[64];
  for (int idx = threadIdx.x; idx < 12 * 64; idx += 256) cw[idx >> 6][idx & 63] = conv_w[idx];
  if (threadIdx.x < 12) cb[threadIdx.x] = conv_b[threadIdx.x];
  if (threadIdx.x < 64) { lgs[threadIdx.x] = out_lng[threadIdx.x]; lbs[threadIdx.x] = out_lnb[threadIdx.x]; }
  __syncthreads();
  const float* hp = &h[((size_t)b * N_ + n) * H_];
  float4 hv[16];
  float mean = 0.f;
#pragma unroll
  for (int i = 0; i < 16; i++) {
    hv[i] = *(const float4*)&hp[i * 4];
    mean += hv[i].x + hv[i].y + hv[i].z + hv[i].w;
  }
  mean *= (1.0f / H_);
  float var = 0.f;
#pragma unroll
  for (int i = 0; i < 16; i++) {
    float dx = hv[i].x - mean, dy = hv[i].y - mean, dz = hv[i].z - mean, dw = hv[i].w - mean;
    var += dx * dx + dy * dy + dz * dz + dw * dw;
  }
  var *= (1.0f / H_);
  const float rs = rsqrtf(var + EPS_);
  float y[64];
#pragma unroll
  for (int i = 0; i < 16; i++) {
    y[4 * i + 0] = (hv[i].x - mean) * rs * lgs[4 * i + 0] + lbs[4 * i + 0];
    y[4 * i + 1] = (hv[i].y - mean) * rs * lgs[4 * i + 1] + lbs[4 * i + 1];
    y[4 * i + 2] = (hv[i].z - mean) * rs * lgs[4 * i + 2] + lbs[4 * i + 2];
    y[4 * i + 3] = (hv[i].w - mean) * rs * lgs[4 * i + 3] + lbs[4 * i + 3];
  }
#pragma unroll
  for (int o = 0; o < 12; o++) {
    float acc = cb[o];
#pragma unroll
    for (int i = 0; i < 64; i++) acc = fmaf(y[i], cw[o][i], acc);
    out[((size_t)b * 12 + o) * N_ + n] = acc;
  }
}

// ---------------------------------------------------------------------------
extern "C" void kernel_launch(void* const* d_in, const int* in_sizes, int n_in,
                              void* d_out, int out_size, void* d_ws, size_t ws_size,
                              hipStream_t stream) {
  const float* src      = (const float*)d_in[0];
  const float* node_emb = (const float*)d_in[1];
  const float* time_emb = (const float*)d_in[2];
  const float* gate_wp  = (const float*)d_in[3];
  const float* gate_bp  = (const float*)d_in[4];
  const float* gate_lng = (const float*)d_in[5];
  const float* gate_lnb = (const float*)d_in[6];
  const float* upd_wp   = (const float*)d_in[7];
  const float* upd_bp   = (const float*)d_in[8];
  const float* upd_lng  = (const float*)d_in[9];
  const float* upd_lnb  = (const float*)d_in[10];
  const float* out_lng  = (const float*)d_in[11];
  const float* out_lnb  = (const float*)d_in[12];
  const float* conv_w   = (const float*)d_in[13];
  const float* conv_b   = (const float*)d_in[14];
  float* out = (float*)d_out;

  constexpr size_t SZ_H   = (size_t)B_ * N_ * H_;        // 4,194,304
  constexpr size_t SZ_R   = SZ_H / 2;                    // r fp16
  constexpr size_t SZ_T   = (size_t)NP_ * 1024 / 2;      // 2,162,688
  constexpr size_t SZ_XG  = (size_t)N_ * 64 * KP_ / 2;   // 7,340,032
  constexpr size_t SZ_WT  = (size_t)N_ * OG_ * KP_ / 2;  // 14,680,064 (WtU aliases 1st half)
  constexpr size_t SZ_WCG = (size_t)COLG_ * 16 / 2;      // 229,376
  constexpr size_t SZ_WCU = (size_t)COLU_ * 16 / 2;      // 114,688
  constexpr size_t SZ_S   = (size_t)N_ * N_ / 2;         // 524,288

  float* ws = (float*)d_ws;
  size_t off = 0;
  float* h      = ws + off; off += SZ_H;
  float* r16F   = ws + off; off += SZ_R;
  float* XtF    = ws + off; off += SZ_T;
  float* y1tF   = ws + off; off += SZ_T;
  float* xgF    = ws + off; off += SZ_XG;
  float* WtF    = ws + off; off += SZ_WT;
  float* wcgF   = ws + off; off += SZ_WCG;
  float* wcuF   = ws + off; off += SZ_WCU;
  float* supGF  = ws + off; off += SZ_S;
  float* supUF  = ws + off; off += 2 * SZ_S;     // double-buffered
  float* eg_all  = ws + off; off += (size_t)T_ * NE_;
  float* egT_all = ws + off; off += (size_t)T_ * NE_;
  float* eu_all  = ws + off; off += (size_t)T_ * NE_;
  float* euT_all = ws + off; off += (size_t)T_ * NE_;
  if (ws_size < off * sizeof(float)) return;     // ~141.4 MB

  _Float16* r16  = (_Float16*)r16F;
  _Float16* Xt   = (_Float16*)XtF;
  _Float16* y1t  = (_Float16*)y1tF;
  _Float16* xg   = (_Float16*)xgF;
  _Float16* WtG  = (_Float16*)WtF;
  _Float16* WtU  = (_Float16*)WtF;
  _Float16* wpCg = (_Float16*)wcgF;
  _Float16* wpCu = (_Float16*)wcuF;
  _Float16* supG = (_Float16*)supGF;
  _Float16* supU = (_Float16*)supUF;

  hipMemsetAsync(h, 0, SZ_H * sizeof(float), stream);
  k_pre0<<<2 * KP_ + 48, 256, 0, stream>>>(gate_wp, upd_wp, wpCg, wpCu,
                                           node_emb, time_emb,
                                           gate_lng, gate_lnb, upd_lng, upd_lnb,
                                           eg_all, egT_all, eu_all, euT_all);
  k_pro<<<3072, 256, 0, stream>>>(egT_all, euT_all, src, supG, supU, Xt, xg);

  for (int t = 0; t < T_; t++) {
    _Float16* sU  = supU + (size_t)(t & 1) * N_ * N_;
    _Float16* sUn = supU + (size_t)((t + 1) & 1) * N_ * N_;
    const float* eg_t = eg_all + (size_t)t * NE_;
    const float* eu_t = eu_all + (size_t)t * NE_;
    const int tn = (t < T_ - 1) ? t + 1 : t;
    const int more = (t < T_ - 1) ? 1 : 0;
    k_g1<<<976, 256, 0, stream>>>(supG, Xt, y1t, xg, eg_t, wpCg, WtG);
    k_g2<<<528, 256, 0, stream>>>(supG, y1t, xg);
    k_cg<<<N_, 256, 0, stream>>>(eg_t, xg, WtG, gate_bp, h, src, t, r16, xg);
    k_tr<<<1024, 256, 0, stream>>>(xg, Xt);        // upd X -> Xt
    k_g3<<<752, 256, 0, stream>>>(sU, Xt, y1t, xg, eu_t, wpCu, WtU);
    k_g4<<<2576, 256, 0, stream>>>(sU, y1t, xg,
                                   egT_all + (size_t)tn * NE_,
                                   euT_all + (size_t)tn * NE_,
                                   supG, sUn, more);
    k_cu<<<N_, 256, 0, stream>>>(eu_t, xg, WtU, upd_bp, r16, src, t, more, h, xg);
    if (more) k_tr<<<1024, 256, 0, stream>>>(xg, Xt);   // next gate X -> Xt
  }
  k_final<<<B_ * N_ / 256, 256, 0, stream>>>(h, out_lng, out_lnb, conv_w, conv_b, out);
}

// Round 9
// 2030.314 us; speedup vs baseline: 5.8072x; 1.0445x over previous
//
#include <hip/hip_runtime.h>
#include <math.h>

namespace {
constexpr int B_ = 64, T_ = 12, N_ = 1024, H_ = 64, E_ = 16;
constexpr int C_  = 65;          // DIN + H
constexpr int BC_ = B_ * C_;     // 4160
constexpr int OG_ = 128;         // gate output = 2H
constexpr int OU_ = 64;          // update output = H
constexpr float EPS_ = 1e-12f;
constexpr int NP_ = 4224;        // BC_ padded for GEMM N-tiling
constexpr int KP_ = 224;         // packed contract K: 3*65=195 + pad to 7*32
constexpr int COLG_ = OG_ * KP_; // 28672
constexpr int COLU_ = OU_ * KP_; // 14336
constexpr int NE_ = N_ * E_;     // 16384
}

typedef unsigned short u16;
typedef unsigned int u32;
using f16x8 = __attribute__((ext_vector_type(8))) _Float16;
using f16x4 = __attribute__((ext_vector_type(4))) _Float16;
using f32x4 = __attribute__((ext_vector_type(4))) float;
using f32x16 = __attribute__((ext_vector_type(16))) float;

__device__ __forceinline__ u32 div65(u32 x) { return (x * 16135u) >> 20; }  // exact for x<5196

// async global->LDS 16B/lane; LDS dest is wave-uniform base + lane*16.
__device__ __forceinline__ void gl_lds16(const void* g, void* l, int lane) {
#if __has_builtin(__builtin_amdgcn_global_load_lds)
  __builtin_amdgcn_global_load_lds((const __attribute__((address_space(1))) u32*)g,
                                   (__attribute__((address_space(3))) u32*)l, 16, 0, 0);
#else
  *(uint4*)((char*)l + lane * 16) = *(const uint4*)g;
#endif
}

// ---------------------------------------------------------------------------
// device bodies shared by fused kernels
// ---------------------------------------------------------------------------
__device__ __forceinline__ void wprep_body(const float* __restrict__ wp, int NO,
                                           _Float16* __restrict__ wpC, int k, int tid) {
  if (tid >= NO) return;
  f16x8 lo = {}, hi = {};
  if (k < 195) {
    const u32 seg = div65((u32)k);
    const u32 ii = k - seg * 65;
#pragma unroll
    for (int d = 0; d < 8; d++)
      lo[d] = (_Float16)wp[(((size_t)d * 3 + seg) * 65 + ii) * NO + tid];
#pragma unroll
    for (int d = 0; d < 8; d++)
      hi[d] = (_Float16)wp[(((size_t)(d + 8) * 3 + seg) * 65 + ii) * NO + tid];
  }
  _Float16* dst = &wpC[((size_t)tid * KP_ + k) * 16];
  *(f16x8*)dst = lo;
  *(f16x8*)(dst + 8) = hi;
}

__device__ __forceinline__ void sup_body(const float* __restrict__ eT,
                                         _Float16* __restrict__ s16,
                                         int n, int tid, float* red) {
  float en[E_];
#pragma unroll
  for (int d = 0; d < E_; d++) en[d] = eT[d * N_ + n];
  float lg[4];
  float mx = -3.4e38f;
#pragma unroll
  for (int j = 0; j < 4; j++) {
    int m = tid + 256 * j;
    float s = 0.f;
#pragma unroll
    for (int d = 0; d < E_; d++) s = fmaf(en[d], eT[d * N_ + m], s);
    lg[j] = s;
    mx = fmaxf(mx, s);
  }
  red[tid] = mx; __syncthreads();
  for (int off = 128; off > 0; off >>= 1) {
    if (tid < off) red[tid] = fmaxf(red[tid], red[tid + off]);
    __syncthreads();
  }
  mx = red[0]; __syncthreads();
  float sum = 0.f;
#pragma unroll
  for (int j = 0; j < 4; j++) { lg[j] = __expf(lg[j] - mx); sum += lg[j]; }
  red[tid] = sum; __syncthreads();
  for (int off = 128; off > 0; off >>= 1) {
    if (tid < off) red[tid] += red[tid + off];
    __syncthreads();
  }
  float inv = 1.0f / red[0];
#pragma unroll
  for (int j = 0; j < 4; j++)
    s16[(size_t)n * N_ + tid + 256 * j] = (_Float16)(lg[j] * inv);
}

__device__ __forceinline__ void wgen_body(const float* __restrict__ e,
                                          const _Float16* __restrict__ wpC, int COLS,
                                          _Float16* __restrict__ Wt,
                                          int xb, int yb, int tid, float (*es)[16]) {
  const int col0 = xb * 1024 + tid * 4;
  const int n0 = yb * 64;
#pragma unroll
  for (int q = 0; q < 4; q++) {
    int idx = tid + q * 256;
    es[idx >> 4][idx & 15] = e[(size_t)n0 * 16 + idx];
  }
  __syncthreads();
  float wc[4][16];
#pragma unroll
  for (int cc = 0; cc < 4; cc++) {
    f16x8 a = *(const f16x8*)&wpC[(size_t)(col0 + cc) * 16];
    f16x8 b = *(const f16x8*)&wpC[(size_t)(col0 + cc) * 16 + 8];
#pragma unroll
    for (int d = 0; d < 8; d++) { wc[cc][d] = (float)a[d]; wc[cc][8 + d] = (float)b[d]; }
  }
  for (int nn = 0; nn < 64; nn++) {
    float acc[4] = {};
#pragma unroll
    for (int d = 0; d < 16; d++) {
      float ev = es[nn][d];
#pragma unroll
      for (int cc = 0; cc < 4; cc++) acc[cc] = fmaf(ev, wc[cc][d], acc[cc]);
    }
    f16x4 pv;
#pragma unroll
    for (int cc = 0; cc < 4; cc++) pv[cc] = (_Float16)acc[cc];
    *(f16x4*)&Wt[(size_t)(n0 + nn) * COLS + col0] = pv;
  }
}

// fp16 MFMA GEMM body, 128x64 tile, BK=64, XOR-swizzled LDS, 32x32x16 MFMA.
// Per wave: 32 rows x 64 cols, 8 MFMA per BK-iter (vs 16 with 16x16x32).
// C/D layout (verified m74/m101): col=lane&31, row=(reg&3)+8*(reg>>2)+4*(lane>>5).
__device__ __forceinline__ void gemm_body(
    const _Float16* __restrict__ A, const _Float16* __restrict__ Bt,
    _Float16* __restrict__ yt, _Float16* xg, int segoff, int combine,
    int bx, int by, int tid, _Float16* As, _Float16* Bs) {
  const int wave = tid >> 6, lane = tid & 63;
  const int m0 = by * 128, c0 = bx * 64;
  const int lrow = lane >> 3;
  const int lchunk = lane & 7;
  const int fm32 = lane & 31, fh = lane >> 5;
  f32x16 acc[2] = {};
  for (int ks = 0; ks < 16; ks++) {
    const int kp = ks * 64;
#pragma unroll
    for (int q = 0; q < 4; q++) {          // A: 16 groups of 8 rows
      const int seg = wave * 4 + q;
      const int row = seg * 8 + lrow;
      const int sw = lchunk ^ (row & 7);
      gl_lds16(A + (size_t)(m0 + row) * 1024 + kp + sw * 8, &As[seg * 8 * 64], lane);
    }
#pragma unroll
    for (int q = 0; q < 2; q++) {          // B: 8 groups of 8 rows
      const int seg = wave * 2 + q;
      const int row = seg * 8 + lrow;
      const int sw = lchunk ^ (row & 7);
      gl_lds16(Bt + (size_t)(c0 + row) * 1024 + kp + sw * 8, &Bs[seg * 8 * 64], lane);
    }
    __syncthreads();
#pragma unroll
    for (int ch = 0; ch < 4; ch++) {       // 4 k-chunks of 16
      const int g = ch * 2 + fh;           // 16B chunk index holding this lane's k
      const int arow = wave * 32 + fm32;
      f16x8 af = *(const f16x8*)&As[arow * 64 + (g ^ (arow & 7)) * 8];
#pragma unroll
      for (int nt = 0; nt < 2; nt++) {
        const int brow = nt * 32 + fm32;
        f16x8 bf = *(const f16x8*)&Bs[brow * 64 + (g ^ (brow & 7)) * 8];
        acc[nt] = __builtin_amdgcn_mfma_f32_32x32x16_f16(af, bf, acc[nt], 0, 0, 0);
      }
    }
    __syncthreads();
  }
#pragma unroll
  for (int nt = 0; nt < 2; nt++) {
    const int col = c0 + nt * 32 + fm32;
    if (col >= BC_) continue;
    const u32 bq = div65((u32)col), cq = (u32)col - bq * 65;
#pragma unroll
    for (int g = 0; g < 4; g++) {
      const int row0 = m0 + wave * 32 + 8 * g + 4 * fh;
      if (yt) {
        f16x4 pv;
#pragma unroll
        for (int rr = 0; rr < 4; rr++) pv[rr] = (_Float16)acc[nt][4 * g + rr];
        *(f16x4*)&yt[(size_t)col * 1024 + row0] = pv;
      }
#pragma unroll
      for (int rr = 0; rr < 4; rr++) {
        size_t base = ((size_t)(row0 + rr) * 64 + bq) * KP_;
        float vv = acc[nt][4 * g + rr];
        if (combine) vv = 2.f * vv - (float)xg[base + cq];
        xg[base + segoff + cq] = (_Float16)vv;
      }
    }
  }
}

// ---------------------------------------------------------------------------
// Prologue 1: wprep gate [0,224), wprep upd [224,448), compute_e all t [448,496).
__global__ __launch_bounds__(256) void k_pre0(
    const float* __restrict__ gate_wp, const float* __restrict__ upd_wp,
    _Float16* __restrict__ wpCg, _Float16* __restrict__ wpCu,
    const float* __restrict__ node_emb, const float* __restrict__ time_emb,
    const float* __restrict__ g_lng, const float* __restrict__ g_lnb,
    const float* __restrict__ u_lng, const float* __restrict__ u_lnb,
    float* __restrict__ eg_all, float* __restrict__ egT_all,
    float* __restrict__ eu_all, float* __restrict__ euT_all) {
  const int bid = blockIdx.x, tid = threadIdx.x;
  if (bid < KP_)     { wprep_body(gate_wp, OG_, wpCg, bid, tid); return; }
  if (bid < 2 * KP_) { wprep_body(upd_wp,  OU_, wpCu, bid - KP_, tid); return; }
  const int idx = bid - 2 * KP_;          // 0..47
  const int t = idx >> 2;
  const int n = (idx & 3) * 256 + tid;
  float v[E_];
  float m = 0.f;
#pragma unroll
  for (int d = 0; d < E_; d++) { v[d] = node_emb[n * E_ + d] + time_emb[t * E_ + d]; m += v[d]; }
  m *= (1.0f / E_);
  float var = 0.f;
#pragma unroll
  for (int d = 0; d < E_; d++) { float x = v[d] - m; var += x * x; }
  var *= (1.0f / E_);
  float rs = rsqrtf(var + EPS_);
#pragma unroll
  for (int d = 0; d < E_; d++) {
    float nv = (v[d] - m) * rs;
    float g = nv * g_lng[d] + g_lnb[d];
    float u = nv * u_lng[d] + u_lnb[d];
    eg_all[(size_t)t * NE_ + n * E_ + d] = g;
    egT_all[(size_t)t * NE_ + d * N_ + n] = g;
    eu_all[(size_t)t * NE_ + n * E_ + d] = u;
    euT_all[(size_t)t * NE_ + d * N_ + n] = u;
  }
}

// ---------------------------------------------------------------------------
// Prologue 2: sup gate t=0 [0,1024), sup upd t=0 [1024,2048),
// build0 (gate X = [x_0 | 0], pads zeroed) [2048,3072).
__global__ __launch_bounds__(256) void k_pro(
    const float* __restrict__ egT0, const float* __restrict__ euT0,
    const float* __restrict__ src,
    _Float16* __restrict__ supG, _Float16* __restrict__ supU0,
    _Float16* __restrict__ Xt, _Float16* __restrict__ xg) {
  __shared__ float red[256];
  const int bid = blockIdx.x, tid = threadIdx.x;
  if (bid < 1024) { sup_body(egT0, supG, bid, tid, red); return; }
  if (bid < 2048) { sup_body(euT0, supU0, bid - 1024, tid, red); return; }
  const int idx = bid - 2048;
  const int b = idx & 63, m0 = (idx >> 6) * 64;
  for (int q = 0; q < 17; q++) {
    int i = tid + q * 256;
    if (i < 64 * 65) {
      int c = i >> 6, m = i & 63;
      float xv = (c == 0) ? src[((size_t)b * T_) * N_ + m0 + m] : 0.f;
      Xt[((size_t)(b * C_ + c)) * 1024 + m0 + m] = (_Float16)xv;
      u32 mm = div65((u32)i), cc = (u32)i - mm * 65;
      float xv2 = (cc == 0) ? src[((size_t)b * T_) * N_ + m0 + mm] : 0.f;
      xg[((size_t)(m0 + mm) * 64 + b) * KP_ + cc] = (_Float16)xv2;
    }
  }
#pragma unroll
  for (int q = 0; q < 8; q++) {
    int i = tid + q * 256;
    int mm = i >> 5, kk = 192 + (i & 31);
    xg[((size_t)(m0 + mm) * 64 + b) * KP_ + kk] = (_Float16)0.f;
  }
}

// ---------------------------------------------------------------------------
// Transpose xg seg0 [m][b][0..65) -> Xt [col=(b,c)][m].  Grid (b, m-tile) = 1024.
__global__ __launch_bounds__(256) void k_tr(const _Float16* __restrict__ xg,
                                            _Float16* __restrict__ Xt) {
  __shared__ _Float16 tile[64][66];
  const int b = blockIdx.x & 63, m0 = (blockIdx.x >> 6) * 64;
  const int tid = threadIdx.x;
  {
    const int m = tid >> 2, c4 = tid & 3;
    const _Float16* rp = &xg[((size_t)(m0 + m) * 64 + b) * KP_ + c4 * 16];
    f16x8 v0 = *(const f16x8*)rp;
    f16x8 v1 = *(const f16x8*)(rp + 8);
#pragma unroll
    for (int i = 0; i < 8; i++) {
      tile[m][c4 * 16 + i] = v0[i];
      tile[m][c4 * 16 + 8 + i] = v1[i];
    }
    if (c4 == 0) tile[m][64] = rp[64];
  }
  __syncthreads();
  {
    const int m = tid & 63, cg = tid >> 6;
    for (int cc = cg; cc < 65; cc += 4)
      Xt[((size_t)(b * C_ + cc)) * 1024 + m0 + m] = tile[m][cc];
  }
}

// ---------------------------------------------------------------------------
// gemm gate1 [0,528) + wgen gate [528,976)
__global__ __launch_bounds__(256) void k_g1(
    const _Float16* __restrict__ supG, const _Float16* __restrict__ Xt,
    _Float16* __restrict__ y1t, _Float16* xg,
    const float* __restrict__ eg_t, const _Float16* __restrict__ wpCg,
    _Float16* __restrict__ WtG) {
  __shared__ __align__(16) _Float16 smem[12288];
  const int bid = blockIdx.x, tid = threadIdx.x;
  if (bid < 528) {
    gemm_body(supG, Xt, y1t, xg, 65, 0, bid % 66, bid / 66, tid, smem, smem + 8192);
  } else {
    const int w = bid - 528;
    wgen_body(eg_t, wpCg, COLG_, WtG, w % 28, w / 28, tid, (float(*)[16])smem);
  }
}

// gemm gate2 (combine)
__global__ __launch_bounds__(256) void k_g2(
    const _Float16* __restrict__ supG, const _Float16* __restrict__ y1t,
    _Float16* xg) {
  __shared__ __align__(16) _Float16 smem[12288];
  gemm_body(supG, y1t, nullptr, xg, 130, 1, blockIdx.x % 66, blockIdx.x / 66,
            threadIdx.x, smem, smem + 8192);
}

// gemm upd1 [0,528) + wgen upd [528,752)
__global__ __launch_bounds__(256) void k_g3(
    const _Float16* __restrict__ supU, const _Float16* __restrict__ Xt,
    _Float16* __restrict__ y1t, _Float16* xg,
    const float* __restrict__ eu_t, const _Float16* __restrict__ wpCu,
    _Float16* __restrict__ WtU) {
  __shared__ __align__(16) _Float16 smem[12288];
  const int bid = blockIdx.x, tid = threadIdx.x;
  if (bid < 528) {
    gemm_body(supU, Xt, y1t, xg, 65, 0, bid % 66, bid / 66, tid, smem, smem + 8192);
  } else {
    const int w = bid - 528;
    wgen_body(eu_t, wpCu, COLU_, WtU, w % 14, w / 14, tid, (float(*)[16])smem);
  }
}

// gemm upd2 [0,528) + sup(t+1) gate [528,1552) + sup(t+1) upd [1552,2576)
__global__ __launch_bounds__(256) void k_g4(
    const _Float16* __restrict__ supU, const _Float16* __restrict__ y1t,
    _Float16* xg,
    const float* __restrict__ egT_nx, const float* __restrict__ euT_nx,
    _Float16* __restrict__ supG, _Float16* __restrict__ supU_nx, int dosup) {
  __shared__ __align__(16) _Float16 smem[12288];
  const int bid = blockIdx.x, tid = threadIdx.x;
  if (bid < 528) {
    gemm_body(supU, y1t, nullptr, xg, 130, 1, bid % 66, bid / 66, tid, smem, smem + 8192);
  } else if (dosup) {
    if (bid < 1552) sup_body(egT_nx, supG, bid - 528, tid, (float*)smem);
    else            sup_body(euT_nx, supU_nx, bid - 1552, tid, (float*)smem);
  }
}

// ---------------------------------------------------------------------------
// Fused gate contract: MFMA zr -> z,r in LDS; coalesced epilogue writes
// r16 (16B vectors) and u = z*h into xg seg0 (row-major).  h is fp16.
__global__ __launch_bounds__(256) void k_cg(
    const float* __restrict__ eg, const _Float16* XG,
    const _Float16* __restrict__ Wt, const float* __restrict__ bp,
    const _Float16* __restrict__ h16, const float* __restrict__ src, int t,
    _Float16* __restrict__ r16, _Float16* xgo) {
  const int n = blockIdx.x;
  const int tid = threadIdx.x;
  const int wave = tid >> 6, lane = tid & 63;
  const int fm = lane & 15, fq = lane >> 4;
  const int wm = wave >> 1, wn = wave & 1;
  __shared__ float es[16];
  __shared__ float bias_s[128];
  __shared__ float zs[64][68];
  __shared__ float rs[64][68];
  if (tid < 16) es[tid] = eg[n * 16 + tid];
  __syncthreads();
  if (tid < 128) {
    float bv = 0.f;
#pragma unroll
    for (int d = 0; d < 16; d++) bv = fmaf(es[d], bp[d * OG_ + tid], bv);
    bias_s[tid] = bv;
  }
  const _Float16* Ab = XG + (size_t)n * 64 * KP_;
  const _Float16* Bb = Wt + (size_t)n * OG_ * KP_;
  f16x8 af[2][2], bf[2][4];
#pragma unroll
  for (int mt = 0; mt < 2; mt++)
    af[0][mt] = *(const f16x8*)&Ab[(wm * 32 + mt * 16 + fm) * KP_ + fq * 8];
#pragma unroll
  for (int nt = 0; nt < 4; nt++)
    bf[0][nt] = *(const f16x8*)&Bb[(wn * 64 + nt * 16 + fm) * KP_ + fq * 8];
  f32x4 acc[2][4] = {};
#pragma unroll
  for (int kk = 0; kk < 7; kk++) {
    const int cur = kk & 1;
    if (kk < 6) {
      const int ko = (kk + 1) * 32 + fq * 8;
#pragma unroll
      for (int mt = 0; mt < 2; mt++)
        af[cur ^ 1][mt] = *(const f16x8*)&Ab[(wm * 32 + mt * 16 + fm) * KP_ + ko];
#pragma unroll
      for (int nt = 0; nt < 4; nt++)
        bf[cur ^ 1][nt] = *(const f16x8*)&Bb[(wn * 64 + nt * 16 + fm) * KP_ + ko];
    }
#pragma unroll
    for (int mt = 0; mt < 2; mt++)
#pragma unroll
      for (int nt = 0; nt < 4; nt++)
        acc[mt][nt] = __builtin_amdgcn_mfma_f32_16x16x32_f16(af[cur][mt], bf[cur][nt], acc[mt][nt], 0, 0, 0);
  }
  __syncthreads();
#pragma unroll
  for (int nt = 0; nt < 4; nt++) {
    const int o = wn * 64 + nt * 16 + fm;
    const float bias = bias_s[o];
#pragma unroll
    for (int mt = 0; mt < 2; mt++) {
      const f32x4 v = acc[mt][nt];
#pragma unroll
      for (int j = 0; j < 4; j++) {
        const int b = wm * 32 + mt * 16 + fq * 4 + j;
        float s = 1.0f / (1.0f + __expf(-(v[j] + bias)));
        if (wn == 0) zs[b][o] = s;
        else         rs[b][o - H_] = s;
      }
    }
  }
  __syncthreads();
  {
    const int b = tid >> 2, q = tid & 3;
    const _Float16* hp = &h16[((size_t)b * N_ + n) * H_ + q * 16];
    _Float16* xp = &xgo[((size_t)n * 64 + b) * KP_ + 1 + q * 16];
    _Float16* rp = &r16[((size_t)b * N_ + n) * H_ + q * 16];
    f16x8 r0, r1;
#pragma unroll
    for (int i = 0; i < 8; i++) {
      r0[i] = (_Float16)rs[b][q * 16 + i];
      r1[i] = (_Float16)rs[b][q * 16 + 8 + i];
    }
    *(f16x8*)rp = r0;
    *(f16x8*)(rp + 8) = r1;
    f16x8 h0 = *(const f16x8*)hp;
    f16x8 h1 = *(const f16x8*)(hp + 8);
    f16x8 x0, x1;
#pragma unroll
    for (int i = 0; i < 8; i++) {
      x0[i] = (_Float16)(zs[b][q * 16 + i] * (float)h0[i]);
      x1[i] = (_Float16)(zs[b][q * 16 + 8 + i] * (float)h1[i]);
    }
    *(f16x8*)xp = x0;
    *(f16x8*)(xp + 8) = x1;
    if (tid < 64) {
      float sv = src[((size_t)tid * T_ + t) * N_ + n];
      xgo[((size_t)n * 64 + tid) * KP_] = (_Float16)sv;
    }
  }
}

// ---------------------------------------------------------------------------
// Fused upd contract: MFMA hc; h_new = r*h + (1-r)*hc via LDS; h fp16; writes h
// (coalesced) and (t<11) next gate inputs into xg seg0.
__global__ __launch_bounds__(256) void k_cu(
    const float* __restrict__ eu, const _Float16* XG,
    const _Float16* __restrict__ Wt, const float* __restrict__ bp,
    const _Float16* __restrict__ r16, const float* __restrict__ src,
    int t, int donext,
    _Float16* __restrict__ h16, _Float16* xgo) {
  const int n = blockIdx.x;
  const int tid = threadIdx.x;
  const int wave = tid >> 6, lane = tid & 63;
  const int fm = lane & 15, fq = lane >> 4;
  __shared__ float es[16];
  __shared__ float bias_s[64];
  __shared__ float hs[64][68];
  __shared__ float rs[64][68];
  if (tid < 16) es[tid] = eu[n * 16 + tid];
  __syncthreads();
  if (tid < 64) {
    float bv = 0.f;
#pragma unroll
    for (int d = 0; d < 16; d++) bv = fmaf(es[d], bp[d * OU_ + tid], bv);
    bias_s[tid] = bv;
  }
  {
    const int b = tid >> 2, q = tid & 3;
    const _Float16* hp = &h16[((size_t)b * N_ + n) * H_ + q * 16];
    const _Float16* rp = &r16[((size_t)b * N_ + n) * H_ + q * 16];
    f16x8 h0 = *(const f16x8*)hp;
    f16x8 h1 = *(const f16x8*)(hp + 8);
    f16x8 r0 = *(const f16x8*)rp;
    f16x8 r1 = *(const f16x8*)(rp + 8);
#pragma unroll
    for (int i = 0; i < 8; i++) {
      hs[b][q * 16 + i] = (float)h0[i];
      hs[b][q * 16 + 8 + i] = (float)h1[i];
      rs[b][q * 16 + i] = (float)r0[i];
      rs[b][q * 16 + 8 + i] = (float)r1[i];
    }
  }
  __syncthreads();
  const _Float16* Ab = XG + (size_t)n * 64 * KP_;
  const _Float16* Bb = Wt + (size_t)n * OU_ * KP_;
  f16x8 af[2], bf[2][4];
  af[0] = *(const f16x8*)&Ab[(wave * 16 + fm) * KP_ + fq * 8];
#pragma unroll
  for (int nt = 0; nt < 4; nt++)
    bf[0][nt] = *(const f16x8*)&Bb[(nt * 16 + fm) * KP_ + fq * 8];
  f32x4 acc[4] = {};
#pragma unroll
  for (int kk = 0; kk < 7; kk++) {
    const int cur = kk & 1;
    if (kk < 6) {
      const int ko = (kk + 1) * 32 + fq * 8;
      af[cur ^ 1] = *(const f16x8*)&Ab[(wave * 16 + fm) * KP_ + ko];
#pragma unroll
      for (int nt = 0; nt < 4; nt++)
        bf[cur ^ 1][nt] = *(const f16x8*)&Bb[(nt * 16 + fm) * KP_ + ko];
    }
#pragma unroll
    for (int nt = 0; nt < 4; nt++)
      acc[nt] = __builtin_amdgcn_mfma_f32_16x16x32_f16(af[cur], bf[cur][nt], acc[nt], 0, 0, 0);
  }
#pragma unroll
  for (int nt = 0; nt < 4; nt++) {
    const int o = nt * 16 + fm;
    const float bias = bias_s[o];
    const f32x4 v = acc[nt];
#pragma unroll
    for (int j = 0; j < 4; j++) {
      const int b = wave * 16 + fq * 4 + j;
      float hc = tanhf(v[j] + bias);
      float rv = rs[b][o];
      hs[b][o] = rv * hs[b][o] + (1.0f - rv) * hc;
    }
  }
  __syncthreads();
  {
    const int b = tid >> 2, q = tid & 3;
    _Float16* hp = &h16[((size_t)b * N_ + n) * H_ + q * 16];
    f16x8 h0, h1;
#pragma unroll
    for (int i = 0; i < 8; i++) {
      h0[i] = (_Float16)hs[b][q * 16 + i];
      h1[i] = (_Float16)hs[b][q * 16 + 8 + i];
    }
    *(f16x8*)hp = h0;
    *(f16x8*)(hp + 8) = h1;
    if (donext) {
      _Float16* xp = &xgo[((size_t)n * 64 + b) * KP_ + 1 + q * 16];
      *(f16x8*)xp = h0;
      *(f16x8*)(xp + 8) = h1;
      if (tid < 64) {
        float sv = src[((size_t)tid * T_ + (t + 1)) * N_ + n];
        xgo[((size_t)n * 64 + tid) * KP_] = (_Float16)sv;
      }
    }
  }
}

// ---------------------------------------------------------------------------
// LN(h) + conv, one thread per (b,n).  h fp16.
__global__ __launch_bounds__(256) void k_final(const _Float16* __restrict__ h16,
                                               const float* __restrict__ out_lng,
                                               const float* __restrict__ out_lnb,
                                               const float* __restrict__ conv_w,
                                               const float* __restrict__ conv_b,
                                               float* __restrict__ out) {
  const int b = blockIdx.x >> 2;
  const int n = (blockIdx.x & 3) * 256 + threadIdx.x;
  __shared__ float cw[12][64];
  __shared__ float cb[12];
  __shared__ float lgs[64], lbs[64];
  for (int idx = threadIdx.x; idx < 12 * 64; idx += 256) cw[idx >> 6][idx & 63] = conv_w[idx];
  if (threadIdx.x < 12) cb[threadIdx.x] = conv_b[threadIdx.x];
  if (threadIdx.x < 64) { lgs[threadIdx.x] = out_lng[threadIdx.x]; lbs[threadIdx.x] = out_lnb[threadIdx.x]; }
  __syncthreads();
  const _Float16* hp = &h16[((size_t)b * N_ + n) * H_];
  float hv[64];
  float mean = 0.f;
#pragma unroll
  for (int i8 = 0; i8 < 8; i8++) {
    f16x8 v = *(const f16x8*)&hp[i8 * 8];
#pragma unroll
    for (int j = 0; j < 8; j++) { hv[i8 * 8 + j] = (float)v[j]; mean += hv[i8 * 8 + j]; }
  }
  mean *= (1.0f / H_);
  float var = 0.f;
#pragma unroll
  for (int i = 0; i < 64; i++) { float d = hv[i] - mean; var += d * d; }
  var *= (1.0f / H_);
  const float rs = rsqrtf(var + EPS_);
  float y[64];
#pragma unroll
  for (int i = 0; i < 64; i++)
    y[i] = (hv[i] - mean) * rs * lgs[i] + lbs[i];
#pragma unroll
  for (int o = 0; o < 12; o++) {
    float acc = cb[o];
#pragma unroll
    for (int i = 0; i < 64; i++) acc = fmaf(y[i], cw[o][i], acc);
    out[((size_t)b * 12 + o) * N_ + n] = acc;
  }
}

// ---------------------------------------------------------------------------
extern "C" void kernel_launch(void* const* d_in, const int* in_sizes, int n_in,
                              void* d_out, int out_size, void* d_ws, size_t ws_size,
                              hipStream_t stream) {
  const float* src      = (const float*)d_in[0];
  const float* node_emb = (const float*)d_in[1];
  const float* time_emb = (const float*)d_in[2];
  const float* gate_wp  = (const float*)d_in[3];
  const float* gate_bp  = (const float*)d_in[4];
  const float* gate_lng = (const float*)d_in[5];
  const float* gate_lnb = (const float*)d_in[6];
  const float* upd_wp   = (const float*)d_in[7];
  const float* upd_bp   = (const float*)d_in[8];
  const float* upd_lng  = (const float*)d_in[9];
  const float* upd_lnb  = (const float*)d_in[10];
  const float* out_lng  = (const float*)d_in[11];
  const float* out_lnb  = (const float*)d_in[12];
  const float* conv_w   = (const float*)d_in[13];
  const float* conv_b   = (const float*)d_in[14];
  float* out = (float*)d_out;

  constexpr size_t SZ_H16 = (size_t)B_ * N_ * H_ / 2;    // h fp16: 2,097,152 slots
  constexpr size_t SZ_R   = SZ_H16;                      // r fp16
  constexpr size_t SZ_T   = (size_t)NP_ * 1024 / 2;      // 2,162,688
  constexpr size_t SZ_XG  = (size_t)N_ * 64 * KP_ / 2;   // 7,340,032
  constexpr size_t SZ_WT  = (size_t)N_ * OG_ * KP_ / 2;  // 14,680,064 (WtU aliases 1st half)
  constexpr size_t SZ_WCG = (size_t)COLG_ * 16 / 2;      // 229,376
  constexpr size_t SZ_WCU = (size_t)COLU_ * 16 / 2;      // 114,688
  constexpr size_t SZ_S   = (size_t)N_ * N_ / 2;         // 524,288

  float* ws = (float*)d_ws;
  size_t off = 0;
  float* h16F   = ws + off; off += SZ_H16;
  float* r16F   = ws + off; off += SZ_R;
  float* XtF    = ws + off; off += SZ_T;
  float* y1tF   = ws + off; off += SZ_T;
  float* xgF    = ws + off; off += SZ_XG;
  float* WtF    = ws + off; off += SZ_WT;
  float* wcgF   = ws + off; off += SZ_WCG;
  float* wcuF   = ws + off; off += SZ_WCU;
  float* supGF  = ws + off; off += SZ_S;
  float* supUF  = ws + off; off += 2 * SZ_S;     // double-buffered
  float* eg_all  = ws + off; off += (size_t)T_ * NE_;
  float* egT_all = ws + off; off += (size_t)T_ * NE_;
  float* eu_all  = ws + off; off += (size_t)T_ * NE_;
  float* euT_all = ws + off; off += (size_t)T_ * NE_;
  if (ws_size < off * sizeof(float)) return;     // ~133 MB

  _Float16* h16  = (_Float16*)h16F;
  _Float16* r16  = (_Float16*)r16F;
  _Float16* Xt   = (_Float16*)XtF;
  _Float16* y1t  = (_Float16*)y1tF;
  _Float16* xg   = (_Float16*)xgF;
  _Float16* WtG  = (_Float16*)WtF;
  _Float16* WtU  = (_Float16*)WtF;
  _Float16* wpCg = (_Float16*)wcgF;
  _Float16* wpCu = (_Float16*)wcuF;
  _Float16* supG = (_Float16*)supGF;
  _Float16* supU = (_Float16*)supUF;

  hipMemsetAsync(h16, 0, SZ_H16 * sizeof(float), stream);
  k_pre0<<<2 * KP_ + 48, 256, 0, stream>>>(gate_wp, upd_wp, wpCg, wpCu,
                                           node_emb, time_emb,
                                           gate_lng, gate_lnb, upd_lng, upd_lnb,
                                           eg_all, egT_all, eu_all, euT_all);
  k_pro<<<3072, 256, 0, stream>>>(egT_all, euT_all, src, supG, supU, Xt, xg);

  for (int t = 0; t < T_; t++) {
    _Float16* sU  = supU + (size_t)(t & 1) * N_ * N_;
    _Float16* sUn = supU + (size_t)((t + 1) & 1) * N_ * N_;
    const float* eg_t = eg_all + (size_t)t * NE_;
    const float* eu_t = eu_all + (size_t)t * NE_;
    const int tn = (t < T_ - 1) ? t + 1 : t;
    const int more = (t < T_ - 1) ? 1 : 0;
    k_g1<<<976, 256, 0, stream>>>(supG, Xt, y1t, xg, eg_t, wpCg, WtG);
    k_g2<<<528, 256, 0, stream>>>(supG, y1t, xg);
    k_cg<<<N_, 256, 0, stream>>>(eg_t, xg, WtG, gate_bp, h16, src, t, r16, xg);
    k_tr<<<1024, 256, 0, stream>>>(xg, Xt);        // upd X -> Xt
    k_g3<<<752, 256, 0, stream>>>(sU, Xt, y1t, xg, eu_t, wpCu, WtU);
    k_g4<<<2576, 256, 0, stream>>>(sU, y1t, xg,
                                   egT_all + (size_t)tn * NE_,
                                   euT_all + (size_t)tn * NE_,
                                   supG, sUn, more);
    k_cu<<<N_, 256, 0, stream>>>(eu_t, xg, WtU, upd_bp, r16, src, t, more, h16, xg);
    if (more) k_tr<<<1024, 256, 0, stream>>>(xg, Xt);   // next gate X -> Xt
  }
  k_final<<<B_ * N_ / 256, 256, 0, stream>>>(h16, out_lng, out_lnb, conv_w, conv_b, out);
}